// Round 10
// baseline (1170.475 us; speedup 1.0000x reference)
//
#include <hip/hip_runtime.h>
#include <hip/hip_bf16.h>

#define SEQ    1024
#define DM     256
#define NH     8
#define NB     8
#define NLAYER 4
#define MLPD   1024
#define ROWS   (NB*SEQ)      // 8192
#define QKVW   6144          // 3*NH*DM
#define INNERW 2048          // NH*DM

typedef __attribute__((ext_vector_type(8))) short bh8;
typedef __attribute__((ext_vector_type(4))) short bh4;
typedef __attribute__((ext_vector_type(4))) float fx4;

__device__ __forceinline__ short f2bf(float f) {
  return __builtin_bit_cast(short, __float2bfloat16(f));
}
__device__ __forceinline__ fx4 mfma16(bh8 a, bh8 b, fx4 c) {
  return __builtin_amdgcn_mfma_f32_16x16x32_bf16(a, b, c, 0, 0, 0);
}
__device__ __forceinline__ void g2l16(const void* g, void* l) {
  __builtin_amdgcn_global_load_lds(
      (const __attribute__((address_space(1))) void*)g,
      (__attribute__((address_space(3))) void*)l, 16, 0, 0);
}
// granule permutation kept from R9 (conflict count invariant to the bijection,
// but harmless; see R9 notes)
__device__ __forceinline__ int kperm(int r) {
  return ((r & 1) << 2) | ((r >> 1) & 3);
}

// ---------------- f32 copy (x -> xf, xf -> out) ----------------
__global__ void copy_f32_k(const float* __restrict__ src, float* __restrict__ dst) {
  size_t i = ((size_t)blockIdx.x * 256 + threadIdx.x) * 4;
  *(fx4*)(dst + i) = *(const fx4*)(src + i);
}

// ---------------- f32 -> bf16 transpose (per-layer via blockIdx.z) ----------------
// src: [R][C] f32 (row stride C), dst: [C][R] bf16
__global__ void wtrans_k(const float* __restrict__ src, __hip_bfloat16* __restrict__ dst,
                         int R, int C, size_t sls, size_t dls) {
  src += (size_t)blockIdx.z * sls;
  dst += (size_t)blockIdx.z * dls;
  __shared__ float t[32][33];
  int tx = threadIdx.x, ty = threadIdx.y;
  int r0 = blockIdx.y * 32, c0 = blockIdx.x * 32;
#pragma unroll
  for (int i = 0; i < 32; i += 8) t[ty + i][tx] = src[(size_t)(r0 + ty + i) * C + c0 + tx];
  __syncthreads();
#pragma unroll
  for (int i = 0; i < 32; i += 8)
    dst[(size_t)(c0 + ty + i) * R + r0 + tx] = __float2bfloat16(t[tx][ty + i]);
}

// V part of qkv (bf16) -> vT[b][h][d][n] (bf16), with key order inside each
// 32-key block permuted to match the PV A-fragment order:
//   slot(k) = ((k>>2)&3)*8 + (k&3) + (((k>>4)&1)<<2)   (k = key within 32-block)
// 64x64 tiles: 128-B contiguous segments on both read and write sides.
__global__ void vtrans_k(const __hip_bfloat16* __restrict__ qkv, __hip_bfloat16* __restrict__ vT) {
  int bh = blockIdx.z, b = bh >> 3, hh = bh & 7;
  const __hip_bfloat16* src = qkv + (size_t)b * SEQ * QKVW + 4096 + hh * 256; // [n][d], ld QKVW
  __hip_bfloat16* dst = vT + (size_t)bh * 256 * SEQ;                          // [d][n], ld SEQ
  __shared__ __hip_bfloat16 t[64][65];
  int tx = threadIdx.x, ty = threadIdx.y;   // (64, 8)
  int n0 = blockIdx.x * 64, d0 = blockIdx.y * 64;
#pragma unroll
  for (int i = 0; i < 64; i += 8) t[ty + i][tx] = src[(size_t)(n0 + ty + i) * QKVW + d0 + tx];
  __syncthreads();
  int slot = (tx & 32) + ((tx >> 2) & 3) * 8 + (tx & 3) + (((tx >> 4) & 1) << 2);
#pragma unroll
  for (int i = 0; i < 64; i += 8) dst[(size_t)(d0 + ty + i) * SEQ + n0 + slot] = t[tx][ty + i];
}

// ---------------- LayerNorm over axis=1 (sequence), per-(b,d) stats ----------------
// grid (DM/8, NB) = 256 blocks, block 256
__global__ void ln_k(const float* __restrict__ xf, const float* __restrict__ gam,
                     const float* __restrict__ bet, __hip_bfloat16* __restrict__ h) {
  int b = blockIdx.y, d0 = blockIdx.x * 8;
  int dl = threadIdx.x & 7;
  int nt = threadIdx.x >> 3;   // 0..31
  int d = d0 + dl;
  const float* xb = xf + (size_t)b * SEQ * DM;
  float s = 0.f, ss = 0.f;
  for (int n = nt; n < SEQ; n += 32) {
    float v = xb[(size_t)n * DM + d];
    s += v; ss += v * v;
  }
  __shared__ float S1[32][8], S2[32][8];
  __shared__ float MU[8], RS[8];
  S1[nt][dl] = s; S2[nt][dl] = ss;
  __syncthreads();
  if (nt == 0) {
    float a = 0.f, c = 0.f;
#pragma unroll
    for (int i = 0; i < 32; i++) { a += S1[i][dl]; c += S2[i][dl]; }
    float mu = a * (1.f / SEQ);
    float var = c * (1.f / SEQ) - mu * mu;
    MU[dl] = mu; RS[dl] = rsqrtf(var + 1e-3f);
  }
  __syncthreads();
  float mu = MU[dl], rs = RS[dl];
  __hip_bfloat16* hb = h + (size_t)b * SEQ * DM;
  for (int n = nt; n < SEQ; n += 32) {
    float v = (xb[(size_t)n * DM + d] - mu) * rs * gam[n] + bet[n];
    hb[(size_t)n * DM + d] = __float2bfloat16(v);
  }
}

// ---------------- GEMM: C[M,Nc] = A[M,K] * Bt[Nc,K]^T  (+ epilogues) ----------------
// BK=64 (32 MFMA per barrier-pair), LDS kperm-swizzled staging, XCD-aware bijective
// block swizzle (T1).
// EPI 0: store bf16   EPI 1: +bias(f32), exact GELU, store bf16   EPI 2: resid[f32] += acc + bias
// EPI 0/1: after the k-loop, accumulators round-trip through the (now free) 32 KB
// smem as a dense 128xBN bf16 tile, then 8 coalesced bh8 stores per thread
// (16 lanes = one full 256-B row) replace 64 scattered 2-B stores. Only 2 extra
// barriers per BLOCK (R6's failed variant paid per-half barriers + half-idle waves).
template <int BN, int EPI>
__global__ __launch_bounds__(256) void gemm_bt(
    const __hip_bfloat16* __restrict__ A, const __hip_bfloat16* __restrict__ Bt,
    __hip_bfloat16* __restrict__ Cout, const float* __restrict__ bias,
    float* __restrict__ resid, int M, int Nc, int K) {
  constexpr int BM = 128, BK = 64;
  constexpr int NR = BN / 32;
  static_assert(BN == 64 || BN == 128, "");
  __shared__ __hip_bfloat16 smem[(BM + BN) * BK];
  __hip_bfloat16* As = smem;
  __hip_bfloat16* Bs = smem + BM * BK;
  const int tid = threadIdx.x;
  const int lane = tid & 63, w = tid >> 6;
  const int g = lane >> 4, qr = lane & 15;
  const int wr = w >> 1, wc = w & 1;
  // XCD swizzle: apparent id -> logical id so each XCD gets a contiguous chunk
  const unsigned aid = blockIdx.y * gridDim.x + blockIdx.x;
  const unsigned nwg = gridDim.x * gridDim.y;
  const unsigned lid = (aid & 7u) * (nwg >> 3) + (aid >> 3);
  const int m0 = (int)(lid / gridDim.x) * BM, n0 = (int)(lid % gridDim.x) * BN;
  const int swr = kperm(qr & 7);

  fx4 acc[4][NR];
#pragma unroll
  for (int m = 0; m < 4; m++)
#pragma unroll
    for (int n = 0; n < NR; n++) acc[m][n] = 0.f;

  constexpr int ACH = (BM * BK) / (8 * 256); // 4
  constexpr int BCH = (BN * BK) / (8 * 256); // 4 or 2

  for (int k0 = 0; k0 < K; k0 += BK) {
    __syncthreads();
#pragma unroll
    for (int c = 0; c < ACH; c++) {
      int idx = tid + c * 256;
      int row = idx >> 3, gr2 = idx & 7;
      g2l16(A + (size_t)(m0 + row) * K + k0 + ((gr2 ^ kperm(row & 7)) << 3), (char*)As + idx * 16);
    }
#pragma unroll
    for (int c = 0; c < BCH; c++) {
      int idx = tid + c * 256;
      int col = idx >> 3, gr2 = idx & 7;
      g2l16(Bt + (size_t)(n0 + col) * K + k0 + ((gr2 ^ kperm(col & 7)) << 3), (char*)Bs + idx * 16);
    }
    __syncthreads();
#pragma unroll
    for (int ks = 0; ks < 2; ks++) {
      bh8 af[4], bf[NR];
#pragma unroll
      for (int m = 0; m < 4; m++)
        af[m] = *(const bh8*)(As + (wr * 64 + m * 16 + qr) * BK + (((ks * 4 + g) ^ swr) << 3));
#pragma unroll
      for (int n = 0; n < NR; n++)
        bf[n] = *(const bh8*)(Bs + (wc * (BN / 2) + n * 16 + qr) * BK + (((ks * 4 + g) ^ swr) << 3));
#pragma unroll
      for (int m = 0; m < 4; m++)
#pragma unroll
        for (int n = 0; n < NR; n++) acc[m][n] = mfma16(af[m], bf[n], acc[m][n]);
    }
  }

  if constexpr (EPI == 2) {
#pragma unroll
    for (int n = 0; n < NR; n++) {
      int gc = n0 + wc * (BN / 2) + n * 16 + qr;
      float bv = bias[gc];
#pragma unroll
      for (int m = 0; m < 4; m++) {
        int grb = m0 + wr * 64 + m * 16 + g * 4;
#pragma unroll
        for (int r = 0; r < 4; r++)
          resid[(size_t)(grb + r) * Nc + gc] += acc[m][n][r] + bv;
      }
    }
  } else {
    // ---- coalesced store via dense smem round-trip ----
    __syncthreads();                       // all waves done reading As/Bs
    __hip_bfloat16* Cs = smem;             // BM*BN elems <= (BM+BN)*BK (16384 == 16384)
#pragma unroll
    for (int n = 0; n < NR; n++) {
      int lc = wc * (BN / 2) + n * 16 + qr;
      float bv = (EPI == 1) ? bias[n0 + lc] : 0.f;
#pragma unroll
      for (int m = 0; m < 4; m++) {
        int lr = wr * 64 + m * 16 + g * 4;
#pragma unroll
        for (int r = 0; r < 4; r++) {
          float v = acc[m][n][r];
          if (EPI == 1) {
            v += bv;
            v = 0.5f * v * (1.f + erff(v * 0.70710678118654752f));
          }
          Cs[(lr + r) * BN + lc] = __float2bfloat16(v);
        }
      }
    }
    __syncthreads();
    constexpr int CCH = (BM * BN) / (8 * 256);  // 8 (BN=128) or 4 (BN=64)
#pragma unroll
    for (int c = 0; c < CCH; c++) {
      int off = (tid + c * 256) * 8;
      int row = off / BN, col = off % BN;
      *(bh8*)(Cout + (size_t)(m0 + row) * Nc + n0 + col) = *(const bh8*)(Cs + off);
    }
  }
}

// ---------------- Flash attention: grid (SEQ/64, NH, NB), 4 waves x 16 q-rows ----------------
// R9 config (best measured: 124 µs): single-buffered Ks/Vs, 256 threads, 4 blocks/CU,
// XCD-aware bijective swizzle, kperm K-granules, defer-max + exp2 softmax.
//   Ks: [key 0..31][256 d], granule G holds data granule G ^ kperm(key&7)
//   Vs: [d 0..255][32 key-slots] (slots PV-permuted by vtrans_k), G ^= (d>>1)&3
__global__ __launch_bounds__(256) void attn_k(
    const __hip_bfloat16* __restrict__ qkv, const __hip_bfloat16* __restrict__ vT,
    __hip_bfloat16* __restrict__ z) {
  __shared__ __hip_bfloat16 Ks[32 * 256];
  __shared__ __hip_bfloat16 Vs[256 * 32];
  const int tid = threadIdx.x;
  const int lane = tid & 63, w = tid >> 6;
  const int g = lane >> 4, qr = lane & 15;
  // XCD swizzle: nwg = 16*8*8 = 1024, chunk = 128 logical blocks per XCD
  const unsigned aid = (blockIdx.z * NH + blockIdx.y) * (SEQ / 64) + blockIdx.x;
  const unsigned lid = (aid & 7u) * 128u + (aid >> 3);
  const int qi = lid & 15, hh = (lid >> 4) & 7, b = lid >> 7;
  const int q0 = qi * 64 + w * 16;
  const size_t qkv_b = (size_t)b * SEQ * QKVW;

  // Q fragments: lane holds Q[q0+qr][kd*32 + g*8 .. +8]
  bh8 qf[8];
  {
    const __hip_bfloat16* qrow = qkv + qkv_b + (size_t)(q0 + qr) * QKVW + hh * 256 + g * 8;
#pragma unroll
    for (int kd = 0; kd < 8; kd++) qf[kd] = *(const bh8*)(qrow + kd * 32);
  }

  fx4 o[16];
#pragma unroll
  for (int i = 0; i < 16; i++) o[i] = 0.f;
  float m_run = -INFINITY, l_run = 0.f;        // m_run in RAW score units
  constexpr float cL = 0.0625f * 1.44269504f;  // scale * log2(e)

  const int ksw = kperm(qr & 7);          // Ks read swizzle (rows qr and 16+qr share it)
  const int vsw = ((qr >> 1) & 3);        // Vs read swizzle (d = nd*16+qr -> (d>>1)&3)

  for (int j0 = 0; j0 < SEQ; j0 += 32) {
    __syncthreads();
#pragma unroll
    for (int c = 0; c < 4; c++) {
      int idx = tid + c * 256;
      int key = idx >> 5, c16 = idx & 31;
      int dp = (c16 ^ kperm(key & 7)) << 3; // pre-swizzled source column (elements)
      g2l16(qkv + qkv_b + (size_t)(j0 + key) * QKVW + 2048 + hh * 256 + dp, (char*)Ks + idx * 16);
    }
    const __hip_bfloat16* vb = vT + ((size_t)(b * 8 + hh) * 256) * SEQ + j0;
#pragma unroll
    for (int c = 0; c < 4; c++) {
      int idx = tid + c * 256;
      int d = idx >> 2, gr = idx & 3;
      int np = (gr ^ ((d >> 1) & 3)) << 3; // pre-swizzled source slot (elements)
      g2l16(vb + (size_t)d * SEQ + np, (char*)Vs + idx * 16);
    }
    __syncthreads();

    // S^T = K * Q^T : lane holds S[q=qr][key = {g*4+r, 16+g*4+r}]  (raw scores)
    fx4 s0 = 0.f, s1 = 0.f;
#pragma unroll
    for (int kd = 0; kd < 8; kd++) {
      bh8 k0f = *(const bh8*)(Ks + (size_t)qr * 256 + (((kd * 4 + g) ^ ksw) << 3));
      bh8 k1f = *(const bh8*)(Ks + (size_t)(16 + qr) * 256 + (((kd * 4 + g) ^ ksw) << 3));
      s0 = mfma16(k0f, qf[kd], s0);
      s1 = mfma16(k1f, qf[kd], s1);
    }
    float sv[8];
#pragma unroll
    for (int r = 0; r < 4; r++) { sv[r] = s0[r]; sv[4 + r] = s1[r]; }
    float pmax = sv[0];
#pragma unroll
    for (int i = 1; i < 8; i++) pmax = fmaxf(pmax, sv[i]);
    pmax = fmaxf(pmax, __shfl_xor(pmax, 16));
    pmax = fmaxf(pmax, __shfl_xor(pmax, 32));
    // defer-max: rescale only if some row's max grew by > 128 raw (= 8 scaled)
    if (!__all(pmax <= m_run + 128.f)) {
      float m_new = fmaxf(m_run, pmax);
      float corr = __builtin_amdgcn_exp2f((m_run - m_new) * cL); // first tile: 0
      float co[4];
#pragma unroll
      for (int r = 0; r < 4; r++) co[r] = __shfl(corr, (lane & 48) | (g * 4 + r));
#pragma unroll
      for (int nd = 0; nd < 16; nd++) {
        o[nd][0] *= co[0]; o[nd][1] *= co[1]; o[nd][2] *= co[2]; o[nd][3] *= co[3];
      }
      l_run *= corr;
      m_run = m_new;
    }
    float mL = m_run * cL;
    float p[8], ps = 0.f;
#pragma unroll
    for (int i = 0; i < 8; i++) {
      p[i] = __builtin_amdgcn_exp2f(fmaf(sv[i], cL, -mL)); // bounded by 2^8
      ps += p[i];
    }
    ps += __shfl_xor(ps, 16);
    ps += __shfl_xor(ps, 32);
    l_run += ps;
    // P -> bf16 A-frag with key(g,i) = g*4 + (i&3) + 16*(i>>2); Vs slots hold V in the
    // same key order, so the B-fragment is ONE bh8 read (swizzled).
    bh8 pa;
#pragma unroll
    for (int i = 0; i < 8; i++) pa[i] = f2bf(p[i]);
#pragma unroll
    for (int nd = 0; nd < 16; nd++) {
      int d = nd * 16 + qr;
      bh8 vf = *(const bh8*)(Vs + (size_t)d * 32 + ((g ^ vsw) << 3));
      o[nd] = mfma16(pa, vf, o[nd]);
    }
  }

  float inv = 1.f / l_run;
  float io[4];
#pragma unroll
  for (int r = 0; r < 4; r++) io[r] = __shfl(inv, (lane & 48) | (g * 4 + r));
  __hip_bfloat16* zb = z + (size_t)b * SEQ * INNERW + hh * 256;
#pragma unroll
  for (int nd = 0; nd < 16; nd++)
#pragma unroll
    for (int r = 0; r < 4; r++)
      zb[(size_t)(q0 + g * 4 + r) * INNERW + nd * 16 + qr] = __float2bfloat16(o[nd][r] * io[r]);
}

// ---------------- host ----------------
extern "C" void kernel_launch(void* const* d_in, const int* in_sizes, int n_in,
                              void* d_out, int out_size, void* d_ws, size_t ws_size,
                              hipStream_t stream) {
  const float* x_in  = (const float*)d_in[0];
  const float* ln1g  = (const float*)d_in[1];
  const float* ln1b  = (const float*)d_in[2];
  const float* w_qkv = (const float*)d_in[3];
  const float* w_out = (const float*)d_in[4];
  const float* b_out = (const float*)d_in[5];
  const float* ln2g  = (const float*)d_in[6];
  const float* ln2b  = (const float*)d_in[7];
  const float* w1    = (const float*)d_in[8];
  const float* b1    = (const float*)d_in[9];
  const float* w2    = (const float*)d_in[10];
  const float* b2    = (const float*)d_in[11];

  char* ws = (char*)d_ws;
  size_t off = 0;
  auto alloc = [&](size_t bytes) { char* p = ws + off; off += (bytes + 255) & ~(size_t)255; return p; };
  float*          xf    = (float*)         alloc((size_t)ROWS * DM * 4);
  __hip_bfloat16* h     = (__hip_bfloat16*)alloc((size_t)ROWS * DM * 2);
  __hip_bfloat16* qkv   = (__hip_bfloat16*)alloc((size_t)ROWS * QKVW * 2);
  __hip_bfloat16* vT    = (__hip_bfloat16*)alloc((size_t)NB * NH * 256 * SEQ * 2);
  __hip_bfloat16* zbuf  = (__hip_bfloat16*)alloc((size_t)ROWS * INNERW * 2);
  __hip_bfloat16* mh    = zbuf; // MLP hidden reuses z region (disjoint lifetimes)
  __hip_bfloat16* wqkvT = (__hip_bfloat16*)alloc((size_t)NLAYER * QKVW * DM * 2);
  __hip_bfloat16* woutT = (__hip_bfloat16*)alloc((size_t)NLAYER * DM * INNERW * 2);
  __hip_bfloat16* w1T   = (__hip_bfloat16*)alloc((size_t)NLAYER * MLPD * DM * 2);
  __hip_bfloat16* w2T   = (__hip_bfloat16*)alloc((size_t)NLAYER * DM * MLPD * 2);
  (void)ws_size; (void)in_sizes; (void)n_in; (void)out_size;

  copy_f32_k<<<2048, 256, 0, stream>>>(x_in, xf);

  // weight transposes+casts (weights constant across the launch)
  wtrans_k<<<dim3(QKVW / 32, DM / 32, NLAYER), dim3(32, 8), 0, stream>>>(
      w_qkv, wqkvT, DM, QKVW, (size_t)DM * QKVW, (size_t)DM * QKVW);
  wtrans_k<<<dim3(DM / 32, INNERW / 32, NLAYER), dim3(32, 8), 0, stream>>>(
      w_out, woutT, INNERW, DM, (size_t)INNERW * DM, (size_t)INNERW * DM);
  wtrans_k<<<dim3(MLPD / 32, DM / 32, NLAYER), dim3(32, 8), 0, stream>>>(
      w1, w1T, DM, MLPD, (size_t)DM * MLPD, (size_t)DM * MLPD);
  wtrans_k<<<dim3(DM / 32, MLPD / 32, NLAYER), dim3(32, 8), 0, stream>>>(
      w2, w2T, MLPD, DM, (size_t)MLPD * DM, (size_t)MLPD * DM);

  for (int i = 0; i < NLAYER; i++) {
    ln_k<<<dim3(DM / 8, NB), 256, 0, stream>>>(xf, ln1g + i * SEQ, ln1b + i * SEQ, h);
    gemm_bt<128, 0><<<dim3(QKVW / 128, ROWS / 128), 256, 0, stream>>>(
        h, wqkvT + (size_t)i * QKVW * DM, qkv, nullptr, nullptr, ROWS, QKVW, DM);
    vtrans_k<<<dim3(SEQ / 64, 256 / 64, NB * NH), dim3(64, 8), 0, stream>>>(qkv, vT);
    attn_k<<<dim3(SEQ / 64, NH, NB), 256, 0, stream>>>(qkv, vT, zbuf);
    gemm_bt<64, 2><<<dim3(DM / 64, ROWS / 128), 256, 0, stream>>>(
        zbuf, woutT + (size_t)i * DM * INNERW, nullptr, b_out + i * DM, xf, ROWS, DM, INNERW);
    ln_k<<<dim3(DM / 8, NB), 256, 0, stream>>>(xf, ln2g + i * SEQ, ln2b + i * SEQ, h);
    gemm_bt<128, 1><<<dim3(MLPD / 128, ROWS / 128), 256, 0, stream>>>(
        h, w1T + (size_t)i * MLPD * DM, mh, b1 + i * MLPD, nullptr, ROWS, MLPD, DM);
    gemm_bt<64, 2><<<dim3(DM / 64, ROWS / 128), 256, 0, stream>>>(
        mh, w2T + (size_t)i * DM * MLPD, nullptr, b2 + i * DM, xf, ROWS, DM, MLPD);
  }

  copy_f32_k<<<2048, 256, 0, stream>>>(xf, (float*)d_out);
}

// Round 11
// 1164.594 us; speedup vs baseline: 1.0051x; 1.0051x over previous
//
#include <hip/hip_runtime.h>
#include <hip/hip_bf16.h>

#define SEQ    1024
#define DM     256
#define NH     8
#define NB     8
#define NLAYER 4
#define MLPD   1024
#define ROWS   (NB*SEQ)      // 8192
#define QKVW   6144          // 3*NH*DM
#define INNERW 2048          // NH*DM

typedef __attribute__((ext_vector_type(8))) short bh8;
typedef __attribute__((ext_vector_type(4))) short bh4;
typedef __attribute__((ext_vector_type(4))) float fx4;

__device__ __forceinline__ short f2bf(float f) {
  return __builtin_bit_cast(short, __float2bfloat16(f));
}
__device__ __forceinline__ fx4 mfma16(bh8 a, bh8 b, fx4 c) {
  return __builtin_amdgcn_mfma_f32_16x16x32_bf16(a, b, c, 0, 0, 0);
}
__device__ __forceinline__ void g2l16(const void* g, void* l) {
  __builtin_amdgcn_global_load_lds(
      (const __attribute__((address_space(1))) void*)g,
      (__attribute__((address_space(3))) void*)l, 16, 0, 0);
}
__device__ __forceinline__ int kperm(int r) {
  return ((r & 1) << 2) | ((r >> 1) & 3);
}

// ---------------- f32 -> bf16 transpose (per-layer via blockIdx.z) ----------------
// src: [R][C] f32 (row stride C), dst: [C][R] bf16
__global__ void wtrans_k(const float* __restrict__ src, __hip_bfloat16* __restrict__ dst,
                         int R, int C, size_t sls, size_t dls) {
  src += (size_t)blockIdx.z * sls;
  dst += (size_t)blockIdx.z * dls;
  __shared__ float t[32][33];
  int tx = threadIdx.x, ty = threadIdx.y;
  int r0 = blockIdx.y * 32, c0 = blockIdx.x * 32;
#pragma unroll
  for (int i = 0; i < 32; i += 8) t[ty + i][tx] = src[(size_t)(r0 + ty + i) * C + c0 + tx];
  __syncthreads();
#pragma unroll
  for (int i = 0; i < 32; i += 8)
    dst[(size_t)(c0 + ty + i) * R + r0 + tx] = __float2bfloat16(t[tx][ty + i]);
}

// V part of qkv (bf16) -> vT[b][h][d][n] (bf16), with key order inside each
// 32-key block permuted to match the PV A-fragment order:
//   slot(k) = ((k>>2)&3)*8 + (k&3) + (((k>>4)&1)<<2)   (k = key within 32-block)
// 64x64 tiles: 128-B contiguous segments on both read and write sides.
__global__ void vtrans_k(const __hip_bfloat16* __restrict__ qkv, __hip_bfloat16* __restrict__ vT) {
  int bh = blockIdx.z, b = bh >> 3, hh = bh & 7;
  const __hip_bfloat16* src = qkv + (size_t)b * SEQ * QKVW + 4096 + hh * 256; // [n][d], ld QKVW
  __hip_bfloat16* dst = vT + (size_t)bh * 256 * SEQ;                          // [d][n], ld SEQ
  __shared__ __hip_bfloat16 t[64][65];
  int tx = threadIdx.x, ty = threadIdx.y;   // (64, 8)
  int n0 = blockIdx.x * 64, d0 = blockIdx.y * 64;
#pragma unroll
  for (int i = 0; i < 64; i += 8) t[ty + i][tx] = src[(size_t)(n0 + ty + i) * QKVW + d0 + tx];
  __syncthreads();
  int slot = (tx & 32) + ((tx >> 2) & 3) * 8 + (tx & 3) + (((tx >> 4) & 1) << 2);
#pragma unroll
  for (int i = 0; i < 64; i += 8) dst[(size_t)(d0 + ty + i) * SEQ + n0 + slot] = t[tx][ty + i];
}

// ---------------- LayerNorm over axis=1 (sequence), per-(b,d) stats ----------------
// grid (DM/8, NB) = 256 blocks, block 256
__global__ void ln_k(const float* __restrict__ xf, const float* __restrict__ gam,
                     const float* __restrict__ bet, __hip_bfloat16* __restrict__ h) {
  int b = blockIdx.y, d0 = blockIdx.x * 8;
  int dl = threadIdx.x & 7;
  int nt = threadIdx.x >> 3;   // 0..31
  int d = d0 + dl;
  const float* xb = xf + (size_t)b * SEQ * DM;
  float s = 0.f, ss = 0.f;
  for (int n = nt; n < SEQ; n += 32) {
    float v = xb[(size_t)n * DM + d];
    s += v; ss += v * v;
  }
  __shared__ float S1[32][8], S2[32][8];
  __shared__ float MU[8], RS[8];
  S1[nt][dl] = s; S2[nt][dl] = ss;
  __syncthreads();
  if (nt == 0) {
    float a = 0.f, c = 0.f;
#pragma unroll
    for (int i = 0; i < 32; i++) { a += S1[i][dl]; c += S2[i][dl]; }
    float mu = a * (1.f / SEQ);
    float var = c * (1.f / SEQ) - mu * mu;
    MU[dl] = mu; RS[dl] = rsqrtf(var + 1e-3f);
  }
  __syncthreads();
  float mu = MU[dl], rs = RS[dl];
  __hip_bfloat16* hb = h + (size_t)b * SEQ * DM;
  for (int n = nt; n < SEQ; n += 32) {
    float v = (xb[(size_t)n * DM + d] - mu) * rs * gam[n] + bet[n];
    hb[(size_t)n * DM + d] = __float2bfloat16(v);
  }
}

// ---------------- GEMM: C[M,Nc] = A[M,K] * Bt[Nc,K]^T  (+ epilogues) ----------------
// BK=64, kperm-swizzled LDS staging, XCD-aware bijective block swizzle.
// SWAPPED MFMA OPERANDS: mfma16(bf, af) computes the transposed C/D fragment, so each
// lane holds 4 CONSECUTIVE OUTPUT COLUMNS at one row (A/B fragments are layout-
// symmetric — same trick as attn's S^T=K*Q^T). Epilogue needs no LDS/barriers:
// EPI 0: 8-B bh4 stores.  EPI 1: +bias, exact GELU, 8-B stores.
// EPI 2: rout = rin + acc + bias as 16-B float4 RMW (rin may differ from rout).
template <int BN, int EPI>
__global__ __launch_bounds__(256) void gemm_bt(
    const __hip_bfloat16* __restrict__ A, const __hip_bfloat16* __restrict__ Bt,
    __hip_bfloat16* __restrict__ Cout, const float* __restrict__ bias,
    const float* __restrict__ rin, float* __restrict__ rout, int M, int Nc, int K) {
  constexpr int BM = 128, BK = 64;
  constexpr int NR = BN / 32;
  static_assert(BN == 64 || BN == 128, "");
  __shared__ __hip_bfloat16 As[BM * BK];
  __shared__ __hip_bfloat16 Bs[BN * BK];
  const int tid = threadIdx.x;
  const int lane = tid & 63, w = tid >> 6;
  const int g = lane >> 4, qr = lane & 15;
  const int wr = w >> 1, wc = w & 1;
  // XCD swizzle: apparent id -> logical id so each XCD gets a contiguous chunk
  const unsigned aid = blockIdx.y * gridDim.x + blockIdx.x;
  const unsigned nwg = gridDim.x * gridDim.y;
  const unsigned lid = (aid & 7u) * (nwg >> 3) + (aid >> 3);
  const int m0 = (int)(lid / gridDim.x) * BM, n0 = (int)(lid % gridDim.x) * BN;
  const int swr = kperm(qr & 7);

  fx4 acc[4][NR];
#pragma unroll
  for (int m = 0; m < 4; m++)
#pragma unroll
    for (int n = 0; n < NR; n++) acc[m][n] = 0.f;

  constexpr int ACH = (BM * BK) / (8 * 256); // 4
  constexpr int BCH = (BN * BK) / (8 * 256); // 4 or 2

  for (int k0 = 0; k0 < K; k0 += BK) {
    __syncthreads();
#pragma unroll
    for (int c = 0; c < ACH; c++) {
      int idx = tid + c * 256;
      int row = idx >> 3, gr2 = idx & 7;
      g2l16(A + (size_t)(m0 + row) * K + k0 + ((gr2 ^ kperm(row & 7)) << 3), (char*)As + idx * 16);
    }
#pragma unroll
    for (int c = 0; c < BCH; c++) {
      int idx = tid + c * 256;
      int col = idx >> 3, gr2 = idx & 7;
      g2l16(Bt + (size_t)(n0 + col) * K + k0 + ((gr2 ^ kperm(col & 7)) << 3), (char*)Bs + idx * 16);
    }
    __syncthreads();
#pragma unroll
    for (int ks = 0; ks < 2; ks++) {
      bh8 af[4], bf[NR];
#pragma unroll
      for (int m = 0; m < 4; m++)
        af[m] = *(const bh8*)(As + (wr * 64 + m * 16 + qr) * BK + (((ks * 4 + g) ^ swr) << 3));
#pragma unroll
      for (int n = 0; n < NR; n++)
        bf[n] = *(const bh8*)(Bs + (wc * (BN / 2) + n * 16 + qr) * BK + (((ks * 4 + g) ^ swr) << 3));
#pragma unroll
      for (int m = 0; m < 4; m++)
#pragma unroll
        for (int n = 0; n < NR; n++) acc[m][n] = mfma16(bf[n], af[m], acc[m][n]);  // SWAPPED
    }
  }

  // Swapped layout: acc[m][n][r] = C[m0+wr*64+m*16+qr][n0+wc*(BN/2)+n*16+g*4+r]
  if constexpr (EPI == 2) {
#pragma unroll
    for (int n = 0; n < NR; n++) {
      int gcb = n0 + wc * (BN / 2) + n * 16 + g * 4;
      fx4 bv = *(const fx4*)(bias + gcb);
#pragma unroll
      for (int m = 0; m < 4; m++) {
        int row = m0 + wr * 64 + m * 16 + qr;
        fx4 rv = *(const fx4*)(rin + (size_t)row * Nc + gcb);
#pragma unroll
        for (int r = 0; r < 4; r++) rv[r] += acc[m][n][r] + bv[r];
        *(fx4*)(rout + (size_t)row * Nc + gcb) = rv;
      }
    }
  } else {
#pragma unroll
    for (int n = 0; n < NR; n++) {
      int gcb = n0 + wc * (BN / 2) + n * 16 + g * 4;
      fx4 bv = 0.f;
      if (EPI == 1) bv = *(const fx4*)(bias + gcb);
#pragma unroll
      for (int m = 0; m < 4; m++) {
        int row = m0 + wr * 64 + m * 16 + qr;
        bh4 ov;
#pragma unroll
        for (int r = 0; r < 4; r++) {
          float v = acc[m][n][r];
          if (EPI == 1) {
            v += bv[r];
            v = 0.5f * v * (1.f + erff(v * 0.70710678118654752f));
          }
          ov[r] = f2bf(v);
        }
        *(bh4*)(Cout + (size_t)row * Nc + gcb) = ov;
      }
    }
  }
}

// ---------------- Flash attention: grid (SEQ/64, NH, NB), 4 waves x 16 q-rows ----------------
// R9 config (best measured: 124 µs): single-buffered Ks/Vs, 256 threads, 4 blocks/CU,
// XCD-aware bijective swizzle, kperm K-granules, defer-max + exp2 softmax.
//   Ks: [key 0..31][256 d], granule G holds data granule G ^ kperm(key&7)
//   Vs: [d 0..255][32 key-slots] (slots PV-permuted by vtrans_k), G ^= (d>>1)&3
__global__ __launch_bounds__(256) void attn_k(
    const __hip_bfloat16* __restrict__ qkv, const __hip_bfloat16* __restrict__ vT,
    __hip_bfloat16* __restrict__ z) {
  __shared__ __hip_bfloat16 Ks[32 * 256];
  __shared__ __hip_bfloat16 Vs[256 * 32];
  const int tid = threadIdx.x;
  const int lane = tid & 63, w = tid >> 6;
  const int g = lane >> 4, qr = lane & 15;
  // XCD swizzle: nwg = 16*8*8 = 1024, chunk = 128 logical blocks per XCD
  const unsigned aid = (blockIdx.z * NH + blockIdx.y) * (SEQ / 64) + blockIdx.x;
  const unsigned lid = (aid & 7u) * 128u + (aid >> 3);
  const int qi = lid & 15, hh = (lid >> 4) & 7, b = lid >> 7;
  const int q0 = qi * 64 + w * 16;
  const size_t qkv_b = (size_t)b * SEQ * QKVW;

  // Q fragments: lane holds Q[q0+qr][kd*32 + g*8 .. +8]
  bh8 qf[8];
  {
    const __hip_bfloat16* qrow = qkv + qkv_b + (size_t)(q0 + qr) * QKVW + hh * 256 + g * 8;
#pragma unroll
    for (int kd = 0; kd < 8; kd++) qf[kd] = *(const bh8*)(qrow + kd * 32);
  }

  fx4 o[16];
#pragma unroll
  for (int i = 0; i < 16; i++) o[i] = 0.f;
  float m_run = -INFINITY, l_run = 0.f;        // m_run in RAW score units
  constexpr float cL = 0.0625f * 1.44269504f;  // scale * log2(e)

  const int ksw = kperm(qr & 7);          // Ks read swizzle (rows qr and 16+qr share it)
  const int vsw = ((qr >> 1) & 3);        // Vs read swizzle (d = nd*16+qr -> (d>>1)&3)

  for (int j0 = 0; j0 < SEQ; j0 += 32) {
    __syncthreads();
#pragma unroll
    for (int c = 0; c < 4; c++) {
      int idx = tid + c * 256;
      int key = idx >> 5, c16 = idx & 31;
      int dp = (c16 ^ kperm(key & 7)) << 3; // pre-swizzled source column (elements)
      g2l16(qkv + qkv_b + (size_t)(j0 + key) * QKVW + 2048 + hh * 256 + dp, (char*)Ks + idx * 16);
    }
    const __hip_bfloat16* vb = vT + ((size_t)(b * 8 + hh) * 256) * SEQ + j0;
#pragma unroll
    for (int c = 0; c < 4; c++) {
      int idx = tid + c * 256;
      int d = idx >> 2, gr = idx & 3;
      int np = (gr ^ ((d >> 1) & 3)) << 3; // pre-swizzled source slot (elements)
      g2l16(vb + (size_t)d * SEQ + np, (char*)Vs + idx * 16);
    }
    __syncthreads();

    // S^T = K * Q^T : lane holds S[q=qr][key = {g*4+r, 16+g*4+r}]  (raw scores)
    fx4 s0 = 0.f, s1 = 0.f;
#pragma unroll
    for (int kd = 0; kd < 8; kd++) {
      bh8 k0f = *(const bh8*)(Ks + (size_t)qr * 256 + (((kd * 4 + g) ^ ksw) << 3));
      bh8 k1f = *(const bh8*)(Ks + (size_t)(16 + qr) * 256 + (((kd * 4 + g) ^ ksw) << 3));
      s0 = mfma16(k0f, qf[kd], s0);
      s1 = mfma16(k1f, qf[kd], s1);
    }
    float sv[8];
#pragma unroll
    for (int r = 0; r < 4; r++) { sv[r] = s0[r]; sv[4 + r] = s1[r]; }
    float pmax = sv[0];
#pragma unroll
    for (int i = 1; i < 8; i++) pmax = fmaxf(pmax, sv[i]);
    pmax = fmaxf(pmax, __shfl_xor(pmax, 16));
    pmax = fmaxf(pmax, __shfl_xor(pmax, 32));
    // defer-max: rescale only if some row's max grew by > 128 raw (= 8 scaled)
    if (!__all(pmax <= m_run + 128.f)) {
      float m_new = fmaxf(m_run, pmax);
      float corr = __builtin_amdgcn_exp2f((m_run - m_new) * cL); // first tile: 0
      float co[4];
#pragma unroll
      for (int r = 0; r < 4; r++) co[r] = __shfl(corr, (lane & 48) | (g * 4 + r));
#pragma unroll
      for (int nd = 0; nd < 16; nd++) {
        o[nd][0] *= co[0]; o[nd][1] *= co[1]; o[nd][2] *= co[2]; o[nd][3] *= co[3];
      }
      l_run *= corr;
      m_run = m_new;
    }
    float mL = m_run * cL;
    float p[8], ps = 0.f;
#pragma unroll
    for (int i = 0; i < 8; i++) {
      p[i] = __builtin_amdgcn_exp2f(fmaf(sv[i], cL, -mL)); // bounded by 2^8
      ps += p[i];
    }
    ps += __shfl_xor(ps, 16);
    ps += __shfl_xor(ps, 32);
    l_run += ps;
    // P -> bf16 A-frag with key(g,i) = g*4 + (i&3) + 16*(i>>2); Vs slots hold V in the
    // same key order, so the B-fragment is ONE bh8 read (swizzled).
    bh8 pa;
#pragma unroll
    for (int i = 0; i < 8; i++) pa[i] = f2bf(p[i]);
#pragma unroll
    for (int nd = 0; nd < 16; nd++) {
      int d = nd * 16 + qr;
      bh8 vf = *(const bh8*)(Vs + (size_t)d * 32 + ((g ^ vsw) << 3));
      o[nd] = mfma16(pa, vf, o[nd]);
    }
  }

  float inv = 1.f / l_run;
  float io[4];
#pragma unroll
  for (int r = 0; r < 4; r++) io[r] = __shfl(inv, (lane & 48) | (g * 4 + r));
  __hip_bfloat16* zb = z + (size_t)b * SEQ * INNERW + hh * 256;
#pragma unroll
  for (int nd = 0; nd < 16; nd++)
#pragma unroll
    for (int r = 0; r < 4; r++)
      zb[(size_t)(q0 + g * 4 + r) * INNERW + nd * 16 + qr] = __float2bfloat16(o[nd][r] * io[r]);
}

// ---------------- host ----------------
extern "C" void kernel_launch(void* const* d_in, const int* in_sizes, int n_in,
                              void* d_out, int out_size, void* d_ws, size_t ws_size,
                              hipStream_t stream) {
  const float* x_in  = (const float*)d_in[0];
  const float* ln1g  = (const float*)d_in[1];
  const float* ln1b  = (const float*)d_in[2];
  const float* w_qkv = (const float*)d_in[3];
  const float* w_out = (const float*)d_in[4];
  const float* b_out = (const float*)d_in[5];
  const float* ln2g  = (const float*)d_in[6];
  const float* ln2b  = (const float*)d_in[7];
  const float* w1    = (const float*)d_in[8];
  const float* b1    = (const float*)d_in[9];
  const float* w2    = (const float*)d_in[10];
  const float* b2    = (const float*)d_in[11];

  char* ws = (char*)d_ws;
  size_t off = 0;
  auto alloc = [&](size_t bytes) { char* p = ws + off; off += (bytes + 255) & ~(size_t)255; return p; };
  float*          xf    = (float*)         alloc((size_t)ROWS * DM * 4);
  __hip_bfloat16* h     = (__hip_bfloat16*)alloc((size_t)ROWS * DM * 2);
  __hip_bfloat16* qkv   = (__hip_bfloat16*)alloc((size_t)ROWS * QKVW * 2);
  __hip_bfloat16* vT    = (__hip_bfloat16*)alloc((size_t)NB * NH * 256 * SEQ * 2);
  __hip_bfloat16* zbuf  = (__hip_bfloat16*)alloc((size_t)ROWS * INNERW * 2);
  __hip_bfloat16* mh    = zbuf; // MLP hidden reuses z region (disjoint lifetimes)
  __hip_bfloat16* wqkvT = (__hip_bfloat16*)alloc((size_t)NLAYER * QKVW * DM * 2);
  __hip_bfloat16* woutT = (__hip_bfloat16*)alloc((size_t)NLAYER * DM * INNERW * 2);
  __hip_bfloat16* w1T   = (__hip_bfloat16*)alloc((size_t)NLAYER * MLPD * DM * 2);
  __hip_bfloat16* w2T   = (__hip_bfloat16*)alloc((size_t)NLAYER * DM * MLPD * 2);
  (void)ws_size; (void)in_sizes; (void)n_in; (void)out_size;

  // weight transposes+casts (weights constant across the launch)
  wtrans_k<<<dim3(QKVW / 32, DM / 32, NLAYER), dim3(32, 8), 0, stream>>>(
      w_qkv, wqkvT, DM, QKVW, (size_t)DM * QKVW, (size_t)DM * QKVW);
  wtrans_k<<<dim3(DM / 32, INNERW / 32, NLAYER), dim3(32, 8), 0, stream>>>(
      w_out, woutT, INNERW, DM, (size_t)INNERW * DM, (size_t)INNERW * DM);
  wtrans_k<<<dim3(MLPD / 32, DM / 32, NLAYER), dim3(32, 8), 0, stream>>>(
      w1, w1T, DM, MLPD, (size_t)DM * MLPD, (size_t)DM * MLPD);
  wtrans_k<<<dim3(DM / 32, MLPD / 32, NLAYER), dim3(32, 8), 0, stream>>>(
      w2, w2T, MLPD, DM, (size_t)MLPD * DM, (size_t)MLPD * DM);

  for (int i = 0; i < NLAYER; i++) {
    // layer 0 reads the residual stream from x_in directly (no initial copy)
    const float* xcur = (i == 0) ? x_in : xf;
    float* xnext_out = (i == NLAYER - 1) ? (float*)d_out : xf;

    ln_k<<<dim3(DM / 8, NB), 256, 0, stream>>>(xcur, ln1g + i * SEQ, ln1b + i * SEQ, h);
    gemm_bt<128, 0><<<dim3(QKVW / 128, ROWS / 128), 256, 0, stream>>>(
        h, wqkvT + (size_t)i * QKVW * DM, qkv, nullptr, nullptr, nullptr, ROWS, QKVW, DM);
    vtrans_k<<<dim3(SEQ / 64, 256 / 64, NB * NH), dim3(64, 8), 0, stream>>>(qkv, vT);
    attn_k<<<dim3(SEQ / 64, NH, NB), 256, 0, stream>>>(qkv, vT, zbuf);
    // attn-out: resid-in = xcur (x_in for layer 0), resid-out = xf
    gemm_bt<64, 2><<<dim3(DM / 64, ROWS / 128), 256, 0, stream>>>(
        zbuf, woutT + (size_t)i * DM * INNERW, nullptr, b_out + i * DM, xcur, xf, ROWS, DM, INNERW);
    ln_k<<<dim3(DM / 8, NB), 256, 0, stream>>>(xf, ln2g + i * SEQ, ln2b + i * SEQ, h);
    gemm_bt<128, 1><<<dim3(MLPD / 128, ROWS / 128), 256, 0, stream>>>(
        h, w1T + (size_t)i * MLPD * DM, mh, b1 + i * MLPD, nullptr, nullptr, ROWS, MLPD, DM);
    // mlp2: resid-in = xf, resid-out = d_out on the last layer (no final copy)
    gemm_bt<64, 2><<<dim3(DM / 64, ROWS / 128), 256, 0, stream>>>(
        mh, w2T + (size_t)i * DM * MLPD, nullptr, b2 + i * DM, xf, xnext_out, ROWS, DM, MLPD);
  }
}

// Round 12
// 1068.676 us; speedup vs baseline: 1.0953x; 1.0898x over previous
//
#include <hip/hip_runtime.h>
#include <hip/hip_bf16.h>

#define SEQ    1024
#define DM     256
#define NH     8
#define NB     8
#define NLAYER 4
#define MLPD   1024
#define ROWS   (NB*SEQ)      // 8192
#define QKVW   6144          // 3*NH*DM
#define INNERW 2048          // NH*DM

typedef __attribute__((ext_vector_type(8))) short bh8;
typedef __attribute__((ext_vector_type(4))) short bh4;
typedef __attribute__((ext_vector_type(4))) float fx4;

__device__ __forceinline__ short f2bf(float f) {
  return __builtin_bit_cast(short, __float2bfloat16(f));
}
__device__ __forceinline__ fx4 mfma16(bh8 a, bh8 b, fx4 c) {
  return __builtin_amdgcn_mfma_f32_16x16x32_bf16(a, b, c, 0, 0, 0);
}
__device__ __forceinline__ void g2l16(const void* g, void* l) {
  __builtin_amdgcn_global_load_lds(
      (const __attribute__((address_space(1))) void*)g,
      (__attribute__((address_space(3))) void*)l, 16, 0, 0);
}
__device__ __forceinline__ int kperm(int r) {
  return ((r & 1) << 2) | ((r >> 1) & 3);
}

// ---------------- f32 -> bf16 transpose (per-layer via blockIdx.z) ----------------
// src: [R][C] f32 (row stride C), dst: [C][R] bf16
__global__ void wtrans_k(const float* __restrict__ src, __hip_bfloat16* __restrict__ dst,
                         int R, int C, size_t sls, size_t dls) {
  src += (size_t)blockIdx.z * sls;
  dst += (size_t)blockIdx.z * dls;
  __shared__ float t[32][33];
  int tx = threadIdx.x, ty = threadIdx.y;
  int r0 = blockIdx.y * 32, c0 = blockIdx.x * 32;
#pragma unroll
  for (int i = 0; i < 32; i += 8) t[ty + i][tx] = src[(size_t)(r0 + ty + i) * C + c0 + tx];
  __syncthreads();
#pragma unroll
  for (int i = 0; i < 32; i += 8)
    dst[(size_t)(c0 + ty + i) * R + r0 + tx] = __float2bfloat16(t[tx][ty + i]);
}

// ---------------- LayerNorm over axis=1 (sequence), per-(b,d) stats ----------------
// grid (DM/8, NB) = 256 blocks, block 256
__global__ void ln_k(const float* __restrict__ xf, const float* __restrict__ gam,
                     const float* __restrict__ bet, __hip_bfloat16* __restrict__ h) {
  int b = blockIdx.y, d0 = blockIdx.x * 8;
  int dl = threadIdx.x & 7;
  int nt = threadIdx.x >> 3;   // 0..31
  int d = d0 + dl;
  const float* xb = xf + (size_t)b * SEQ * DM;
  float s = 0.f, ss = 0.f;
  for (int n = nt; n < SEQ; n += 32) {
    float v = xb[(size_t)n * DM + d];
    s += v; ss += v * v;
  }
  __shared__ float S1[32][8], S2[32][8];
  __shared__ float MU[8], RS[8];
  S1[nt][dl] = s; S2[nt][dl] = ss;
  __syncthreads();
  if (nt == 0) {
    float a = 0.f, c = 0.f;
#pragma unroll
    for (int i = 0; i < 32; i++) { a += S1[i][dl]; c += S2[i][dl]; }
    float mu = a * (1.f / SEQ);
    float var = c * (1.f / SEQ) - mu * mu;
    MU[dl] = mu; RS[dl] = rsqrtf(var + 1e-3f);
  }
  __syncthreads();
  float mu = MU[dl], rs = RS[dl];
  __hip_bfloat16* hb = h + (size_t)b * SEQ * DM;
  for (int n = nt; n < SEQ; n += 32) {
    float v = (xb[(size_t)n * DM + d] - mu) * rs * gam[n] + bet[n];
    hb[(size_t)n * DM + d] = __float2bfloat16(v);
  }
}

// ---------------- GEMM: C[M,Nc] = A[M,K] * Bt[Nc,K]^T  (+ epilogues) ----------------
// BK=64, kperm-swizzled LDS staging, XCD-aware bijective block swizzle, R9 epilogues.
// EPI 0: scalar bf16 stores   EPI 1: +bias, exact GELU, bf16 stores
// EPI 2: rout = rin + acc + bias (f32, rin may differ from rout)
// EPI 3 (qkv): n0 < 4096 -> EPI0 store into qkv; n0 >= 4096 (the V third) ->
//   TRANSPOSED store into vT via a 128x132-padded LDS round-trip, with the PV
//   slot-permutation  slot(k)=((k>>2)&3)*8+(k&3)+(((k>>4)&1)<<2)  applied on the
//   LDS write (maps 4 consecutive rows to 4 consecutive slots -> bh4 writes).
//   This replaces the standalone vtrans kernel (67 MB/layer round-trip) and the
//   V region of the qkv buffer is never written.
template <int BN, int EPI>
__global__ __launch_bounds__(256) void gemm_bt(
    const __hip_bfloat16* __restrict__ A, const __hip_bfloat16* __restrict__ Bt,
    __hip_bfloat16* __restrict__ Cout, const float* __restrict__ bias,
    const float* __restrict__ rin, float* __restrict__ rout,
    __hip_bfloat16* __restrict__ vT, int M, int Nc, int K) {
  constexpr int BM = 128, BK = 64;
  constexpr int NR = BN / 32;
  static_assert(BN == 64 || BN == 128, "");
  constexpr int LDSE = (EPI == 3) ? 128 * 132 : (BM + BN) * BK;
  __shared__ __hip_bfloat16 smem[LDSE];
  __hip_bfloat16* As = smem;
  __hip_bfloat16* Bs = smem + BM * BK;
  const int tid = threadIdx.x;
  const int lane = tid & 63, w = tid >> 6;
  const int g = lane >> 4, qr = lane & 15;
  const int wr = w >> 1, wc = w & 1;
  // XCD swizzle: apparent id -> logical id so each XCD gets a contiguous chunk
  const unsigned aid = blockIdx.y * gridDim.x + blockIdx.x;
  const unsigned nwg = gridDim.x * gridDim.y;
  const unsigned lid = (aid & 7u) * (nwg >> 3) + (aid >> 3);
  const int m0 = (int)(lid / gridDim.x) * BM, n0 = (int)(lid % gridDim.x) * BN;
  const int swr = kperm(qr & 7);

  fx4 acc[4][NR];
#pragma unroll
  for (int m = 0; m < 4; m++)
#pragma unroll
    for (int n = 0; n < NR; n++) acc[m][n] = 0.f;

  constexpr int ACH = (BM * BK) / (8 * 256); // 4
  constexpr int BCH = (BN * BK) / (8 * 256); // 4 or 2

  for (int k0 = 0; k0 < K; k0 += BK) {
    __syncthreads();
#pragma unroll
    for (int c = 0; c < ACH; c++) {
      int idx = tid + c * 256;
      int row = idx >> 3, gr2 = idx & 7;
      g2l16(A + (size_t)(m0 + row) * K + k0 + ((gr2 ^ kperm(row & 7)) << 3), (char*)As + idx * 16);
    }
#pragma unroll
    for (int c = 0; c < BCH; c++) {
      int idx = tid + c * 256;
      int col = idx >> 3, gr2 = idx & 7;
      g2l16(Bt + (size_t)(n0 + col) * K + k0 + ((gr2 ^ kperm(col & 7)) << 3), (char*)Bs + idx * 16);
    }
    __syncthreads();
#pragma unroll
    for (int ks = 0; ks < 2; ks++) {
      bh8 af[4], bf[NR];
#pragma unroll
      for (int m = 0; m < 4; m++)
        af[m] = *(const bh8*)(As + (wr * 64 + m * 16 + qr) * BK + (((ks * 4 + g) ^ swr) << 3));
#pragma unroll
      for (int n = 0; n < NR; n++)
        bf[n] = *(const bh8*)(Bs + (wc * (BN / 2) + n * 16 + qr) * BK + (((ks * 4 + g) ^ swr) << 3));
#pragma unroll
      for (int m = 0; m < 4; m++)
#pragma unroll
        for (int n = 0; n < NR; n++) acc[m][n] = mfma16(af[m], bf[n], acc[m][n]);
    }
  }

  // acc[m][n][r] = C[m0 + wr*64 + m*16 + g*4 + r][n0 + wc*(BN/2) + n*16 + qr]
  if constexpr (EPI == 2) {
#pragma unroll
    for (int n = 0; n < NR; n++) {
      int gc = n0 + wc * (BN / 2) + n * 16 + qr;
      float bv = bias[gc];
#pragma unroll
      for (int m = 0; m < 4; m++) {
        int grb = m0 + wr * 64 + m * 16 + g * 4;
#pragma unroll
        for (int r = 0; r < 4; r++)
          rout[(size_t)(grb + r) * Nc + gc] = rin[(size_t)(grb + r) * Nc + gc] + acc[m][n][r] + bv;
      }
    }
  } else if (EPI == 3 && n0 >= 4096) {
    // ---- V third: transposed store into vT via padded-LDS round-trip ----
    __syncthreads();                       // all waves done with As/Bs
    __hip_bfloat16* Cs = smem;             // [128 d][132 nn-padded]
#pragma unroll
    for (int n = 0; n < NR; n++) {
      int dl = wc * (BN / 2) + n * 16 + qr;
#pragma unroll
      for (int m = 0; m < 4; m++) {
        // permuted nn base: slot applied within each 32-row group
        int nlp = wr * 64 + (m >> 1) * 32 + g * 8 + (m & 1) * 4;
        bh4 v;
#pragma unroll
        for (int r = 0; r < 4; r++) v[r] = f2bf(acc[m][n][r]);
        *(bh4*)(Cs + dl * 132 + nlp) = v;
      }
    }
    __syncthreads();
    const int dl = tid >> 1, half = tid & 1;
    const int bb = m0 >> 10;
    const int hh = (n0 - 4096) >> 8;
    const int d0v = (n0 - 4096) & 255;
    __hip_bfloat16* dst =
        vT + ((size_t)(bb * 8 + hh) * 256 + d0v + dl) * SEQ + (m0 & 1023) + half * 64;
#pragma unroll
    for (int j = 0; j < 8; j++)
      *(bh8*)(dst + j * 8) = *(const bh8*)(Cs + dl * 132 + half * 64 + j * 8);
  } else {
#pragma unroll
    for (int n = 0; n < NR; n++) {
      int gc = n0 + wc * (BN / 2) + n * 16 + qr;
      float bv = (EPI == 1) ? bias[gc] : 0.f;
#pragma unroll
      for (int m = 0; m < 4; m++) {
        int grb = m0 + wr * 64 + m * 16 + g * 4;
#pragma unroll
        for (int r = 0; r < 4; r++) {
          float v = acc[m][n][r];
          if (EPI == 1) {
            v += bv;
            v = 0.5f * v * (1.f + erff(v * 0.70710678118654752f));
          }
          Cout[(size_t)(grb + r) * Nc + gc] = __float2bfloat16(v);
        }
      }
    }
  }
}

// ---------------- Flash attention: grid (SEQ/64, NH, NB), 4 waves x 16 q-rows ----------------
// R9 config (best measured: 124 µs): single-buffered Ks/Vs, 256 threads, 4 blocks/CU,
// XCD-aware bijective swizzle, kperm K-granules, defer-max + exp2 softmax.
//   Ks: [key 0..31][256 d], granule G holds data granule G ^ kperm(key&7)
//   Vs: [d 0..255][32 key-slots] (slots PV-permuted at vT creation), G ^= (d>>1)&3
__global__ __launch_bounds__(256) void attn_k(
    const __hip_bfloat16* __restrict__ qkv, const __hip_bfloat16* __restrict__ vT,
    __hip_bfloat16* __restrict__ z) {
  __shared__ __hip_bfloat16 Ks[32 * 256];
  __shared__ __hip_bfloat16 Vs[256 * 32];
  const int tid = threadIdx.x;
  const int lane = tid & 63, w = tid >> 6;
  const int g = lane >> 4, qr = lane & 15;
  // XCD swizzle: nwg = 16*8*8 = 1024, chunk = 128 logical blocks per XCD
  const unsigned aid = (blockIdx.z * NH + blockIdx.y) * (SEQ / 64) + blockIdx.x;
  const unsigned lid = (aid & 7u) * 128u + (aid >> 3);
  const int qi = lid & 15, hh = (lid >> 4) & 7, b = lid >> 7;
  const int q0 = qi * 64 + w * 16;
  const size_t qkv_b = (size_t)b * SEQ * QKVW;

  // Q fragments: lane holds Q[q0+qr][kd*32 + g*8 .. +8]
  bh8 qf[8];
  {
    const __hip_bfloat16* qrow = qkv + qkv_b + (size_t)(q0 + qr) * QKVW + hh * 256 + g * 8;
#pragma unroll
    for (int kd = 0; kd < 8; kd++) qf[kd] = *(const bh8*)(qrow + kd * 32);
  }

  fx4 o[16];
#pragma unroll
  for (int i = 0; i < 16; i++) o[i] = 0.f;
  float m_run = -INFINITY, l_run = 0.f;        // m_run in RAW score units
  constexpr float cL = 0.0625f * 1.44269504f;  // scale * log2(e)

  const int ksw = kperm(qr & 7);          // Ks read swizzle (rows qr and 16+qr share it)
  const int vsw = ((qr >> 1) & 3);        // Vs read swizzle (d = nd*16+qr -> (d>>1)&3)

  for (int j0 = 0; j0 < SEQ; j0 += 32) {
    __syncthreads();
#pragma unroll
    for (int c = 0; c < 4; c++) {
      int idx = tid + c * 256;
      int key = idx >> 5, c16 = idx & 31;
      int dp = (c16 ^ kperm(key & 7)) << 3; // pre-swizzled source column (elements)
      g2l16(qkv + qkv_b + (size_t)(j0 + key) * QKVW + 2048 + hh * 256 + dp, (char*)Ks + idx * 16);
    }
    const __hip_bfloat16* vb = vT + ((size_t)(b * 8 + hh) * 256) * SEQ + j0;
#pragma unroll
    for (int c = 0; c < 4; c++) {
      int idx = tid + c * 256;
      int d = idx >> 2, gr = idx & 3;
      int np = (gr ^ ((d >> 1) & 3)) << 3; // pre-swizzled source slot (elements)
      g2l16(vb + (size_t)d * SEQ + np, (char*)Vs + idx * 16);
    }
    __syncthreads();

    // S^T = K * Q^T : lane holds S[q=qr][key = {g*4+r, 16+g*4+r}]  (raw scores)
    fx4 s0 = 0.f, s1 = 0.f;
#pragma unroll
    for (int kd = 0; kd < 8; kd++) {
      bh8 k0f = *(const bh8*)(Ks + (size_t)qr * 256 + (((kd * 4 + g) ^ ksw) << 3));
      bh8 k1f = *(const bh8*)(Ks + (size_t)(16 + qr) * 256 + (((kd * 4 + g) ^ ksw) << 3));
      s0 = mfma16(k0f, qf[kd], s0);
      s1 = mfma16(k1f, qf[kd], s1);
    }
    float sv[8];
#pragma unroll
    for (int r = 0; r < 4; r++) { sv[r] = s0[r]; sv[4 + r] = s1[r]; }
    float pmax = sv[0];
#pragma unroll
    for (int i = 1; i < 8; i++) pmax = fmaxf(pmax, sv[i]);
    pmax = fmaxf(pmax, __shfl_xor(pmax, 16));
    pmax = fmaxf(pmax, __shfl_xor(pmax, 32));
    // defer-max: rescale only if some row's max grew by > 128 raw (= 8 scaled)
    if (!__all(pmax <= m_run + 128.f)) {
      float m_new = fmaxf(m_run, pmax);
      float corr = __builtin_amdgcn_exp2f((m_run - m_new) * cL); // first tile: 0
      float co[4];
#pragma unroll
      for (int r = 0; r < 4; r++) co[r] = __shfl(corr, (lane & 48) | (g * 4 + r));
#pragma unroll
      for (int nd = 0; nd < 16; nd++) {
        o[nd][0] *= co[0]; o[nd][1] *= co[1]; o[nd][2] *= co[2]; o[nd][3] *= co[3];
      }
      l_run *= corr;
      m_run = m_new;
    }
    float mL = m_run * cL;
    float p[8], ps = 0.f;
#pragma unroll
    for (int i = 0; i < 8; i++) {
      p[i] = __builtin_amdgcn_exp2f(fmaf(sv[i], cL, -mL)); // bounded by 2^8
      ps += p[i];
    }
    ps += __shfl_xor(ps, 16);
    ps += __shfl_xor(ps, 32);
    l_run += ps;
    // P -> bf16 A-frag with key(g,i) = g*4 + (i&3) + 16*(i>>2); Vs slots hold V in the
    // same key order, so the B-fragment is ONE bh8 read (swizzled).
    bh8 pa;
#pragma unroll
    for (int i = 0; i < 8; i++) pa[i] = f2bf(p[i]);
#pragma unroll
    for (int nd = 0; nd < 16; nd++) {
      int d = nd * 16 + qr;
      bh8 vf = *(const bh8*)(Vs + (size_t)d * 32 + ((g ^ vsw) << 3));
      o[nd] = mfma16(pa, vf, o[nd]);
    }
  }

  float inv = 1.f / l_run;
  float io[4];
#pragma unroll
  for (int r = 0; r < 4; r++) io[r] = __shfl(inv, (lane & 48) | (g * 4 + r));
  __hip_bfloat16* zb = z + (size_t)b * SEQ * INNERW + hh * 256;
#pragma unroll
  for (int nd = 0; nd < 16; nd++)
#pragma unroll
    for (int r = 0; r < 4; r++)
      zb[(size_t)(q0 + g * 4 + r) * INNERW + nd * 16 + qr] = __float2bfloat16(o[nd][r] * io[r]);
}

// ---------------- host ----------------
extern "C" void kernel_launch(void* const* d_in, const int* in_sizes, int n_in,
                              void* d_out, int out_size, void* d_ws, size_t ws_size,
                              hipStream_t stream) {
  const float* x_in  = (const float*)d_in[0];
  const float* ln1g  = (const float*)d_in[1];
  const float* ln1b  = (const float*)d_in[2];
  const float* w_qkv = (const float*)d_in[3];
  const float* w_out = (const float*)d_in[4];
  const float* b_out = (const float*)d_in[5];
  const float* ln2g  = (const float*)d_in[6];
  const float* ln2b  = (const float*)d_in[7];
  const float* w1    = (const float*)d_in[8];
  const float* b1    = (const float*)d_in[9];
  const float* w2    = (const float*)d_in[10];
  const float* b2    = (const float*)d_in[11];

  char* ws = (char*)d_ws;
  size_t off = 0;
  auto alloc = [&](size_t bytes) { char* p = ws + off; off += (bytes + 255) & ~(size_t)255; return p; };
  float*          xf    = (float*)         alloc((size_t)ROWS * DM * 4);
  __hip_bfloat16* h     = (__hip_bfloat16*)alloc((size_t)ROWS * DM * 2);
  __hip_bfloat16* qkv   = (__hip_bfloat16*)alloc((size_t)ROWS * QKVW * 2);
  __hip_bfloat16* vT    = (__hip_bfloat16*)alloc((size_t)NB * NH * 256 * SEQ * 2);
  __hip_bfloat16* zbuf  = (__hip_bfloat16*)alloc((size_t)ROWS * INNERW * 2);
  __hip_bfloat16* mh    = zbuf; // MLP hidden reuses z region (disjoint lifetimes)
  __hip_bfloat16* wqkvT = (__hip_bfloat16*)alloc((size_t)NLAYER * QKVW * DM * 2);
  __hip_bfloat16* woutT = (__hip_bfloat16*)alloc((size_t)NLAYER * DM * INNERW * 2);
  __hip_bfloat16* w1T   = (__hip_bfloat16*)alloc((size_t)NLAYER * MLPD * DM * 2);
  __hip_bfloat16* w2T   = (__hip_bfloat16*)alloc((size_t)NLAYER * DM * MLPD * 2);
  (void)ws_size; (void)in_sizes; (void)n_in; (void)out_size;

  // weight transposes+casts (weights constant across the launch)
  wtrans_k<<<dim3(QKVW / 32, DM / 32, NLAYER), dim3(32, 8), 0, stream>>>(
      w_qkv, wqkvT, DM, QKVW, (size_t)DM * QKVW, (size_t)DM * QKVW);
  wtrans_k<<<dim3(DM / 32, INNERW / 32, NLAYER), dim3(32, 8), 0, stream>>>(
      w_out, woutT, INNERW, DM, (size_t)INNERW * DM, (size_t)INNERW * DM);
  wtrans_k<<<dim3(MLPD / 32, DM / 32, NLAYER), dim3(32, 8), 0, stream>>>(
      w1, w1T, DM, MLPD, (size_t)DM * MLPD, (size_t)DM * MLPD);
  wtrans_k<<<dim3(DM / 32, MLPD / 32, NLAYER), dim3(32, 8), 0, stream>>>(
      w2, w2T, MLPD, DM, (size_t)MLPD * DM, (size_t)MLPD * DM);

  for (int i = 0; i < NLAYER; i++) {
    // layer 0 reads the residual stream from x_in directly (no initial copy)
    const float* xcur = (i == 0) ? x_in : xf;
    float* xnext_out = (i == NLAYER - 1) ? (float*)d_out : xf;

    ln_k<<<dim3(DM / 8, NB), 256, 0, stream>>>(xcur, ln1g + i * SEQ, ln1b + i * SEQ, h);
    // qkv GEMM with fused V-transpose epilogue (EPI 3) — vtrans kernel eliminated
    gemm_bt<128, 3><<<dim3(QKVW / 128, ROWS / 128), 256, 0, stream>>>(
        h, wqkvT + (size_t)i * QKVW * DM, qkv, nullptr, nullptr, nullptr, vT, ROWS, QKVW, DM);
    attn_k<<<dim3(SEQ / 64, NH, NB), 256, 0, stream>>>(qkv, vT, zbuf);
    // attn-out: resid-in = xcur (x_in for layer 0), resid-out = xf
    gemm_bt<64, 2><<<dim3(DM / 64, ROWS / 128), 256, 0, stream>>>(
        zbuf, woutT + (size_t)i * DM * INNERW, nullptr, b_out + i * DM, xcur, xf, nullptr,
        ROWS, DM, INNERW);
    ln_k<<<dim3(DM / 8, NB), 256, 0, stream>>>(xf, ln2g + i * SEQ, ln2b + i * SEQ, h);
    gemm_bt<128, 1><<<dim3(MLPD / 128, ROWS / 128), 256, 0, stream>>>(
        h, w1T + (size_t)i * MLPD * DM, mh, b1 + i * MLPD, nullptr, nullptr, nullptr,
        ROWS, MLPD, DM);
    // mlp2: resid-in = xf, resid-out = d_out on the last layer (no final copy)
    gemm_bt<64, 2><<<dim3(DM / 64, ROWS / 128), 256, 0, stream>>>(
        mh, w2T + (size_t)i * DM * MLPD, nullptr, b2 + i * DM, xf, xnext_out, nullptr,
        ROWS, DM, MLPD);
  }
}

// Round 13
// 1017.620 us; speedup vs baseline: 1.1502x; 1.0502x over previous
//
#include <hip/hip_runtime.h>
#include <hip/hip_bf16.h>

#define SEQ    1024
#define DM     256
#define NH     8
#define NB     8
#define NLAYER 4
#define MLPD   1024
#define ROWS   (NB*SEQ)      // 8192
#define QKVW   6144          // 3*NH*DM
#define INNERW 2048          // NH*DM

typedef __attribute__((ext_vector_type(8))) short bh8;
typedef __attribute__((ext_vector_type(4))) short bh4;
typedef __attribute__((ext_vector_type(4))) float fx4;

__device__ __forceinline__ short f2bf(float f) {
  return __builtin_bit_cast(short, __float2bfloat16(f));
}
__device__ __forceinline__ fx4 mfma16(bh8 a, bh8 b, fx4 c) {
  return __builtin_amdgcn_mfma_f32_16x16x32_bf16(a, b, c, 0, 0, 0);
}
__device__ __forceinline__ void g2l16(const void* g, void* l) {
  __builtin_amdgcn_global_load_lds(
      (const __attribute__((address_space(1))) void*)g,
      (__attribute__((address_space(3))) void*)l, 16, 0, 0);
}
__device__ __forceinline__ int kperm(int r) {
  return ((r & 1) << 2) | ((r >> 1) & 3);
}

// ---------------- f32 -> bf16 transpose (per-layer via blockIdx.z) ----------------
// src: [R][C] f32 (row stride C), dst: [C][R] bf16
__global__ void wtrans_k(const float* __restrict__ src, __hip_bfloat16* __restrict__ dst,
                         int R, int C, size_t sls, size_t dls) {
  src += (size_t)blockIdx.z * sls;
  dst += (size_t)blockIdx.z * dls;
  __shared__ float t[32][33];
  int tx = threadIdx.x, ty = threadIdx.y;
  int r0 = blockIdx.y * 32, c0 = blockIdx.x * 32;
#pragma unroll
  for (int i = 0; i < 32; i += 8) t[ty + i][tx] = src[(size_t)(r0 + ty + i) * C + c0 + tx];
  __syncthreads();
#pragma unroll
  for (int i = 0; i < 32; i += 8)
    dst[(size_t)(c0 + ty + i) * R + r0 + tx] = __float2bfloat16(t[tx][ty + i]);
}

// ---------------- LayerNorm over axis=1 (sequence), per-(b,d) stats ----------------
// grid (DM/16, NB) = 128 blocks, block 256. fx4 loads (64-B segments per 4 lanes),
// bh4 stores. Stats per d-column over the 1024-row sequence.
__global__ void ln_k(const float* __restrict__ xf, const float* __restrict__ gam,
                     const float* __restrict__ bet, __hip_bfloat16* __restrict__ h) {
  int b = blockIdx.y, d0 = blockIdx.x * 16;
  int dl = threadIdx.x & 3;          // fx4 column: d = d0 + dl*4 .. +3
  int nt = threadIdx.x >> 2;         // 0..63, rows stride 64
  const float* xb = xf + (size_t)b * SEQ * DM + d0 + dl * 4;
  fx4 s = 0.f, ss = 0.f;
  for (int n = nt; n < SEQ; n += 64) {
    fx4 v = *(const fx4*)(xb + (size_t)n * DM);
    s += v; ss += v * v;
  }
  __shared__ fx4 S1[64][4], S2[64][4];
  __shared__ fx4 MU[4], RS[4];
  S1[nt][dl] = s; S2[nt][dl] = ss;
  __syncthreads();
  if (nt == 0) {
    fx4 a = 0.f, c = 0.f;
#pragma unroll
    for (int i = 0; i < 64; i++) { a += S1[i][dl]; c += S2[i][dl]; }
    fx4 mu, rs;
#pragma unroll
    for (int r = 0; r < 4; r++) {
      mu[r] = a[r] * (1.f / SEQ);
      float var = c[r] * (1.f / SEQ) - mu[r] * mu[r];
      rs[r] = rsqrtf(var + 1e-3f);
    }
    MU[dl] = mu; RS[dl] = rs;
  }
  __syncthreads();
  fx4 mu = MU[dl], rs = RS[dl];
  __hip_bfloat16* hb = h + (size_t)b * SEQ * DM + d0 + dl * 4;
  for (int n = nt; n < SEQ; n += 64) {
    fx4 v = *(const fx4*)(xb + (size_t)n * DM);
    float gn = gam[n], bn = bet[n];
    bh4 o;
#pragma unroll
    for (int r = 0; r < 4; r++) o[r] = f2bf((v[r] - mu[r]) * rs[r] * gn + bn);
    *(bh4*)(hb + (size_t)n * DM) = o;
  }
}

// ---------------- GEMM: C[M,Nc] = A[M,K] * Bt[Nc,K]^T  (+ epilogues) ----------------
// BK=64, kperm-swizzled LDS staging, XCD-aware bijective block swizzle, R9 epilogues.
// EPI 0: scalar bf16 stores   EPI 1: +bias, exact GELU, bf16 stores
// EPI 2: rout = rin + acc + bias (f32, rin may differ from rout)
// EPI 3 (qkv): n0 < 4096 -> EPI0 store into qkv; n0 >= 4096 (the V third) ->
//   TRANSPOSED store into vT via a 128x132-padded LDS round-trip, with the PV
//   slot-permutation applied on the LDS write. Replaces the vtrans kernel.
template <int BN, int EPI>
__global__ __launch_bounds__(256) void gemm_bt(
    const __hip_bfloat16* __restrict__ A, const __hip_bfloat16* __restrict__ Bt,
    __hip_bfloat16* __restrict__ Cout, const float* __restrict__ bias,
    const float* __restrict__ rin, float* __restrict__ rout,
    __hip_bfloat16* __restrict__ vT, int M, int Nc, int K) {
  constexpr int BM = 128, BK = 64;
  constexpr int NR = BN / 32;
  static_assert(BN == 64 || BN == 128, "");
  constexpr int LDSE = (EPI == 3) ? 128 * 132 : (BM + BN) * BK;
  __shared__ __hip_bfloat16 smem[LDSE];
  __hip_bfloat16* As = smem;
  __hip_bfloat16* Bs = smem + BM * BK;
  const int tid = threadIdx.x;
  const int lane = tid & 63, w = tid >> 6;
  const int g = lane >> 4, qr = lane & 15;
  const int wr = w >> 1, wc = w & 1;
  // XCD swizzle: apparent id -> logical id so each XCD gets a contiguous chunk
  const unsigned aid = blockIdx.y * gridDim.x + blockIdx.x;
  const unsigned nwg = gridDim.x * gridDim.y;
  const unsigned lid = (aid & 7u) * (nwg >> 3) + (aid >> 3);
  const int m0 = (int)(lid / gridDim.x) * BM, n0 = (int)(lid % gridDim.x) * BN;
  const int swr = kperm(qr & 7);

  fx4 acc[4][NR];
#pragma unroll
  for (int m = 0; m < 4; m++)
#pragma unroll
    for (int n = 0; n < NR; n++) acc[m][n] = 0.f;

  constexpr int ACH = (BM * BK) / (8 * 256); // 4
  constexpr int BCH = (BN * BK) / (8 * 256); // 4 or 2

  for (int k0 = 0; k0 < K; k0 += BK) {
    __syncthreads();
#pragma unroll
    for (int c = 0; c < ACH; c++) {
      int idx = tid + c * 256;
      int row = idx >> 3, gr2 = idx & 7;
      g2l16(A + (size_t)(m0 + row) * K + k0 + ((gr2 ^ kperm(row & 7)) << 3), (char*)As + idx * 16);
    }
#pragma unroll
    for (int c = 0; c < BCH; c++) {
      int idx = tid + c * 256;
      int col = idx >> 3, gr2 = idx & 7;
      g2l16(Bt + (size_t)(n0 + col) * K + k0 + ((gr2 ^ kperm(col & 7)) << 3), (char*)Bs + idx * 16);
    }
    __syncthreads();
#pragma unroll
    for (int ks = 0; ks < 2; ks++) {
      bh8 af[4], bf[NR];
#pragma unroll
      for (int m = 0; m < 4; m++)
        af[m] = *(const bh8*)(As + (wr * 64 + m * 16 + qr) * BK + (((ks * 4 + g) ^ swr) << 3));
#pragma unroll
      for (int n = 0; n < NR; n++)
        bf[n] = *(const bh8*)(Bs + (wc * (BN / 2) + n * 16 + qr) * BK + (((ks * 4 + g) ^ swr) << 3));
#pragma unroll
      for (int m = 0; m < 4; m++)
#pragma unroll
        for (int n = 0; n < NR; n++) acc[m][n] = mfma16(af[m], bf[n], acc[m][n]);
    }
  }

  // acc[m][n][r] = C[m0 + wr*64 + m*16 + g*4 + r][n0 + wc*(BN/2) + n*16 + qr]
  if constexpr (EPI == 2) {
#pragma unroll
    for (int n = 0; n < NR; n++) {
      int gc = n0 + wc * (BN / 2) + n * 16 + qr;
      float bv = bias[gc];
#pragma unroll
      for (int m = 0; m < 4; m++) {
        int grb = m0 + wr * 64 + m * 16 + g * 4;
#pragma unroll
        for (int r = 0; r < 4; r++)
          rout[(size_t)(grb + r) * Nc + gc] = rin[(size_t)(grb + r) * Nc + gc] + acc[m][n][r] + bv;
      }
    }
  } else if (EPI == 3 && n0 >= 4096) {
    // ---- V third: transposed store into vT via padded-LDS round-trip ----
    __syncthreads();                       // all waves done with As/Bs
    __hip_bfloat16* Cs = smem;             // [128 d][132 nn-padded]
#pragma unroll
    for (int n = 0; n < NR; n++) {
      int dl = wc * (BN / 2) + n * 16 + qr;
#pragma unroll
      for (int m = 0; m < 4; m++) {
        // permuted nn base: slot applied within each 32-row group
        int nlp = wr * 64 + (m >> 1) * 32 + g * 8 + (m & 1) * 4;
        bh4 v;
#pragma unroll
        for (int r = 0; r < 4; r++) v[r] = f2bf(acc[m][n][r]);
        *(bh4*)(Cs + dl * 132 + nlp) = v;
      }
    }
    __syncthreads();
    const int dl = tid >> 1, half = tid & 1;
    const int bb = m0 >> 10;
    const int hh = (n0 - 4096) >> 8;
    const int d0v = (n0 - 4096) & 255;
    __hip_bfloat16* dst =
        vT + ((size_t)(bb * 8 + hh) * 256 + d0v + dl) * SEQ + (m0 & 1023) + half * 64;
#pragma unroll
    for (int j = 0; j < 8; j++)
      *(bh8*)(dst + j * 8) = *(const bh8*)(Cs + dl * 132 + half * 64 + j * 8);
  } else {
#pragma unroll
    for (int n = 0; n < NR; n++) {
      int gc = n0 + wc * (BN / 2) + n * 16 + qr;
      float bv = (EPI == 1) ? bias[gc] : 0.f;
#pragma unroll
      for (int m = 0; m < 4; m++) {
        int grb = m0 + wr * 64 + m * 16 + g * 4;
#pragma unroll
        for (int r = 0; r < 4; r++) {
          float v = acc[m][n][r];
          if (EPI == 1) {
            v += bv;
            v = 0.5f * v * (1.f + erff(v * 0.70710678118654752f));
          }
          Cout[(size_t)(grb + r) * Nc + gc] = __float2bfloat16(v);
        }
      }
    }
  }
}

// ---------------- Flash attention: grid (SEQ/64, NH, NB), 4 waves x 16 q-rows ----------------
// R9 structure + SWAPPED PV operands: o = mfma16(vf, pa) transposes the O fragment
// so lane (g,qr) holds O[q = qr][d = nd*16 + g*4 + r]. The online-softmax rescale
// and the final 1/l normalization become lane-local (no shuffles), and the z-store
// is 16 bh4 stores/thread (4 g-groups compose 32-B row segments) instead of 64
// scalar stores.
//   Ks: [key 0..31][256 d], granule G holds data granule G ^ kperm(key&7)
//   Vs: [d 0..255][32 key-slots] (slots PV-permuted at vT creation), G ^= (d>>1)&3
__global__ __launch_bounds__(256) void attn_k(
    const __hip_bfloat16* __restrict__ qkv, const __hip_bfloat16* __restrict__ vT,
    __hip_bfloat16* __restrict__ z) {
  __shared__ __hip_bfloat16 Ks[32 * 256];
  __shared__ __hip_bfloat16 Vs[256 * 32];
  const int tid = threadIdx.x;
  const int lane = tid & 63, w = tid >> 6;
  const int g = lane >> 4, qr = lane & 15;
  // XCD swizzle: nwg = 16*8*8 = 1024, chunk = 128 logical blocks per XCD
  const unsigned aid = (blockIdx.z * NH + blockIdx.y) * (SEQ / 64) + blockIdx.x;
  const unsigned lid = (aid & 7u) * 128u + (aid >> 3);
  const int qi = lid & 15, hh = (lid >> 4) & 7, b = lid >> 7;
  const int q0 = qi * 64 + w * 16;
  const size_t qkv_b = (size_t)b * SEQ * QKVW;

  // Q fragments: lane holds Q[q0+qr][kd*32 + g*8 .. +8]
  bh8 qf[8];
  {
    const __hip_bfloat16* qrow = qkv + qkv_b + (size_t)(q0 + qr) * QKVW + hh * 256 + g * 8;
#pragma unroll
    for (int kd = 0; kd < 8; kd++) qf[kd] = *(const bh8*)(qrow + kd * 32);
  }

  fx4 o[16];
#pragma unroll
  for (int i = 0; i < 16; i++) o[i] = 0.f;
  float m_run = -INFINITY, l_run = 0.f;        // m_run in RAW score units
  constexpr float cL = 0.0625f * 1.44269504f;  // scale * log2(e)

  const int ksw = kperm(qr & 7);          // Ks read swizzle (rows qr and 16+qr share it)
  const int vsw = ((qr >> 1) & 3);        // Vs read swizzle (d = nd*16+qr -> (d>>1)&3)

  for (int j0 = 0; j0 < SEQ; j0 += 32) {
    __syncthreads();
#pragma unroll
    for (int c = 0; c < 4; c++) {
      int idx = tid + c * 256;
      int key = idx >> 5, c16 = idx & 31;
      int dp = (c16 ^ kperm(key & 7)) << 3; // pre-swizzled source column (elements)
      g2l16(qkv + qkv_b + (size_t)(j0 + key) * QKVW + 2048 + hh * 256 + dp, (char*)Ks + idx * 16);
    }
    const __hip_bfloat16* vb = vT + ((size_t)(b * 8 + hh) * 256) * SEQ + j0;
#pragma unroll
    for (int c = 0; c < 4; c++) {
      int idx = tid + c * 256;
      int d = idx >> 2, gr = idx & 3;
      int np = (gr ^ ((d >> 1) & 3)) << 3; // pre-swizzled source slot (elements)
      g2l16(vb + (size_t)d * SEQ + np, (char*)Vs + idx * 16);
    }
    __syncthreads();

    // S^T = K * Q^T : lane holds S[q=qr][key = {g*4+r, 16+g*4+r}]  (raw scores)
    fx4 s0 = 0.f, s1 = 0.f;
#pragma unroll
    for (int kd = 0; kd < 8; kd++) {
      bh8 k0f = *(const bh8*)(Ks + (size_t)qr * 256 + (((kd * 4 + g) ^ ksw) << 3));
      bh8 k1f = *(const bh8*)(Ks + (size_t)(16 + qr) * 256 + (((kd * 4 + g) ^ ksw) << 3));
      s0 = mfma16(k0f, qf[kd], s0);
      s1 = mfma16(k1f, qf[kd], s1);
    }
    float sv[8];
#pragma unroll
    for (int r = 0; r < 4; r++) { sv[r] = s0[r]; sv[4 + r] = s1[r]; }
    float pmax = sv[0];
#pragma unroll
    for (int i = 1; i < 8; i++) pmax = fmaxf(pmax, sv[i]);
    pmax = fmaxf(pmax, __shfl_xor(pmax, 16));
    pmax = fmaxf(pmax, __shfl_xor(pmax, 32));
    // defer-max: rescale only if some row's max grew by > 128 raw (= 8 scaled)
    if (!__all(pmax <= m_run + 128.f)) {
      float m_new = fmaxf(m_run, pmax);
      float corr = __builtin_amdgcn_exp2f((m_run - m_new) * cL); // first tile: 0
      // swapped-O layout: every o[nd][r] has q = qr -> corr is lane-local
#pragma unroll
      for (int nd = 0; nd < 16; nd++) {
        o[nd][0] *= corr; o[nd][1] *= corr; o[nd][2] *= corr; o[nd][3] *= corr;
      }
      l_run *= corr;
      m_run = m_new;
    }
    float mL = m_run * cL;
    float p[8], ps = 0.f;
#pragma unroll
    for (int i = 0; i < 8; i++) {
      p[i] = __builtin_amdgcn_exp2f(fmaf(sv[i], cL, -mL)); // bounded by 2^8
      ps += p[i];
    }
    ps += __shfl_xor(ps, 16);
    ps += __shfl_xor(ps, 32);
    l_run += ps;
    // P -> bf16 A-frag with key(g,i) = g*4 + (i&3) + 16*(i>>2); Vs slots hold V in the
    // same key order. SWAPPED: mfma16(vf, pa) -> lane holds O[q=qr][d=nd*16+g*4+r].
    bh8 pa;
#pragma unroll
    for (int i = 0; i < 8; i++) pa[i] = f2bf(p[i]);
#pragma unroll
    for (int nd = 0; nd < 16; nd++) {
      int d = nd * 16 + qr;
      bh8 vf = *(const bh8*)(Vs + (size_t)d * 32 + ((g ^ vsw) << 3));
      o[nd] = mfma16(vf, pa, o[nd]);
    }
  }

  float inv = 1.f / l_run;   // q = qr: lane-local, no shuffles
  __hip_bfloat16* zb = z + (size_t)b * SEQ * INNERW + hh * 256 + (size_t)(q0 + qr) * INNERW;
#pragma unroll
  for (int nd = 0; nd < 16; nd++) {
    bh4 ov;
#pragma unroll
    for (int r = 0; r < 4; r++) ov[r] = f2bf(o[nd][r] * inv);
    *(bh4*)(zb + nd * 16 + g * 4) = ov;
  }
}

// ---------------- host ----------------
extern "C" void kernel_launch(void* const* d_in, const int* in_sizes, int n_in,
                              void* d_out, int out_size, void* d_ws, size_t ws_size,
                              hipStream_t stream) {
  const float* x_in  = (const float*)d_in[0];
  const float* ln1g  = (const float*)d_in[1];
  const float* ln1b  = (const float*)d_in[2];
  const float* w_qkv = (const float*)d_in[3];
  const float* w_out = (const float*)d_in[4];
  const float* b_out = (const float*)d_in[5];
  const float* ln2g  = (const float*)d_in[6];
  const float* ln2b  = (const float*)d_in[7];
  const float* w1    = (const float*)d_in[8];
  const float* b1    = (const float*)d_in[9];
  const float* w2    = (const float*)d_in[10];
  const float* b2    = (const float*)d_in[11];

  char* ws = (char*)d_ws;
  size_t off = 0;
  auto alloc = [&](size_t bytes) { char* p = ws + off; off += (bytes + 255) & ~(size_t)255; return p; };
  float*          xf    = (float*)         alloc((size_t)ROWS * DM * 4);
  __hip_bfloat16* h     = (__hip_bfloat16*)alloc((size_t)ROWS * DM * 2);
  __hip_bfloat16* qkv   = (__hip_bfloat16*)alloc((size_t)ROWS * QKVW * 2);
  __hip_bfloat16* vT    = (__hip_bfloat16*)alloc((size_t)NB * NH * 256 * SEQ * 2);
  __hip_bfloat16* zbuf  = (__hip_bfloat16*)alloc((size_t)ROWS * INNERW * 2);
  __hip_bfloat16* mh    = zbuf; // MLP hidden reuses z region (disjoint lifetimes)
  __hip_bfloat16* wqkvT = (__hip_bfloat16*)alloc((size_t)NLAYER * QKVW * DM * 2);
  __hip_bfloat16* woutT = (__hip_bfloat16*)alloc((size_t)NLAYER * DM * INNERW * 2);
  __hip_bfloat16* w1T   = (__hip_bfloat16*)alloc((size_t)NLAYER * MLPD * DM * 2);
  __hip_bfloat16* w2T   = (__hip_bfloat16*)alloc((size_t)NLAYER * DM * MLPD * 2);
  (void)ws_size; (void)in_sizes; (void)n_in; (void)out_size;

  // weight transposes+casts (weights constant across the launch)
  wtrans_k<<<dim3(QKVW / 32, DM / 32, NLAYER), dim3(32, 8), 0, stream>>>(
      w_qkv, wqkvT, DM, QKVW, (size_t)DM * QKVW, (size_t)DM * QKVW);
  wtrans_k<<<dim3(DM / 32, INNERW / 32, NLAYER), dim3(32, 8), 0, stream>>>(
      w_out, woutT, INNERW, DM, (size_t)INNERW * DM, (size_t)INNERW * DM);
  wtrans_k<<<dim3(MLPD / 32, DM / 32, NLAYER), dim3(32, 8), 0, stream>>>(
      w1, w1T, DM, MLPD, (size_t)DM * MLPD, (size_t)DM * MLPD);
  wtrans_k<<<dim3(DM / 32, MLPD / 32, NLAYER), dim3(32, 8), 0, stream>>>(
      w2, w2T, MLPD, DM, (size_t)MLPD * DM, (size_t)MLPD * DM);

  for (int i = 0; i < NLAYER; i++) {
    // layer 0 reads the residual stream from x_in directly (no initial copy)
    const float* xcur = (i == 0) ? x_in : xf;
    float* xnext_out = (i == NLAYER - 1) ? (float*)d_out : xf;

    ln_k<<<dim3(DM / 16, NB), 256, 0, stream>>>(xcur, ln1g + i * SEQ, ln1b + i * SEQ, h);
    // qkv GEMM with fused V-transpose epilogue (EPI 3) — vtrans kernel eliminated
    gemm_bt<128, 3><<<dim3(QKVW / 128, ROWS / 128), 256, 0, stream>>>(
        h, wqkvT + (size_t)i * QKVW * DM, qkv, nullptr, nullptr, nullptr, vT, ROWS, QKVW, DM);
    attn_k<<<dim3(SEQ / 64, NH, NB), 256, 0, stream>>>(qkv, vT, zbuf);
    // attn-out: resid-in = xcur (x_in for layer 0), resid-out = xf
    gemm_bt<64, 2><<<dim3(DM / 64, ROWS / 128), 256, 0, stream>>>(
        zbuf, woutT + (size_t)i * DM * INNERW, nullptr, b_out + i * DM, xcur, xf, nullptr,
        ROWS, DM, INNERW);
    ln_k<<<dim3(DM / 16, NB), 256, 0, stream>>>(xf, ln2g + i * SEQ, ln2b + i * SEQ, h);
    gemm_bt<128, 1><<<dim3(MLPD / 128, ROWS / 128), 256, 0, stream>>>(
        h, w1T + (size_t)i * MLPD * DM, mh, b1 + i * MLPD, nullptr, nullptr, nullptr,
        ROWS, MLPD, DM);
    // mlp2: resid-in = xf, resid-out = d_out on the last layer (no final copy)
    gemm_bt<64, 2><<<dim3(DM / 64, ROWS / 128), 256, 0, stream>>>(
        mh, w2T + (size_t)i * DM * MLPD, nullptr, b2 + i * DM, xf, xnext_out, nullptr,
        ROWS, DM, MLPD);
  }
}

// Round 14
// 979.654 us; speedup vs baseline: 1.1948x; 1.0388x over previous
//
#include <hip/hip_runtime.h>
#include <hip/hip_bf16.h>

#define SEQ    1024
#define DM     256
#define NH     8
#define NB     8
#define NLAYER 4
#define MLPD   1024
#define ROWS   (NB*SEQ)      // 8192
#define QKVW   6144          // 3*NH*DM
#define INNERW 2048          // NH*DM

typedef __attribute__((ext_vector_type(8))) short bh8;
typedef __attribute__((ext_vector_type(4))) short bh4;
typedef __attribute__((ext_vector_type(4))) float fx4;

__device__ __forceinline__ short f2bf(float f) {
  return __builtin_bit_cast(short, __float2bfloat16(f));
}
__device__ __forceinline__ fx4 mfma16(bh8 a, bh8 b, fx4 c) {
  return __builtin_amdgcn_mfma_f32_16x16x32_bf16(a, b, c, 0, 0, 0);
}
__device__ __forceinline__ void g2l16(const void* g, void* l) {
  __builtin_amdgcn_global_load_lds(
      (const __attribute__((address_space(1))) void*)g,
      (__attribute__((address_space(3))) void*)l, 16, 0, 0);
}
__device__ __forceinline__ int kperm(int r) {
  return ((r & 1) << 2) | ((r >> 1) & 3);
}

// ---------------- f32 -> bf16 transpose (per-layer via blockIdx.z) ----------------
// src: [R][C] f32 (row stride C), dst: [C][R] bf16
__global__ void wtrans_k(const float* __restrict__ src, __hip_bfloat16* __restrict__ dst,
                         int R, int C, size_t sls, size_t dls) {
  src += (size_t)blockIdx.z * sls;
  dst += (size_t)blockIdx.z * dls;
  __shared__ float t[32][33];
  int tx = threadIdx.x, ty = threadIdx.y;
  int r0 = blockIdx.y * 32, c0 = blockIdx.x * 32;
#pragma unroll
  for (int i = 0; i < 32; i += 8) t[ty + i][tx] = src[(size_t)(r0 + ty + i) * C + c0 + tx];
  __syncthreads();
#pragma unroll
  for (int i = 0; i < 32; i += 8)
    dst[(size_t)(c0 + ty + i) * R + r0 + tx] = __float2bfloat16(t[tx][ty + i]);
}

// ---------------- LayerNorm over axis=1 (sequence), per-(b,d) stats ----------------
// grid (DM/16, NB) = 128 blocks, block 256. fx4 loads, bh4 stores.
__global__ void ln_k(const float* __restrict__ xf, const float* __restrict__ gam,
                     const float* __restrict__ bet, __hip_bfloat16* __restrict__ h) {
  int b = blockIdx.y, d0 = blockIdx.x * 16;
  int dl = threadIdx.x & 3;          // fx4 column: d = d0 + dl*4 .. +3
  int nt = threadIdx.x >> 2;         // 0..63, rows stride 64
  const float* xb = xf + (size_t)b * SEQ * DM + d0 + dl * 4;
  fx4 s = 0.f, ss = 0.f;
  for (int n = nt; n < SEQ; n += 64) {
    fx4 v = *(const fx4*)(xb + (size_t)n * DM);
    s += v; ss += v * v;
  }
  __shared__ fx4 S1[64][4], S2[64][4];
  __shared__ fx4 MU[4], RS[4];
  S1[nt][dl] = s; S2[nt][dl] = ss;
  __syncthreads();
  if (nt == 0) {
    fx4 a = 0.f, c = 0.f;
#pragma unroll
    for (int i = 0; i < 64; i++) { a += S1[i][dl]; c += S2[i][dl]; }
    fx4 mu, rs;
#pragma unroll
    for (int r = 0; r < 4; r++) {
      mu[r] = a[r] * (1.f / SEQ);
      float var = c[r] * (1.f / SEQ) - mu[r] * mu[r];
      rs[r] = rsqrtf(var + 1e-3f);
    }
    MU[dl] = mu; RS[dl] = rs;
  }
  __syncthreads();
  fx4 mu = MU[dl], rs = RS[dl];
  __hip_bfloat16* hb = h + (size_t)b * SEQ * DM + d0 + dl * 4;
  for (int n = nt; n < SEQ; n += 64) {
    fx4 v = *(const fx4*)(xb + (size_t)n * DM);
    float gn = gam[n], bn = bet[n];
    bh4 o;
#pragma unroll
    for (int r = 0; r < 4; r++) o[r] = f2bf((v[r] - mu[r]) * rs[r] * gn + bn);
    *(bh4*)(hb + (size_t)n * DM) = o;
  }
}

// ---------------- GEMM: C[M,Nc] = A[M,K] * Bt[Nc,K]^T  (+ epilogues) ----------------
// BK=64, kperm-swizzled LDS staging, XCD-aware bijective block swizzle.
// BM templated: EPI2 (skinny-N residual GEMMs) use BM=64 so grid = 512 blocks
// (2 blocks/CU, 8 waves/CU) instead of 256 (1 block/CU) — doubles the TLP that
// hides the stage->drain stall (same mechanism that favors 4 blocks/CU in attn).
// EPI 0: bf16 stores   EPI 1: +bias, exact GELU   EPI 2: rout = rin + acc + bias
// EPI 3 (qkv, BM=128): V third stored TRANSPOSED into vT via padded-LDS round-trip.
template <int BM, int BN, int EPI>
__global__ __launch_bounds__(256) void gemm_bt(
    const __hip_bfloat16* __restrict__ A, const __hip_bfloat16* __restrict__ Bt,
    __hip_bfloat16* __restrict__ Cout, const float* __restrict__ bias,
    const float* __restrict__ rin, float* __restrict__ rout,
    __hip_bfloat16* __restrict__ vT, int M, int Nc, int K) {
  constexpr int BK = 64;
  constexpr int NR = BN / 32;
  constexpr int MR = BM / 32;
  static_assert(BN == 64 || BN == 128, "");
  static_assert(BM == 64 || BM == 128, "");
  constexpr int LDSE = (EPI == 3) ? 128 * 132 : (BM + BN) * BK;
  __shared__ __hip_bfloat16 smem[LDSE];
  __hip_bfloat16* As = smem;
  __hip_bfloat16* Bs = smem + BM * BK;
  const int tid = threadIdx.x;
  const int lane = tid & 63, w = tid >> 6;
  const int g = lane >> 4, qr = lane & 15;
  const int wr = w >> 1, wc = w & 1;
  // XCD swizzle: apparent id -> logical id so each XCD gets a contiguous chunk
  const unsigned aid = blockIdx.y * gridDim.x + blockIdx.x;
  const unsigned nwg = gridDim.x * gridDim.y;
  const unsigned lid = (aid & 7u) * (nwg >> 3) + (aid >> 3);
  const int m0 = (int)(lid / gridDim.x) * BM, n0 = (int)(lid % gridDim.x) * BN;
  const int swr = kperm(qr & 7);

  fx4 acc[MR][NR];
#pragma unroll
  for (int m = 0; m < MR; m++)
#pragma unroll
    for (int n = 0; n < NR; n++) acc[m][n] = 0.f;

  constexpr int ACH = (BM * BK) / (8 * 256); // 4 or 2
  constexpr int BCH = (BN * BK) / (8 * 256); // 4 or 2

  for (int k0 = 0; k0 < K; k0 += BK) {
    __syncthreads();
#pragma unroll
    for (int c = 0; c < ACH; c++) {
      int idx = tid + c * 256;
      int row = idx >> 3, gr2 = idx & 7;
      g2l16(A + (size_t)(m0 + row) * K + k0 + ((gr2 ^ kperm(row & 7)) << 3), (char*)As + idx * 16);
    }
#pragma unroll
    for (int c = 0; c < BCH; c++) {
      int idx = tid + c * 256;
      int col = idx >> 3, gr2 = idx & 7;
      g2l16(Bt + (size_t)(n0 + col) * K + k0 + ((gr2 ^ kperm(col & 7)) << 3), (char*)Bs + idx * 16);
    }
    __syncthreads();
#pragma unroll
    for (int ks = 0; ks < 2; ks++) {
      bh8 af[MR], bf[NR];
#pragma unroll
      for (int m = 0; m < MR; m++)
        af[m] = *(const bh8*)(As + (wr * (BM / 2) + m * 16 + qr) * BK + (((ks * 4 + g) ^ swr) << 3));
#pragma unroll
      for (int n = 0; n < NR; n++)
        bf[n] = *(const bh8*)(Bs + (wc * (BN / 2) + n * 16 + qr) * BK + (((ks * 4 + g) ^ swr) << 3));
#pragma unroll
      for (int m = 0; m < MR; m++)
#pragma unroll
        for (int n = 0; n < NR; n++) acc[m][n] = mfma16(af[m], bf[n], acc[m][n]);
    }
  }

  // acc[m][n][r] = C[m0 + wr*(BM/2) + m*16 + g*4 + r][n0 + wc*(BN/2) + n*16 + qr]
  if constexpr (EPI == 2) {
#pragma unroll
    for (int n = 0; n < NR; n++) {
      int gc = n0 + wc * (BN / 2) + n * 16 + qr;
      float bv = bias[gc];
#pragma unroll
      for (int m = 0; m < MR; m++) {
        int grb = m0 + wr * (BM / 2) + m * 16 + g * 4;
#pragma unroll
        for (int r = 0; r < 4; r++)
          rout[(size_t)(grb + r) * Nc + gc] = rin[(size_t)(grb + r) * Nc + gc] + acc[m][n][r] + bv;
      }
    }
  } else if (EPI == 3 && n0 >= 4096) {
    // ---- V third: transposed store into vT via padded-LDS round-trip (BM=128) ----
    __syncthreads();                       // all waves done with As/Bs
    __hip_bfloat16* Cs = smem;             // [128 d][132 nn-padded]
#pragma unroll
    for (int n = 0; n < NR; n++) {
      int dl = wc * (BN / 2) + n * 16 + qr;
#pragma unroll
      for (int m = 0; m < MR; m++) {
        // permuted nn base: slot applied within each 32-row group
        int nlp = wr * (BM / 2) + (m >> 1) * 32 + g * 8 + (m & 1) * 4;
        bh4 v;
#pragma unroll
        for (int r = 0; r < 4; r++) v[r] = f2bf(acc[m][n][r]);
        *(bh4*)(Cs + dl * 132 + nlp) = v;
      }
    }
    __syncthreads();
    const int dl = tid >> 1, half = tid & 1;
    const int bb = m0 >> 10;
    const int hh = (n0 - 4096) >> 8;
    const int d0v = (n0 - 4096) & 255;
    __hip_bfloat16* dst =
        vT + ((size_t)(bb * 8 + hh) * 256 + d0v + dl) * SEQ + (m0 & 1023) + half * 64;
#pragma unroll
    for (int j = 0; j < 8; j++)
      *(bh8*)(dst + j * 8) = *(const bh8*)(Cs + dl * 132 + half * 64 + j * 8);
  } else {
#pragma unroll
    for (int n = 0; n < NR; n++) {
      int gc = n0 + wc * (BN / 2) + n * 16 + qr;
      float bv = (EPI == 1) ? bias[gc] : 0.f;
#pragma unroll
      for (int m = 0; m < MR; m++) {
        int grb = m0 + wr * (BM / 2) + m * 16 + g * 4;
#pragma unroll
        for (int r = 0; r < 4; r++) {
          float v = acc[m][n][r];
          if (EPI == 1) {
            v += bv;
            v = 0.5f * v * (1.f + erff(v * 0.70710678118654752f));
          }
          Cout[(size_t)(grb + r) * Nc + gc] = __float2bfloat16(v);
        }
      }
    }
  }
}

// ---------------- Flash attention: grid (SEQ/64, NH, NB), 4 waves x 16 q-rows ----------------
// R13 config: single-buffered Ks/Vs, 256 threads, 4 blocks/CU, XCD bijective swizzle,
// kperm K-granules, defer-max + exp2 softmax, SWAPPED PV (lane-local rescale,
// bh4 z-stores).
//   Ks: [key 0..31][256 d], granule G holds data granule G ^ kperm(key&7)
//   Vs: [d 0..255][32 key-slots] (slots PV-permuted at vT creation), G ^= (d>>1)&3
__global__ __launch_bounds__(256) void attn_k(
    const __hip_bfloat16* __restrict__ qkv, const __hip_bfloat16* __restrict__ vT,
    __hip_bfloat16* __restrict__ z) {
  __shared__ __hip_bfloat16 Ks[32 * 256];
  __shared__ __hip_bfloat16 Vs[256 * 32];
  const int tid = threadIdx.x;
  const int lane = tid & 63, w = tid >> 6;
  const int g = lane >> 4, qr = lane & 15;
  // XCD swizzle: nwg = 16*8*8 = 1024, chunk = 128 logical blocks per XCD
  const unsigned aid = (blockIdx.z * NH + blockIdx.y) * (SEQ / 64) + blockIdx.x;
  const unsigned lid = (aid & 7u) * 128u + (aid >> 3);
  const int qi = lid & 15, hh = (lid >> 4) & 7, b = lid >> 7;
  const int q0 = qi * 64 + w * 16;
  const size_t qkv_b = (size_t)b * SEQ * QKVW;

  // Q fragments: lane holds Q[q0+qr][kd*32 + g*8 .. +8]
  bh8 qf[8];
  {
    const __hip_bfloat16* qrow = qkv + qkv_b + (size_t)(q0 + qr) * QKVW + hh * 256 + g * 8;
#pragma unroll
    for (int kd = 0; kd < 8; kd++) qf[kd] = *(const bh8*)(qrow + kd * 32);
  }

  fx4 o[16];
#pragma unroll
  for (int i = 0; i < 16; i++) o[i] = 0.f;
  float m_run = -INFINITY, l_run = 0.f;        // m_run in RAW score units
  constexpr float cL = 0.0625f * 1.44269504f;  // scale * log2(e)

  const int ksw = kperm(qr & 7);          // Ks read swizzle (rows qr and 16+qr share it)
  const int vsw = ((qr >> 1) & 3);        // Vs read swizzle (d = nd*16+qr -> (d>>1)&3)

  for (int j0 = 0; j0 < SEQ; j0 += 32) {
    __syncthreads();
#pragma unroll
    for (int c = 0; c < 4; c++) {
      int idx = tid + c * 256;
      int key = idx >> 5, c16 = idx & 31;
      int dp = (c16 ^ kperm(key & 7)) << 3; // pre-swizzled source column (elements)
      g2l16(qkv + qkv_b + (size_t)(j0 + key) * QKVW + 2048 + hh * 256 + dp, (char*)Ks + idx * 16);
    }
    const __hip_bfloat16* vb = vT + ((size_t)(b * 8 + hh) * 256) * SEQ + j0;
#pragma unroll
    for (int c = 0; c < 4; c++) {
      int idx = tid + c * 256;
      int d = idx >> 2, gr = idx & 3;
      int np = (gr ^ ((d >> 1) & 3)) << 3; // pre-swizzled source slot (elements)
      g2l16(vb + (size_t)d * SEQ + np, (char*)Vs + idx * 16);
    }
    __syncthreads();

    // S^T = K * Q^T : lane holds S[q=qr][key = {g*4+r, 16+g*4+r}]  (raw scores)
    fx4 s0 = 0.f, s1 = 0.f;
#pragma unroll
    for (int kd = 0; kd < 8; kd++) {
      bh8 k0f = *(const bh8*)(Ks + (size_t)qr * 256 + (((kd * 4 + g) ^ ksw) << 3));
      bh8 k1f = *(const bh8*)(Ks + (size_t)(16 + qr) * 256 + (((kd * 4 + g) ^ ksw) << 3));
      s0 = mfma16(k0f, qf[kd], s0);
      s1 = mfma16(k1f, qf[kd], s1);
    }
    float sv[8];
#pragma unroll
    for (int r = 0; r < 4; r++) { sv[r] = s0[r]; sv[4 + r] = s1[r]; }
    float pmax = sv[0];
#pragma unroll
    for (int i = 1; i < 8; i++) pmax = fmaxf(pmax, sv[i]);
    pmax = fmaxf(pmax, __shfl_xor(pmax, 16));
    pmax = fmaxf(pmax, __shfl_xor(pmax, 32));
    // defer-max: rescale only if some row's max grew by > 128 raw (= 8 scaled)
    if (!__all(pmax <= m_run + 128.f)) {
      float m_new = fmaxf(m_run, pmax);
      float corr = __builtin_amdgcn_exp2f((m_run - m_new) * cL); // first tile: 0
      // swapped-O layout: every o[nd][r] has q = qr -> corr is lane-local
#pragma unroll
      for (int nd = 0; nd < 16; nd++) {
        o[nd][0] *= corr; o[nd][1] *= corr; o[nd][2] *= corr; o[nd][3] *= corr;
      }
      l_run *= corr;
      m_run = m_new;
    }
    float mL = m_run * cL;
    float p[8], ps = 0.f;
#pragma unroll
    for (int i = 0; i < 8; i++) {
      p[i] = __builtin_amdgcn_exp2f(fmaf(sv[i], cL, -mL)); // bounded by 2^8
      ps += p[i];
    }
    ps += __shfl_xor(ps, 16);
    ps += __shfl_xor(ps, 32);
    l_run += ps;
    // P -> bf16 A-frag with key(g,i) = g*4 + (i&3) + 16*(i>>2); Vs slots hold V in the
    // same key order. SWAPPED: mfma16(vf, pa) -> lane holds O[q=qr][d=nd*16+g*4+r].
    bh8 pa;
#pragma unroll
    for (int i = 0; i < 8; i++) pa[i] = f2bf(p[i]);
#pragma unroll
    for (int nd = 0; nd < 16; nd++) {
      int d = nd * 16 + qr;
      bh8 vf = *(const bh8*)(Vs + (size_t)d * 32 + ((g ^ vsw) << 3));
      o[nd] = mfma16(vf, pa, o[nd]);
    }
  }

  float inv = 1.f / l_run;   // q = qr: lane-local, no shuffles
  __hip_bfloat16* zb = z + (size_t)b * SEQ * INNERW + hh * 256 + (size_t)(q0 + qr) * INNERW;
#pragma unroll
  for (int nd = 0; nd < 16; nd++) {
    bh4 ov;
#pragma unroll
    for (int r = 0; r < 4; r++) ov[r] = f2bf(o[nd][r] * inv);
    *(bh4*)(zb + nd * 16 + g * 4) = ov;
  }
}

// ---------------- host ----------------
extern "C" void kernel_launch(void* const* d_in, const int* in_sizes, int n_in,
                              void* d_out, int out_size, void* d_ws, size_t ws_size,
                              hipStream_t stream) {
  const float* x_in  = (const float*)d_in[0];
  const float* ln1g  = (const float*)d_in[1];
  const float* ln1b  = (const float*)d_in[2];
  const float* w_qkv = (const float*)d_in[3];
  const float* w_out = (const float*)d_in[4];
  const float* b_out = (const float*)d_in[5];
  const float* ln2g  = (const float*)d_in[6];
  const float* ln2b  = (const float*)d_in[7];
  const float* w1    = (const float*)d_in[8];
  const float* b1    = (const float*)d_in[9];
  const float* w2    = (const float*)d_in[10];
  const float* b2    = (const float*)d_in[11];

  char* ws = (char*)d_ws;
  size_t off = 0;
  auto alloc = [&](size_t bytes) { char* p = ws + off; off += (bytes + 255) & ~(size_t)255; return p; };
  float*          xf    = (float*)         alloc((size_t)ROWS * DM * 4);
  __hip_bfloat16* h     = (__hip_bfloat16*)alloc((size_t)ROWS * DM * 2);
  __hip_bfloat16* qkv   = (__hip_bfloat16*)alloc((size_t)ROWS * QKVW * 2);
  __hip_bfloat16* vT    = (__hip_bfloat16*)alloc((size_t)NB * NH * 256 * SEQ * 2);
  __hip_bfloat16* zbuf  = (__hip_bfloat16*)alloc((size_t)ROWS * INNERW * 2);
  __hip_bfloat16* mh    = zbuf; // MLP hidden reuses z region (disjoint lifetimes)
  __hip_bfloat16* wqkvT = (__hip_bfloat16*)alloc((size_t)NLAYER * QKVW * DM * 2);
  __hip_bfloat16* woutT = (__hip_bfloat16*)alloc((size_t)NLAYER * DM * INNERW * 2);
  __hip_bfloat16* w1T   = (__hip_bfloat16*)alloc((size_t)NLAYER * MLPD * DM * 2);
  __hip_bfloat16* w2T   = (__hip_bfloat16*)alloc((size_t)NLAYER * DM * MLPD * 2);
  (void)ws_size; (void)in_sizes; (void)n_in; (void)out_size;

  // weight transposes+casts (weights constant across the launch)
  wtrans_k<<<dim3(QKVW / 32, DM / 32, NLAYER), dim3(32, 8), 0, stream>>>(
      w_qkv, wqkvT, DM, QKVW, (size_t)DM * QKVW, (size_t)DM * QKVW);
  wtrans_k<<<dim3(DM / 32, INNERW / 32, NLAYER), dim3(32, 8), 0, stream>>>(
      w_out, woutT, INNERW, DM, (size_t)INNERW * DM, (size_t)INNERW * DM);
  wtrans_k<<<dim3(MLPD / 32, DM / 32, NLAYER), dim3(32, 8), 0, stream>>>(
      w1, w1T, DM, MLPD, (size_t)DM * MLPD, (size_t)DM * MLPD);
  wtrans_k<<<dim3(DM / 32, MLPD / 32, NLAYER), dim3(32, 8), 0, stream>>>(
      w2, w2T, MLPD, DM, (size_t)MLPD * DM, (size_t)MLPD * DM);

  for (int i = 0; i < NLAYER; i++) {
    // layer 0 reads the residual stream from x_in directly (no initial copy)
    const float* xcur = (i == 0) ? x_in : xf;
    float* xnext_out = (i == NLAYER - 1) ? (float*)d_out : xf;

    ln_k<<<dim3(DM / 16, NB), 256, 0, stream>>>(xcur, ln1g + i * SEQ, ln1b + i * SEQ, h);
    // qkv GEMM with fused V-transpose epilogue (EPI 3) — vtrans kernel eliminated
    gemm_bt<128, 128, 3><<<dim3(QKVW / 128, ROWS / 128), 256, 0, stream>>>(
        h, wqkvT + (size_t)i * QKVW * DM, qkv, nullptr, nullptr, nullptr, vT, ROWS, QKVW, DM);
    attn_k<<<dim3(SEQ / 64, NH, NB), 256, 0, stream>>>(qkv, vT, zbuf);
    // attn-out: BM=64 -> 512 blocks (2/CU); resid-in = xcur, resid-out = xf
    gemm_bt<64, 64, 2><<<dim3(DM / 64, ROWS / 64), 256, 0, stream>>>(
        zbuf, woutT + (size_t)i * DM * INNERW, nullptr, b_out + i * DM, xcur, xf, nullptr,
        ROWS, DM, INNERW);
    ln_k<<<dim3(DM / 16, NB), 256, 0, stream>>>(xf, ln2g + i * SEQ, ln2b + i * SEQ, h);
    gemm_bt<128, 128, 1><<<dim3(MLPD / 128, ROWS / 128), 256, 0, stream>>>(
        h, w1T + (size_t)i * MLPD * DM, mh, b1 + i * MLPD, nullptr, nullptr, nullptr,
        ROWS, MLPD, DM);
    // mlp2: BM=64 -> 512 blocks (2/CU); resid-in = xf, resid-out = d_out on last layer
    gemm_bt<64, 64, 2><<<dim3(DM / 64, ROWS / 64), 256, 0, stream>>>(
        mh, w2T + (size_t)i * DM * MLPD, nullptr, b2 + i * DM, xf, xnext_out, nullptr,
        ROWS, DM, MLPD);
  }
}

// Round 15
// 961.373 us; speedup vs baseline: 1.2175x; 1.0190x over previous
//
#include <hip/hip_runtime.h>
#include <hip/hip_bf16.h>

#define SEQ    1024
#define DM     256
#define NH     8
#define NB     8
#define NLAYER 4
#define MLPD   1024
#define ROWS   (NB*SEQ)      // 8192
#define QKVW   6144          // 3*NH*DM
#define INNERW 2048          // NH*DM

typedef __attribute__((ext_vector_type(8))) short bh8;
typedef __attribute__((ext_vector_type(4))) short bh4;
typedef __attribute__((ext_vector_type(4))) float fx4;

__device__ __forceinline__ short f2bf(float f) {
  return __builtin_bit_cast(short, __float2bfloat16(f));
}
__device__ __forceinline__ fx4 mfma16(bh8 a, bh8 b, fx4 c) {
  return __builtin_amdgcn_mfma_f32_16x16x32_bf16(a, b, c, 0, 0, 0);
}
__device__ __forceinline__ void g2l16(const void* g, void* l) {
  __builtin_amdgcn_global_load_lds(
      (const __attribute__((address_space(1))) void*)g,
      (__attribute__((address_space(3))) void*)l, 16, 0, 0);
}
__device__ __forceinline__ int kperm(int r) {
  return ((r & 1) << 2) | ((r >> 1) & 3);
}

// ---------------- f32 -> bf16 transpose (per-layer via blockIdx.z) ----------------
// src: [R][C] f32 (row stride C), dst: [C][R] bf16
__global__ void wtrans_k(const float* __restrict__ src, __hip_bfloat16* __restrict__ dst,
                         int R, int C, size_t sls, size_t dls) {
  src += (size_t)blockIdx.z * sls;
  dst += (size_t)blockIdx.z * dls;
  __shared__ float t[32][33];
  int tx = threadIdx.x, ty = threadIdx.y;
  int r0 = blockIdx.y * 32, c0 = blockIdx.x * 32;
#pragma unroll
  for (int i = 0; i < 32; i += 8) t[ty + i][tx] = src[(size_t)(r0 + ty + i) * C + c0 + tx];
  __syncthreads();
#pragma unroll
  for (int i = 0; i < 32; i += 8)
    dst[(size_t)(c0 + ty + i) * R + r0 + tx] = __float2bfloat16(t[tx][ty + i]);
}

// ---------------- LayerNorm over axis=1 (sequence), per-(b,d) stats ----------------
// grid (DM/8, NB) = 256 blocks (full chip), block 256. fx4 loads, bh4 stores.
// Two-stage LDS reduction of the per-column sums.
__global__ void ln_k(const float* __restrict__ xf, const float* __restrict__ gam,
                     const float* __restrict__ bet, __hip_bfloat16* __restrict__ h) {
  int b = blockIdx.y, d0 = blockIdx.x * 8;
  int dl = threadIdx.x & 1;          // fx4 column: d = d0 + dl*4 .. +3
  int nt = threadIdx.x >> 1;         // 0..127, rows stride 128
  const float* xb = xf + (size_t)b * SEQ * DM + d0 + dl * 4;
  fx4 s = 0.f, ss = 0.f;
  for (int n = nt; n < SEQ; n += 128) {
    fx4 v = *(const fx4*)(xb + (size_t)n * DM);
    s += v; ss += v * v;
  }
  __shared__ fx4 S1[128][2], S2[128][2];
  __shared__ fx4 MU[2], RS[2];
  S1[nt][dl] = s; S2[nt][dl] = ss;
  __syncthreads();
  if (nt < 16) {
    fx4 a = S1[nt][dl], c = S2[nt][dl];
#pragma unroll
    for (int i = 0; i < 7; i++) { a += S1[nt + 16 + i * 16][dl]; c += S2[nt + 16 + i * 16][dl]; }
    S1[nt][dl] = a; S2[nt][dl] = c;
  }
  __syncthreads();
  if (nt == 0) {
    fx4 a = 0.f, c = 0.f;
#pragma unroll
    for (int i = 0; i < 16; i++) { a += S1[i][dl]; c += S2[i][dl]; }
    fx4 mu, rs;
#pragma unroll
    for (int r = 0; r < 4; r++) {
      mu[r] = a[r] * (1.f / SEQ);
      float var = c[r] * (1.f / SEQ) - mu[r] * mu[r];
      rs[r] = rsqrtf(var + 1e-3f);
    }
    MU[dl] = mu; RS[dl] = rs;
  }
  __syncthreads();
  fx4 mu = MU[dl], rs = RS[dl];
  __hip_bfloat16* hb = h + (size_t)b * SEQ * DM + d0 + dl * 4;
  for (int n = nt; n < SEQ; n += 128) {
    fx4 v = *(const fx4*)(xb + (size_t)n * DM);
    float gn = gam[n], bn = bet[n];
    bh4 o;
#pragma unroll
    for (int r = 0; r < 4; r++) o[r] = f2bf((v[r] - mu[r]) * rs[r] * gn + bn);
    *(bh4*)(hb + (size_t)n * DM) = o;
  }
}

// ---------------- GEMM: C[M,Nc] = A[M,K] * Bt[Nc,K]^T  (+ epilogues) ----------------
// BK=64, kperm-swizzled LDS staging, XCD-aware bijective block swizzle.
// DBUF=1 (EPI1/EPI2): double-buffered LDS, stage(t+1) issued BEFORE compute(t),
//   ONE barrier per k-iter — the barrier's implicit vmcnt(0) drain of the staging
//   loads sits after a full compute phase and is hidden (R7-attn mechanism).
//   Occupancy-neutral: EPI2 kernels are grid-limited at 2 blocks/CU; mlp1 at
//   BM=64 dbuf (48 KB) gets 3 blocks/CU vs 2 (grid) before.
// DBUF=0 (EPI3 qkv): single-buffered (dbuf would halve its 4 blocks/CU — R2 lesson).
// EPI 0: bf16 stores   EPI 1: +bias, exact GELU   EPI 2: rout = rin + acc + bias
// EPI 3 (qkv, BM=128): V third stored TRANSPOSED into vT via padded-LDS round-trip.
template <int BM, int BN, int EPI, int DBUF>
__global__ __launch_bounds__(256) void gemm_bt(
    const __hip_bfloat16* __restrict__ A, const __hip_bfloat16* __restrict__ Bt,
    __hip_bfloat16* __restrict__ Cout, const float* __restrict__ bias,
    const float* __restrict__ rin, float* __restrict__ rout,
    __hip_bfloat16* __restrict__ vT, int M, int Nc, int K) {
  constexpr int BK = 64;
  constexpr int NR = BN / 32;
  constexpr int MR = BM / 32;
  constexpr int SPAN = (BM + BN) * BK;
  static_assert(BN == 64 || BN == 128, "");
  static_assert(BM == 64 || BM == 128, "");
  constexpr int LDSE = (EPI == 3) ? 128 * 132 : SPAN * (DBUF ? 2 : 1);
  __shared__ __hip_bfloat16 smem[LDSE];
  const int tid = threadIdx.x;
  const int lane = tid & 63, w = tid >> 6;
  const int g = lane >> 4, qr = lane & 15;
  const int wr = w >> 1, wc = w & 1;
  // XCD swizzle: apparent id -> logical id so each XCD gets a contiguous chunk
  const unsigned aid = blockIdx.y * gridDim.x + blockIdx.x;
  const unsigned nwg = gridDim.x * gridDim.y;
  const unsigned lid = (aid & 7u) * (nwg >> 3) + (aid >> 3);
  const int m0 = (int)(lid / gridDim.x) * BM, n0 = (int)(lid % gridDim.x) * BN;
  const int swr = kperm(qr & 7);

  fx4 acc[MR][NR];
#pragma unroll
  for (int m = 0; m < MR; m++)
#pragma unroll
    for (int n = 0; n < NR; n++) acc[m][n] = 0.f;

  constexpr int ACH = (BM * BK) / (8 * 256); // 4 or 2
  constexpr int BCH = (BN * BK) / (8 * 256); // 4 or 2

  auto stage = [&](int buf, int k0) {
    __hip_bfloat16* As_ = smem + buf * SPAN;
    __hip_bfloat16* Bs_ = As_ + BM * BK;
#pragma unroll
    for (int c = 0; c < ACH; c++) {
      int idx = tid + c * 256;
      int row = idx >> 3, gr2 = idx & 7;
      g2l16(A + (size_t)(m0 + row) * K + k0 + ((gr2 ^ kperm(row & 7)) << 3), (char*)As_ + idx * 16);
    }
#pragma unroll
    for (int c = 0; c < BCH; c++) {
      int idx = tid + c * 256;
      int col = idx >> 3, gr2 = idx & 7;
      g2l16(Bt + (size_t)(n0 + col) * K + k0 + ((gr2 ^ kperm(col & 7)) << 3), (char*)Bs_ + idx * 16);
    }
  };
  auto comp = [&](const __hip_bfloat16* As_, const __hip_bfloat16* Bs_) {
#pragma unroll
    for (int ks = 0; ks < 2; ks++) {
      bh8 af[MR], bf[NR];
#pragma unroll
      for (int m = 0; m < MR; m++)
        af[m] = *(const bh8*)(As_ + (wr * (BM / 2) + m * 16 + qr) * BK + (((ks * 4 + g) ^ swr) << 3));
#pragma unroll
      for (int n = 0; n < NR; n++)
        bf[n] = *(const bh8*)(Bs_ + (wc * (BN / 2) + n * 16 + qr) * BK + (((ks * 4 + g) ^ swr) << 3));
#pragma unroll
      for (int m = 0; m < MR; m++)
#pragma unroll
        for (int n = 0; n < NR; n++) acc[m][n] = mfma16(af[m], bf[n], acc[m][n]);
    }
  };

  if constexpr (DBUF) {
    stage(0, 0);
    __syncthreads();                 // drains initial stage
    const int NT = K / BK;
    for (int t = 0; t < NT; ++t) {
      const int cur = t & 1;
      if (t + 1 < NT) stage(cur ^ 1, (t + 1) * BK);   // issued BEFORE compute
      comp(smem + cur * SPAN, smem + cur * SPAN + BM * BK);
      __syncthreads();               // drain (hidden by compute) + buffer-reuse guard
    }
  } else {
    for (int k0 = 0; k0 < K; k0 += BK) {
      __syncthreads();
      stage(0, k0);
      __syncthreads();
      comp(smem, smem + BM * BK);
    }
  }

  // acc[m][n][r] = C[m0 + wr*(BM/2) + m*16 + g*4 + r][n0 + wc*(BN/2) + n*16 + qr]
  if constexpr (EPI == 2) {
#pragma unroll
    for (int n = 0; n < NR; n++) {
      int gc = n0 + wc * (BN / 2) + n * 16 + qr;
      float bv = bias[gc];
#pragma unroll
      for (int m = 0; m < MR; m++) {
        int grb = m0 + wr * (BM / 2) + m * 16 + g * 4;
#pragma unroll
        for (int r = 0; r < 4; r++)
          rout[(size_t)(grb + r) * Nc + gc] = rin[(size_t)(grb + r) * Nc + gc] + acc[m][n][r] + bv;
      }
    }
  } else if (EPI == 3 && n0 >= 4096) {
    // ---- V third: transposed store into vT via padded-LDS round-trip (BM=128) ----
    __syncthreads();                       // all waves done with As/Bs
    __hip_bfloat16* Cs = smem;             // [128 d][132 nn-padded]
#pragma unroll
    for (int n = 0; n < NR; n++) {
      int dl = wc * (BN / 2) + n * 16 + qr;
#pragma unroll
      for (int m = 0; m < MR; m++) {
        // permuted nn base: slot applied within each 32-row group
        int nlp = wr * (BM / 2) + (m >> 1) * 32 + g * 8 + (m & 1) * 4;
        bh4 v;
#pragma unroll
        for (int r = 0; r < 4; r++) v[r] = f2bf(acc[m][n][r]);
        *(bh4*)(Cs + dl * 132 + nlp) = v;
      }
    }
    __syncthreads();
    const int dl = tid >> 1, half = tid & 1;
    const int bb = m0 >> 10;
    const int hh = (n0 - 4096) >> 8;
    const int d0v = (n0 - 4096) & 255;
    __hip_bfloat16* dst =
        vT + ((size_t)(bb * 8 + hh) * 256 + d0v + dl) * SEQ + (m0 & 1023) + half * 64;
#pragma unroll
    for (int j = 0; j < 8; j++)
      *(bh8*)(dst + j * 8) = *(const bh8*)(Cs + dl * 132 + half * 64 + j * 8);
  } else {
#pragma unroll
    for (int n = 0; n < NR; n++) {
      int gc = n0 + wc * (BN / 2) + n * 16 + qr;
      float bv = (EPI == 1) ? bias[gc] : 0.f;
#pragma unroll
      for (int m = 0; m < MR; m++) {
        int grb = m0 + wr * (BM / 2) + m * 16 + g * 4;
#pragma unroll
        for (int r = 0; r < 4; r++) {
          float v = acc[m][n][r];
          if (EPI == 1) {
            v += bv;
            v = 0.5f * v * (1.f + erff(v * 0.70710678118654752f));
          }
          Cout[(size_t)(grb + r) * Nc + gc] = __float2bfloat16(v);
        }
      }
    }
  }
}

// ---------------- Flash attention: grid (SEQ/64, NH, NB), 4 waves x 16 q-rows ----------------
// R13/R14 config (best measured): single-buffered Ks/Vs, 256 threads, 4 blocks/CU,
// XCD bijective swizzle, kperm K-granules, defer-max + exp2 softmax, SWAPPED PV
// (lane-local rescale, bh4 z-stores).
//   Ks: [key 0..31][256 d], granule G holds data granule G ^ kperm(key&7)
//   Vs: [d 0..255][32 key-slots] (slots PV-permuted at vT creation), G ^= (d>>1)&3
__global__ __launch_bounds__(256) void attn_k(
    const __hip_bfloat16* __restrict__ qkv, const __hip_bfloat16* __restrict__ vT,
    __hip_bfloat16* __restrict__ z) {
  __shared__ __hip_bfloat16 Ks[32 * 256];
  __shared__ __hip_bfloat16 Vs[256 * 32];
  const int tid = threadIdx.x;
  const int lane = tid & 63, w = tid >> 6;
  const int g = lane >> 4, qr = lane & 15;
  // XCD swizzle: nwg = 16*8*8 = 1024, chunk = 128 logical blocks per XCD
  const unsigned aid = (blockIdx.z * NH + blockIdx.y) * (SEQ / 64) + blockIdx.x;
  const unsigned lid = (aid & 7u) * 128u + (aid >> 3);
  const int qi = lid & 15, hh = (lid >> 4) & 7, b = lid >> 7;
  const int q0 = qi * 64 + w * 16;
  const size_t qkv_b = (size_t)b * SEQ * QKVW;

  // Q fragments: lane holds Q[q0+qr][kd*32 + g*8 .. +8]
  bh8 qf[8];
  {
    const __hip_bfloat16* qrow = qkv + qkv_b + (size_t)(q0 + qr) * QKVW + hh * 256 + g * 8;
#pragma unroll
    for (int kd = 0; kd < 8; kd++) qf[kd] = *(const bh8*)(qrow + kd * 32);
  }

  fx4 o[16];
#pragma unroll
  for (int i = 0; i < 16; i++) o[i] = 0.f;
  float m_run = -INFINITY, l_run = 0.f;        // m_run in RAW score units
  constexpr float cL = 0.0625f * 1.44269504f;  // scale * log2(e)

  const int ksw = kperm(qr & 7);          // Ks read swizzle (rows qr and 16+qr share it)
  const int vsw = ((qr >> 1) & 3);        // Vs read swizzle (d = nd*16+qr -> (d>>1)&3)

  for (int j0 = 0; j0 < SEQ; j0 += 32) {
    __syncthreads();
#pragma unroll
    for (int c = 0; c < 4; c++) {
      int idx = tid + c * 256;
      int key = idx >> 5, c16 = idx & 31;
      int dp = (c16 ^ kperm(key & 7)) << 3; // pre-swizzled source column (elements)
      g2l16(qkv + qkv_b + (size_t)(j0 + key) * QKVW + 2048 + hh * 256 + dp, (char*)Ks + idx * 16);
    }
    const __hip_bfloat16* vb = vT + ((size_t)(b * 8 + hh) * 256) * SEQ + j0;
#pragma unroll
    for (int c = 0; c < 4; c++) {
      int idx = tid + c * 256;
      int d = idx >> 2, gr = idx & 3;
      int np = (gr ^ ((d >> 1) & 3)) << 3; // pre-swizzled source slot (elements)
      g2l16(vb + (size_t)d * SEQ + np, (char*)Vs + idx * 16);
    }
    __syncthreads();

    // S^T = K * Q^T : lane holds S[q=qr][key = {g*4+r, 16+g*4+r}]  (raw scores)
    fx4 s0 = 0.f, s1 = 0.f;
#pragma unroll
    for (int kd = 0; kd < 8; kd++) {
      bh8 k0f = *(const bh8*)(Ks + (size_t)qr * 256 + (((kd * 4 + g) ^ ksw) << 3));
      bh8 k1f = *(const bh8*)(Ks + (size_t)(16 + qr) * 256 + (((kd * 4 + g) ^ ksw) << 3));
      s0 = mfma16(k0f, qf[kd], s0);
      s1 = mfma16(k1f, qf[kd], s1);
    }
    float sv[8];
#pragma unroll
    for (int r = 0; r < 4; r++) { sv[r] = s0[r]; sv[4 + r] = s1[r]; }
    float pmax = sv[0];
#pragma unroll
    for (int i = 1; i < 8; i++) pmax = fmaxf(pmax, sv[i]);
    pmax = fmaxf(pmax, __shfl_xor(pmax, 16));
    pmax = fmaxf(pmax, __shfl_xor(pmax, 32));
    // defer-max: rescale only if some row's max grew by > 128 raw (= 8 scaled)
    if (!__all(pmax <= m_run + 128.f)) {
      float m_new = fmaxf(m_run, pmax);
      float corr = __builtin_amdgcn_exp2f((m_run - m_new) * cL); // first tile: 0
      // swapped-O layout: every o[nd][r] has q = qr -> corr is lane-local
#pragma unroll
      for (int nd = 0; nd < 16; nd++) {
        o[nd][0] *= corr; o[nd][1] *= corr; o[nd][2] *= corr; o[nd][3] *= corr;
      }
      l_run *= corr;
      m_run = m_new;
    }
    float mL = m_run * cL;
    float p[8], ps = 0.f;
#pragma unroll
    for (int i = 0; i < 8; i++) {
      p[i] = __builtin_amdgcn_exp2f(fmaf(sv[i], cL, -mL)); // bounded by 2^8
      ps += p[i];
    }
    ps += __shfl_xor(ps, 16);
    ps += __shfl_xor(ps, 32);
    l_run += ps;
    // P -> bf16 A-frag with key(g,i) = g*4 + (i&3) + 16*(i>>2); Vs slots hold V in the
    // same key order. SWAPPED: mfma16(vf, pa) -> lane holds O[q=qr][d=nd*16+g*4+r].
    bh8 pa;
#pragma unroll
    for (int i = 0; i < 8; i++) pa[i] = f2bf(p[i]);
#pragma unroll
    for (int nd = 0; nd < 16; nd++) {
      int d = nd * 16 + qr;
      bh8 vf = *(const bh8*)(Vs + (size_t)d * 32 + ((g ^ vsw) << 3));
      o[nd] = mfma16(vf, pa, o[nd]);
    }
  }

  float inv = 1.f / l_run;   // q = qr: lane-local, no shuffles
  __hip_bfloat16* zb = z + (size_t)b * SEQ * INNERW + hh * 256 + (size_t)(q0 + qr) * INNERW;
#pragma unroll
  for (int nd = 0; nd < 16; nd++) {
    bh4 ov;
#pragma unroll
    for (int r = 0; r < 4; r++) ov[r] = f2bf(o[nd][r] * inv);
    *(bh4*)(zb + nd * 16 + g * 4) = ov;
  }
}

// ---------------- host ----------------
extern "C" void kernel_launch(void* const* d_in, const int* in_sizes, int n_in,
                              void* d_out, int out_size, void* d_ws, size_t ws_size,
                              hipStream_t stream) {
  const float* x_in  = (const float*)d_in[0];
  const float* ln1g  = (const float*)d_in[1];
  const float* ln1b  = (const float*)d_in[2];
  const float* w_qkv = (const float*)d_in[3];
  const float* w_out = (const float*)d_in[4];
  const float* b_out = (const float*)d_in[5];
  const float* ln2g  = (const float*)d_in[6];
  const float* ln2b  = (const float*)d_in[7];
  const float* w1    = (const float*)d_in[8];
  const float* b1    = (const float*)d_in[9];
  const float* w2    = (const float*)d_in[10];
  const float* b2    = (const float*)d_in[11];

  char* ws = (char*)d_ws;
  size_t off = 0;
  auto alloc = [&](size_t bytes) { char* p = ws + off; off += (bytes + 255) & ~(size_t)255; return p; };
  float*          xf    = (float*)         alloc((size_t)ROWS * DM * 4);
  __hip_bfloat16* h     = (__hip_bfloat16*)alloc((size_t)ROWS * DM * 2);
  __hip_bfloat16* qkv   = (__hip_bfloat16*)alloc((size_t)ROWS * QKVW * 2);
  __hip_bfloat16* vT    = (__hip_bfloat16*)alloc((size_t)NB * NH * 256 * SEQ * 2);
  __hip_bfloat16* zbuf  = (__hip_bfloat16*)alloc((size_t)ROWS * INNERW * 2);
  __hip_bfloat16* mh    = zbuf; // MLP hidden reuses z region (disjoint lifetimes)
  __hip_bfloat16* wqkvT = (__hip_bfloat16*)alloc((size_t)NLAYER * QKVW * DM * 2);
  __hip_bfloat16* woutT = (__hip_bfloat16*)alloc((size_t)NLAYER * DM * INNERW * 2);
  __hip_bfloat16* w1T   = (__hip_bfloat16*)alloc((size_t)NLAYER * MLPD * DM * 2);
  __hip_bfloat16* w2T   = (__hip_bfloat16*)alloc((size_t)NLAYER * DM * MLPD * 2);
  (void)ws_size; (void)in_sizes; (void)n_in; (void)out_size;

  // weight transposes+casts (weights constant across the launch)
  wtrans_k<<<dim3(QKVW / 32, DM / 32, NLAYER), dim3(32, 8), 0, stream>>>(
      w_qkv, wqkvT, DM, QKVW, (size_t)DM * QKVW, (size_t)DM * QKVW);
  wtrans_k<<<dim3(DM / 32, INNERW / 32, NLAYER), dim3(32, 8), 0, stream>>>(
      w_out, woutT, INNERW, DM, (size_t)INNERW * DM, (size_t)INNERW * DM);
  wtrans_k<<<dim3(MLPD / 32, DM / 32, NLAYER), dim3(32, 8), 0, stream>>>(
      w1, w1T, DM, MLPD, (size_t)DM * MLPD, (size_t)DM * MLPD);
  wtrans_k<<<dim3(DM / 32, MLPD / 32, NLAYER), dim3(32, 8), 0, stream>>>(
      w2, w2T, MLPD, DM, (size_t)MLPD * DM, (size_t)MLPD * DM);

  for (int i = 0; i < NLAYER; i++) {
    // layer 0 reads the residual stream from x_in directly (no initial copy)
    const float* xcur = (i == 0) ? x_in : xf;
    float* xnext_out = (i == NLAYER - 1) ? (float*)d_out : xf;

    ln_k<<<dim3(DM / 8, NB), 256, 0, stream>>>(xcur, ln1g + i * SEQ, ln1b + i * SEQ, h);
    // qkv GEMM with fused V-transpose epilogue (EPI 3) — vtrans kernel eliminated
    gemm_bt<128, 128, 3, 0><<<dim3(QKVW / 128, ROWS / 128), 256, 0, stream>>>(
        h, wqkvT + (size_t)i * QKVW * DM, qkv, nullptr, nullptr, nullptr, vT, ROWS, QKVW, DM);
    attn_k<<<dim3(SEQ / 64, NH, NB), 256, 0, stream>>>(qkv, vT, zbuf);
    // attn-out: BM=64, dbuf pipeline; resid-in = xcur, resid-out = xf
    gemm_bt<64, 64, 2, 1><<<dim3(DM / 64, ROWS / 64), 256, 0, stream>>>(
        zbuf, woutT + (size_t)i * DM * INNERW, nullptr, b_out + i * DM, xcur, xf, nullptr,
        ROWS, DM, INNERW);
    ln_k<<<dim3(DM / 8, NB), 256, 0, stream>>>(xf, ln2g + i * SEQ, ln2b + i * SEQ, h);
    // mlp1: BM=64 (grid 1024 = 4/CU wanted, 3/CU LDS-limited with dbuf), dbuf pipeline
    gemm_bt<64, 128, 1, 1><<<dim3(MLPD / 128, ROWS / 64), 256, 0, stream>>>(
        h, w1T + (size_t)i * MLPD * DM, mh, b1 + i * MLPD, nullptr, nullptr, nullptr,
        ROWS, MLPD, DM);
    // mlp2: BM=64, dbuf; resid-in = xf, resid-out = d_out on last layer
    gemm_bt<64, 64, 2, 1><<<dim3(DM / 64, ROWS / 64), 256, 0, stream>>>(
        mh, w2T + (size_t)i * DM * MLPD, nullptr, b2 + i * DM, xf, xnext_out, nullptr,
        ROWS, DM, MLPD);
  }
}

// Round 16
// 942.489 us; speedup vs baseline: 1.2419x; 1.0200x over previous
//
#include <hip/hip_runtime.h>
#include <hip/hip_bf16.h>

#define SEQ    1024
#define DM     256
#define NH     8
#define NB     8
#define NLAYER 4
#define MLPD   1024
#define ROWS   (NB*SEQ)      // 8192
#define QKVW   6144          // 3*NH*DM
#define INNERW 2048          // NH*DM

typedef __attribute__((ext_vector_type(8))) short bh8;
typedef __attribute__((ext_vector_type(4))) short bh4;
typedef __attribute__((ext_vector_type(4))) float fx4;

__device__ __forceinline__ short f2bf(float f) {
  return __builtin_bit_cast(short, __float2bfloat16(f));
}
__device__ __forceinline__ fx4 mfma16(bh8 a, bh8 b, fx4 c) {
  return __builtin_amdgcn_mfma_f32_16x16x32_bf16(a, b, c, 0, 0, 0);
}
__device__ __forceinline__ void g2l16(const void* g, void* l) {
  __builtin_amdgcn_global_load_lds(
      (const __attribute__((address_space(1))) void*)g,
      (__attribute__((address_space(3))) void*)l, 16, 0, 0);
}
__device__ __forceinline__ int kperm(int r) {
  return ((r & 1) << 2) | ((r >> 1) & 3);
}

// ---------------- f32 -> bf16 transpose (per-layer via blockIdx.z) ----------------
// src: [R][C] f32 (row stride C), dst: [C][R] bf16
__global__ void wtrans_k(const float* __restrict__ src, __hip_bfloat16* __restrict__ dst,
                         int R, int C, size_t sls, size_t dls) {
  src += (size_t)blockIdx.z * sls;
  dst += (size_t)blockIdx.z * dls;
  __shared__ float t[32][33];
  int tx = threadIdx.x, ty = threadIdx.y;
  int r0 = blockIdx.y * 32, c0 = blockIdx.x * 32;
#pragma unroll
  for (int i = 0; i < 32; i += 8) t[ty + i][tx] = src[(size_t)(r0 + ty + i) * C + c0 + tx];
  __syncthreads();
#pragma unroll
  for (int i = 0; i < 32; i += 8)
    dst[(size_t)(c0 + ty + i) * R + r0 + tx] = __float2bfloat16(t[tx][ty + i]);
}

// ---------------- layer-0 LN stats: column sums of x_in ----------------
// grid (DM/8, NB), block 256. Writes per-(b,d) sum and sumsq (plain stores).
__global__ void stats0_k(const float* __restrict__ x, float* __restrict__ statS,
                         float* __restrict__ statSS) {
  int b = blockIdx.y, d0 = blockIdx.x * 8;
  int dl = threadIdx.x & 1, nt = threadIdx.x >> 1;
  const float* xb = x + (size_t)b * SEQ * DM + d0 + dl * 4;
  fx4 s = 0.f, ss = 0.f;
  for (int n = nt; n < SEQ; n += 128) {
    fx4 v = *(const fx4*)(xb + (size_t)n * DM);
    s += v; ss += v * v;
  }
  __shared__ fx4 S1[128][2], S2[128][2];
  S1[nt][dl] = s; S2[nt][dl] = ss;
  __syncthreads();
  if (nt < 16) {
    fx4 a = S1[nt][dl], c = S2[nt][dl];
#pragma unroll
    for (int i = 0; i < 7; i++) { a += S1[nt + 16 + i * 16][dl]; c += S2[nt + 16 + i * 16][dl]; }
    S1[nt][dl] = a; S2[nt][dl] = c;
  }
  __syncthreads();
  if (nt == 0) {
    fx4 a = 0.f, c = 0.f;
#pragma unroll
    for (int i = 0; i < 16; i++) { a += S1[i][dl]; c += S2[i][dl]; }
    *(fx4*)(statS + b * DM + d0 + dl * 4) = a;
    *(fx4*)(statSS + b * DM + d0 + dl * 4) = c;
  }
}

// ---------------- LayerNorm normalize-only (stats precomputed) ----------------
// grid (DM/8, NB) = 256 blocks. Reads statS/SS, single pass over xf, then ZEROS the
// stats so the next accumulating GEMM (EPI2) finds clean buffers.
__global__ void ln_k(const float* __restrict__ xf, const float* __restrict__ gam,
                     const float* __restrict__ bet, __hip_bfloat16* __restrict__ h,
                     float* __restrict__ statS, float* __restrict__ statSS) {
  int b = blockIdx.y, d0 = blockIdx.x * 8;
  int dl = threadIdx.x & 1;
  int nt = threadIdx.x >> 1;
  fx4 s = *(const fx4*)(statS + b * DM + d0 + dl * 4);
  fx4 ss = *(const fx4*)(statSS + b * DM + d0 + dl * 4);
  fx4 mu, rs;
#pragma unroll
  for (int r = 0; r < 4; r++) {
    mu[r] = s[r] * (1.f / SEQ);
    float var = ss[r] * (1.f / SEQ) - mu[r] * mu[r];
    rs[r] = rsqrtf(var + 1e-3f);
  }
  __syncthreads();   // all threads have read stats
  if (threadIdx.x < 2) {
    *(fx4*)(statS + b * DM + d0 + threadIdx.x * 4) = fx4{0.f, 0.f, 0.f, 0.f};
    *(fx4*)(statSS + b * DM + d0 + threadIdx.x * 4) = fx4{0.f, 0.f, 0.f, 0.f};
  }
  const float* xb = xf + (size_t)b * SEQ * DM + d0 + dl * 4;
  __hip_bfloat16* hb = h + (size_t)b * SEQ * DM + d0 + dl * 4;
  for (int n = nt; n < SEQ; n += 128) {
    fx4 v = *(const fx4*)(xb + (size_t)n * DM);
    float gn = gam[n], bn = bet[n];
    bh4 o;
#pragma unroll
    for (int r = 0; r < 4; r++) o[r] = f2bf((v[r] - mu[r]) * rs[r] * gn + bn);
    *(bh4*)(hb + (size_t)n * DM) = o;
  }
}

// ---------------- GEMM: C[M,Nc] = A[M,K] * Bt[Nc,K]^T  (+ epilogues) ----------------
// BK=64, kperm-swizzled LDS staging, XCD-aware bijective block swizzle.
// DBUF=1: double-buffered LDS, stage(t+1) issued BEFORE compute(t), one barrier/iter.
// EPI 0: bf16 stores   EPI 1: +bias, exact GELU
// EPI 2: rout = rin + acc + bias; per-(b,d) sum/sumsq wave-reduced (shfl over g) and
//        atomicAdd'ed into statS/statSS (LN stats fusion; skipped when statS==nullptr)
// EPI 3 (qkv): V third (n0>=4096) stored TRANSPOSED into vT via padded-LDS round-trip
//        (parameterized for BM 64/128), Q/K thirds via EPI0 path.
template <int BM, int BN, int EPI, int DBUF>
__global__ __launch_bounds__(256) void gemm_bt(
    const __hip_bfloat16* __restrict__ A, const __hip_bfloat16* __restrict__ Bt,
    __hip_bfloat16* __restrict__ Cout, const float* __restrict__ bias,
    const float* __restrict__ rin, float* __restrict__ rout,
    __hip_bfloat16* __restrict__ vT, float* __restrict__ statS,
    float* __restrict__ statSS, int M, int Nc, int K) {
  constexpr int BK = 64;
  constexpr int NR = BN / 32;
  constexpr int MR = BM / 32;
  constexpr int SPAN = (BM + BN) * BK;
  constexpr int CP = BM + 4;               // EPI3 padded nn stride
  static_assert(BN == 64 || BN == 128, "");
  static_assert(BM == 64 || BM == 128, "");
  constexpr int BUFE = SPAN * (DBUF ? 2 : 1);
  constexpr int LDSE = (EPI == 3) ? (BUFE > 128 * CP ? BUFE : 128 * CP) : BUFE;
  __shared__ __hip_bfloat16 smem[LDSE];
  const int tid = threadIdx.x;
  const int lane = tid & 63, w = tid >> 6;
  const int g = lane >> 4, qr = lane & 15;
  const int wr = w >> 1, wc = w & 1;
  // XCD swizzle: apparent id -> logical id so each XCD gets a contiguous chunk
  const unsigned aid = blockIdx.y * gridDim.x + blockIdx.x;
  const unsigned nwg = gridDim.x * gridDim.y;
  const unsigned lid = (aid & 7u) * (nwg >> 3) + (aid >> 3);
  const int m0 = (int)(lid / gridDim.x) * BM, n0 = (int)(lid % gridDim.x) * BN;
  const int swr = kperm(qr & 7);

  fx4 acc[MR][NR];
#pragma unroll
  for (int m = 0; m < MR; m++)
#pragma unroll
    for (int n = 0; n < NR; n++) acc[m][n] = 0.f;

  constexpr int ACH = (BM * BK) / (8 * 256);
  constexpr int BCH = (BN * BK) / (8 * 256);

  auto stage = [&](int buf, int k0) {
    __hip_bfloat16* As_ = smem + buf * SPAN;
    __hip_bfloat16* Bs_ = As_ + BM * BK;
#pragma unroll
    for (int c = 0; c < ACH; c++) {
      int idx = tid + c * 256;
      int row = idx >> 3, gr2 = idx & 7;
      g2l16(A + (size_t)(m0 + row) * K + k0 + ((gr2 ^ kperm(row & 7)) << 3), (char*)As_ + idx * 16);
    }
#pragma unroll
    for (int c = 0; c < BCH; c++) {
      int idx = tid + c * 256;
      int col = idx >> 3, gr2 = idx & 7;
      g2l16(Bt + (size_t)(n0 + col) * K + k0 + ((gr2 ^ kperm(col & 7)) << 3), (char*)Bs_ + idx * 16);
    }
  };
  auto comp = [&](const __hip_bfloat16* As_, const __hip_bfloat16* Bs_) {
#pragma unroll
    for (int ks = 0; ks < 2; ks++) {
      bh8 af[MR], bf[NR];
#pragma unroll
      for (int m = 0; m < MR; m++)
        af[m] = *(const bh8*)(As_ + (wr * (BM / 2) + m * 16 + qr) * BK + (((ks * 4 + g) ^ swr) << 3));
#pragma unroll
      for (int n = 0; n < NR; n++)
        bf[n] = *(const bh8*)(Bs_ + (wc * (BN / 2) + n * 16 + qr) * BK + (((ks * 4 + g) ^ swr) << 3));
#pragma unroll
      for (int m = 0; m < MR; m++)
#pragma unroll
        for (int n = 0; n < NR; n++) acc[m][n] = mfma16(af[m], bf[n], acc[m][n]);
    }
  };

  if constexpr (DBUF) {
    stage(0, 0);
    __syncthreads();
    const int NT = K / BK;
    for (int t = 0; t < NT; ++t) {
      const int cur = t & 1;
      if (t + 1 < NT) stage(cur ^ 1, (t + 1) * BK);
      comp(smem + cur * SPAN, smem + cur * SPAN + BM * BK);
      __syncthreads();
    }
  } else {
    for (int k0 = 0; k0 < K; k0 += BK) {
      __syncthreads();
      stage(0, k0);
      __syncthreads();
      comp(smem, smem + BM * BK);
    }
  }

  // acc[m][n][r] = C[m0 + wr*(BM/2) + m*16 + g*4 + r][n0 + wc*(BN/2) + n*16 + qr]
  if constexpr (EPI == 2) {
    float psum[NR], psq[NR];
#pragma unroll
    for (int n = 0; n < NR; n++) { psum[n] = 0.f; psq[n] = 0.f; }
#pragma unroll
    for (int n = 0; n < NR; n++) {
      int gc = n0 + wc * (BN / 2) + n * 16 + qr;
      float bv = bias[gc];
#pragma unroll
      for (int m = 0; m < MR; m++) {
        int grb = m0 + wr * (BM / 2) + m * 16 + g * 4;
#pragma unroll
        for (int r = 0; r < 4; r++) {
          float v = rin[(size_t)(grb + r) * Nc + gc] + acc[m][n][r] + bv;
          rout[(size_t)(grb + r) * Nc + gc] = v;
          psum[n] += v; psq[n] += v * v;
        }
      }
    }
    if (statS) {   // LN stats fusion: reduce over the 4 g-groups, one atomic per column
      int b = m0 >> 10;
#pragma unroll
      for (int n = 0; n < NR; n++) {
        int gc = n0 + wc * (BN / 2) + n * 16 + qr;
        float a = psum[n];
        a += __shfl_xor(a, 16); a += __shfl_xor(a, 32);
        float c = psq[n];
        c += __shfl_xor(c, 16); c += __shfl_xor(c, 32);
        if (g == 0) {
          atomicAdd(statS + b * DM + gc, a);
          atomicAdd(statSS + b * DM + gc, c);
        }
      }
    }
  } else if (EPI == 3 && n0 >= 4096) {
    // ---- V third: transposed store into vT via padded-LDS round-trip ----
    __syncthreads();
    __hip_bfloat16* Cs = smem;             // [128 d][CP nn-padded]
#pragma unroll
    for (int n = 0; n < NR; n++) {
      int dl = wc * (BN / 2) + n * 16 + qr;
#pragma unroll
      for (int m = 0; m < MR; m++) {
        int grp = (wr * (BM / 2) + m * 16) & ~31;
        int nlp = grp + g * 8 + (m & 1) * 4;   // PV slot permutation within 32-row group
        bh4 v;
#pragma unroll
        for (int r = 0; r < 4; r++) v[r] = f2bf(acc[m][n][r]);
        *(bh4*)(Cs + dl * CP + nlp) = v;
      }
    }
    __syncthreads();
    const int dl = tid >> 1, half = tid & 1;
    const int bb = m0 >> 10;
    const int hh = (n0 - 4096) >> 8;
    const int d0v = (n0 - 4096) & 255;
    __hip_bfloat16* dst =
        vT + ((size_t)(bb * 8 + hh) * 256 + d0v + dl) * SEQ + (m0 & 1023) + half * (BM / 2);
#pragma unroll
    for (int j = 0; j < BM / 16; j++)
      *(bh8*)(dst + j * 8) = *(const bh8*)(Cs + dl * CP + half * (BM / 2) + j * 8);
  } else {
#pragma unroll
    for (int n = 0; n < NR; n++) {
      int gc = n0 + wc * (BN / 2) + n * 16 + qr;
      float bv = (EPI == 1) ? bias[gc] : 0.f;
#pragma unroll
      for (int m = 0; m < MR; m++) {
        int grb = m0 + wr * (BM / 2) + m * 16 + g * 4;
#pragma unroll
        for (int r = 0; r < 4; r++) {
          float v = acc[m][n][r];
          if (EPI == 1) {
            v += bv;
            v = 0.5f * v * (1.f + erff(v * 0.70710678118654752f));
          }
          Cout[(size_t)(grb + r) * Nc + gc] = __float2bfloat16(v);
        }
      }
    }
  }
}

// ---------------- Flash attention: grid (SEQ/64, NH, NB), 4 waves x 16 q-rows ----------------
// R13/R14 config (best measured): single-buffered Ks/Vs, 256 threads, 4 blocks/CU,
// XCD bijective swizzle, kperm K-granules, defer-max + exp2 softmax, SWAPPED PV
// (lane-local rescale, bh4 z-stores).
//   Ks: [key 0..31][256 d], granule G holds data granule G ^ kperm(key&7)
//   Vs: [d 0..255][32 key-slots] (slots PV-permuted at vT creation), G ^= (d>>1)&3
__global__ __launch_bounds__(256) void attn_k(
    const __hip_bfloat16* __restrict__ qkv, const __hip_bfloat16* __restrict__ vT,
    __hip_bfloat16* __restrict__ z) {
  __shared__ __hip_bfloat16 Ks[32 * 256];
  __shared__ __hip_bfloat16 Vs[256 * 32];
  const int tid = threadIdx.x;
  const int lane = tid & 63, w = tid >> 6;
  const int g = lane >> 4, qr = lane & 15;
  // XCD swizzle: nwg = 16*8*8 = 1024, chunk = 128 logical blocks per XCD
  const unsigned aid = (blockIdx.z * NH + blockIdx.y) * (SEQ / 64) + blockIdx.x;
  const unsigned lid = (aid & 7u) * 128u + (aid >> 3);
  const int qi = lid & 15, hh = (lid >> 4) & 7, b = lid >> 7;
  const int q0 = qi * 64 + w * 16;
  const size_t qkv_b = (size_t)b * SEQ * QKVW;

  // Q fragments: lane holds Q[q0+qr][kd*32 + g*8 .. +8]
  bh8 qf[8];
  {
    const __hip_bfloat16* qrow = qkv + qkv_b + (size_t)(q0 + qr) * QKVW + hh * 256 + g * 8;
#pragma unroll
    for (int kd = 0; kd < 8; kd++) qf[kd] = *(const bh8*)(qrow + kd * 32);
  }

  fx4 o[16];
#pragma unroll
  for (int i = 0; i < 16; i++) o[i] = 0.f;
  float m_run = -INFINITY, l_run = 0.f;        // m_run in RAW score units
  constexpr float cL = 0.0625f * 1.44269504f;  // scale * log2(e)

  const int ksw = kperm(qr & 7);          // Ks read swizzle (rows qr and 16+qr share it)
  const int vsw = ((qr >> 1) & 3);        // Vs read swizzle (d = nd*16+qr -> (d>>1)&3)

  for (int j0 = 0; j0 < SEQ; j0 += 32) {
    __syncthreads();
#pragma unroll
    for (int c = 0; c < 4; c++) {
      int idx = tid + c * 256;
      int key = idx >> 5, c16 = idx & 31;
      int dp = (c16 ^ kperm(key & 7)) << 3; // pre-swizzled source column (elements)
      g2l16(qkv + qkv_b + (size_t)(j0 + key) * QKVW + 2048 + hh * 256 + dp, (char*)Ks + idx * 16);
    }
    const __hip_bfloat16* vb = vT + ((size_t)(b * 8 + hh) * 256) * SEQ + j0;
#pragma unroll
    for (int c = 0; c < 4; c++) {
      int idx = tid + c * 256;
      int d = idx >> 2, gr = idx & 3;
      int np = (gr ^ ((d >> 1) & 3)) << 3; // pre-swizzled source slot (elements)
      g2l16(vb + (size_t)d * SEQ + np, (char*)Vs + idx * 16);
    }
    __syncthreads();

    // S^T = K * Q^T : lane holds S[q=qr][key = {g*4+r, 16+g*4+r}]  (raw scores)
    fx4 s0 = 0.f, s1 = 0.f;
#pragma unroll
    for (int kd = 0; kd < 8; kd++) {
      bh8 k0f = *(const bh8*)(Ks + (size_t)qr * 256 + (((kd * 4 + g) ^ ksw) << 3));
      bh8 k1f = *(const bh8*)(Ks + (size_t)(16 + qr) * 256 + (((kd * 4 + g) ^ ksw) << 3));
      s0 = mfma16(k0f, qf[kd], s0);
      s1 = mfma16(k1f, qf[kd], s1);
    }
    float sv[8];
#pragma unroll
    for (int r = 0; r < 4; r++) { sv[r] = s0[r]; sv[4 + r] = s1[r]; }
    float pmax = sv[0];
#pragma unroll
    for (int i = 1; i < 8; i++) pmax = fmaxf(pmax, sv[i]);
    pmax = fmaxf(pmax, __shfl_xor(pmax, 16));
    pmax = fmaxf(pmax, __shfl_xor(pmax, 32));
    // defer-max: rescale only if some row's max grew by > 128 raw (= 8 scaled)
    if (!__all(pmax <= m_run + 128.f)) {
      float m_new = fmaxf(m_run, pmax);
      float corr = __builtin_amdgcn_exp2f((m_run - m_new) * cL); // first tile: 0
      // swapped-O layout: every o[nd][r] has q = qr -> corr is lane-local
#pragma unroll
      for (int nd = 0; nd < 16; nd++) {
        o[nd][0] *= corr; o[nd][1] *= corr; o[nd][2] *= corr; o[nd][3] *= corr;
      }
      l_run *= corr;
      m_run = m_new;
    }
    float mL = m_run * cL;
    float p[8], ps = 0.f;
#pragma unroll
    for (int i = 0; i < 8; i++) {
      p[i] = __builtin_amdgcn_exp2f(fmaf(sv[i], cL, -mL)); // bounded by 2^8
      ps += p[i];
    }
    ps += __shfl_xor(ps, 16);
    ps += __shfl_xor(ps, 32);
    l_run += ps;
    // P -> bf16 A-frag with key(g,i) = g*4 + (i&3) + 16*(i>>2); Vs slots hold V in the
    // same key order. SWAPPED: mfma16(vf, pa) -> lane holds O[q=qr][d=nd*16+g*4+r].
    bh8 pa;
#pragma unroll
    for (int i = 0; i < 8; i++) pa[i] = f2bf(p[i]);
#pragma unroll
    for (int nd = 0; nd < 16; nd++) {
      int d = nd * 16 + qr;
      bh8 vf = *(const bh8*)(Vs + (size_t)d * 32 + ((g ^ vsw) << 3));
      o[nd] = mfma16(vf, pa, o[nd]);
    }
  }

  float inv = 1.f / l_run;   // q = qr: lane-local, no shuffles
  __hip_bfloat16* zb = z + (size_t)b * SEQ * INNERW + hh * 256 + (size_t)(q0 + qr) * INNERW;
#pragma unroll
  for (int nd = 0; nd < 16; nd++) {
    bh4 ov;
#pragma unroll
    for (int r = 0; r < 4; r++) ov[r] = f2bf(o[nd][r] * inv);
    *(bh4*)(zb + nd * 16 + g * 4) = ov;
  }
}

// ---------------- host ----------------
extern "C" void kernel_launch(void* const* d_in, const int* in_sizes, int n_in,
                              void* d_out, int out_size, void* d_ws, size_t ws_size,
                              hipStream_t stream) {
  const float* x_in  = (const float*)d_in[0];
  const float* ln1g  = (const float*)d_in[1];
  const float* ln1b  = (const float*)d_in[2];
  const float* w_qkv = (const float*)d_in[3];
  const float* w_out = (const float*)d_in[4];
  const float* b_out = (const float*)d_in[5];
  const float* ln2g  = (const float*)d_in[6];
  const float* ln2b  = (const float*)d_in[7];
  const float* w1    = (const float*)d_in[8];
  const float* b1    = (const float*)d_in[9];
  const float* w2    = (const float*)d_in[10];
  const float* b2    = (const float*)d_in[11];

  char* ws = (char*)d_ws;
  size_t off = 0;
  auto alloc = [&](size_t bytes) { char* p = ws + off; off += (bytes + 255) & ~(size_t)255; return p; };
  float*          xf    = (float*)         alloc((size_t)ROWS * DM * 4);
  __hip_bfloat16* h     = (__hip_bfloat16*)alloc((size_t)ROWS * DM * 2);
  __hip_bfloat16* qkv   = (__hip_bfloat16*)alloc((size_t)ROWS * QKVW * 2);
  __hip_bfloat16* vT    = (__hip_bfloat16*)alloc((size_t)NB * NH * 256 * SEQ * 2);
  __hip_bfloat16* zbuf  = (__hip_bfloat16*)alloc((size_t)ROWS * INNERW * 2);
  __hip_bfloat16* mh    = zbuf; // MLP hidden reuses z region (disjoint lifetimes)
  __hip_bfloat16* wqkvT = (__hip_bfloat16*)alloc((size_t)NLAYER * QKVW * DM * 2);
  __hip_bfloat16* woutT = (__hip_bfloat16*)alloc((size_t)NLAYER * DM * INNERW * 2);
  __hip_bfloat16* w1T   = (__hip_bfloat16*)alloc((size_t)NLAYER * MLPD * DM * 2);
  __hip_bfloat16* w2T   = (__hip_bfloat16*)alloc((size_t)NLAYER * DM * MLPD * 2);
  float*          statS = (float*)         alloc((size_t)NB * DM * 4);
  float*          statSS= (float*)         alloc((size_t)NB * DM * 4);
  (void)ws_size; (void)in_sizes; (void)n_in; (void)out_size;

  // weight transposes+casts (weights constant across the launch)
  wtrans_k<<<dim3(QKVW / 32, DM / 32, NLAYER), dim3(32, 8), 0, stream>>>(
      w_qkv, wqkvT, DM, QKVW, (size_t)DM * QKVW, (size_t)DM * QKVW);
  wtrans_k<<<dim3(DM / 32, INNERW / 32, NLAYER), dim3(32, 8), 0, stream>>>(
      w_out, woutT, INNERW, DM, (size_t)INNERW * DM, (size_t)INNERW * DM);
  wtrans_k<<<dim3(MLPD / 32, DM / 32, NLAYER), dim3(32, 8), 0, stream>>>(
      w1, w1T, DM, MLPD, (size_t)DM * MLPD, (size_t)DM * MLPD);
  wtrans_k<<<dim3(DM / 32, MLPD / 32, NLAYER), dim3(32, 8), 0, stream>>>(
      w2, w2T, MLPD, DM, (size_t)MLPD * DM, (size_t)MLPD * DM);

  // layer-0 ln1 stats from x_in (also leaves buffers ready: ln_k zeros after reading)
  stats0_k<<<dim3(DM / 8, NB), 256, 0, stream>>>(x_in, statS, statSS);

  for (int i = 0; i < NLAYER; i++) {
    const float* xcur = (i == 0) ? x_in : xf;
    float* xnext_out = (i == NLAYER - 1) ? (float*)d_out : xf;
    float* sS = (i == NLAYER - 1) ? nullptr : statS;    // last mlp2's stats unused
    float* sSS = (i == NLAYER - 1) ? nullptr : statSS;

    // ln1: stats from previous mlp2 (or stats0_k); zeros buffers after reading
    ln_k<<<dim3(DM / 8, NB), 256, 0, stream>>>(xcur, ln1g + i * SEQ, ln1b + i * SEQ, h,
                                               statS, statSS);
    // qkv GEMM with fused V-transpose epilogue; dbuf pipeline (BM=64)
    gemm_bt<64, 128, 3, 1><<<dim3(QKVW / 128, ROWS / 64), 256, 0, stream>>>(
        h, wqkvT + (size_t)i * QKVW * DM, qkv, nullptr, nullptr, nullptr, vT,
        nullptr, nullptr, ROWS, QKVW, DM);
    attn_k<<<dim3(SEQ / 64, NH, NB), 256, 0, stream>>>(qkv, vT, zbuf);
    // attn-out: dbuf; resid xcur->xf; accumulates ln2 stats
    gemm_bt<64, 64, 2, 1><<<dim3(DM / 64, ROWS / 64), 256, 0, stream>>>(
        zbuf, woutT + (size_t)i * DM * INNERW, nullptr, b_out + i * DM, xcur, xf, nullptr,
        statS, statSS, ROWS, DM, INNERW);
    // ln2: reads attn-out stats; zeros buffers
    ln_k<<<dim3(DM / 8, NB), 256, 0, stream>>>(xf, ln2g + i * SEQ, ln2b + i * SEQ, h,
                                               statS, statSS);
    gemm_bt<64, 128, 1, 1><<<dim3(MLPD / 128, ROWS / 64), 256, 0, stream>>>(
        h, w1T + (size_t)i * MLPD * DM, mh, b1 + i * MLPD, nullptr, nullptr, nullptr,
        nullptr, nullptr, ROWS, MLPD, DM);
    // mlp2: dbuf; resid xf->(xf|d_out); accumulates next ln1 stats (except last layer)
    gemm_bt<64, 64, 2, 1><<<dim3(DM / 64, ROWS / 64), 256, 0, stream>>>(
        mh, w2T + (size_t)i * DM * MLPD, nullptr, b2 + i * DM, xf, xnext_out, nullptr,
        sS, sSS, ROWS, DM, MLPD);
  }
}

// Round 17
// 920.177 us; speedup vs baseline: 1.2720x; 1.0242x over previous
//
#include <hip/hip_runtime.h>
#include <hip/hip_bf16.h>

#define SEQ    1024
#define DM     256
#define NH     8
#define NB     8
#define NLAYER 4
#define MLPD   1024
#define ROWS   (NB*SEQ)      // 8192
#define QKVW   6144          // 3*NH*DM
#define INNERW 2048          // NH*DM

typedef __attribute__((ext_vector_type(8))) short bh8;
typedef __attribute__((ext_vector_type(4))) short bh4;
typedef __attribute__((ext_vector_type(4))) float fx4;

__device__ __forceinline__ short f2bf(float f) {
  return __builtin_bit_cast(short, __float2bfloat16(f));
}
__device__ __forceinline__ fx4 mfma16(bh8 a, bh8 b, fx4 c) {
  return __builtin_amdgcn_mfma_f32_16x16x32_bf16(a, b, c, 0, 0, 0);
}
__device__ __forceinline__ void g2l16(const void* g, void* l) {
  __builtin_amdgcn_global_load_lds(
      (const __attribute__((address_space(1))) void*)g,
      (__attribute__((address_space(3))) void*)l, 16, 0, 0);
}
__device__ __forceinline__ int kperm(int r) {
  return ((r & 1) << 2) | ((r >> 1) & 3);
}

// ---------------- f32 -> bf16 transpose (per-layer via blockIdx.z) ----------------
// src: [R][C] f32 (row stride C), dst: [C][R] bf16
__global__ void wtrans_k(const float* __restrict__ src, __hip_bfloat16* __restrict__ dst,
                         int R, int C, size_t sls, size_t dls) {
  src += (size_t)blockIdx.z * sls;
  dst += (size_t)blockIdx.z * dls;
  __shared__ float t[32][33];
  int tx = threadIdx.x, ty = threadIdx.y;
  int r0 = blockIdx.y * 32, c0 = blockIdx.x * 32;
#pragma unroll
  for (int i = 0; i < 32; i += 8) t[ty + i][tx] = src[(size_t)(r0 + ty + i) * C + c0 + tx];
  __syncthreads();
#pragma unroll
  for (int i = 0; i < 32; i += 8)
    dst[(size_t)(c0 + ty + i) * R + r0 + tx] = __float2bfloat16(t[tx][ty + i]);
}

// ---------------- layer-0 LN stats: column sums of x_in ----------------
// grid (DM/8, NB), block 256. Writes per-(b,d) sum and sumsq (plain stores).
__global__ void stats0_k(const float* __restrict__ x, float* __restrict__ statS,
                         float* __restrict__ statSS) {
  int b = blockIdx.y, d0 = blockIdx.x * 8;
  int dl = threadIdx.x & 1, nt = threadIdx.x >> 1;
  const float* xb = x + (size_t)b * SEQ * DM + d0 + dl * 4;
  fx4 s = 0.f, ss = 0.f;
  for (int n = nt; n < SEQ; n += 128) {
    fx4 v = *(const fx4*)(xb + (size_t)n * DM);
    s += v; ss += v * v;
  }
  __shared__ fx4 S1[128][2], S2[128][2];
  S1[nt][dl] = s; S2[nt][dl] = ss;
  __syncthreads();
  if (nt < 16) {
    fx4 a = S1[nt][dl], c = S2[nt][dl];
#pragma unroll
    for (int i = 0; i < 7; i++) { a += S1[nt + 16 + i * 16][dl]; c += S2[nt + 16 + i * 16][dl]; }
    S1[nt][dl] = a; S2[nt][dl] = c;
  }
  __syncthreads();
  if (nt == 0) {
    fx4 a = 0.f, c = 0.f;
#pragma unroll
    for (int i = 0; i < 16; i++) { a += S1[i][dl]; c += S2[i][dl]; }
    *(fx4*)(statS + b * DM + d0 + dl * 4) = a;
    *(fx4*)(statSS + b * DM + d0 + dl * 4) = c;
  }
}

// ---------------- LayerNorm normalize-only (stats precomputed) ----------------
// grid (DM/8, NB) = 256 blocks. Reads statS/SS, single pass over xf, then ZEROS the
// stats so the next accumulating GEMM (EPI2) finds clean buffers.
__global__ void ln_k(const float* __restrict__ xf, const float* __restrict__ gam,
                     const float* __restrict__ bet, __hip_bfloat16* __restrict__ h,
                     float* __restrict__ statS, float* __restrict__ statSS) {
  int b = blockIdx.y, d0 = blockIdx.x * 8;
  int dl = threadIdx.x & 1;
  int nt = threadIdx.x >> 1;
  fx4 s = *(const fx4*)(statS + b * DM + d0 + dl * 4);
  fx4 ss = *(const fx4*)(statSS + b * DM + d0 + dl * 4);
  fx4 mu, rs;
#pragma unroll
  for (int r = 0; r < 4; r++) {
    mu[r] = s[r] * (1.f / SEQ);
    float var = ss[r] * (1.f / SEQ) - mu[r] * mu[r];
    rs[r] = rsqrtf(var + 1e-3f);
  }
  __syncthreads();   // all threads have read stats
  if (threadIdx.x < 2) {
    *(fx4*)(statS + b * DM + d0 + threadIdx.x * 4) = fx4{0.f, 0.f, 0.f, 0.f};
    *(fx4*)(statSS + b * DM + d0 + threadIdx.x * 4) = fx4{0.f, 0.f, 0.f, 0.f};
  }
  const float* xb = xf + (size_t)b * SEQ * DM + d0 + dl * 4;
  __hip_bfloat16* hb = h + (size_t)b * SEQ * DM + d0 + dl * 4;
  for (int n = nt; n < SEQ; n += 128) {
    fx4 v = *(const fx4*)(xb + (size_t)n * DM);
    float gn = gam[n], bn = bet[n];
    bh4 o;
#pragma unroll
    for (int r = 0; r < 4; r++) o[r] = f2bf((v[r] - mu[r]) * rs[r] * gn + bn);
    *(bh4*)(hb + (size_t)n * DM) = o;
  }
}

// ---------------- GEMM: C[M,Nc] = A[M,K] * Bt[Nc,K]^T  (+ epilogues) ----------------
// BK templated (64 for K=256 GEMMs; 128 for long-K EPI2 GEMMs: halves the per-iter
// barrier+vmcnt-drain count at UNCHANGED occupancy — those kernels are grid-limited
// at 2 blocks/CU and 64 KB dbuf LDS still fits 2/CU). kperm swizzle generalizes:
// the XOR touches only the low 3 bits of the granule index (bank pattern repeats
// every 128 B), so staging/read remain inverse bijections for any BK.
// DBUF=1: double-buffered LDS, stage(t+1) issued BEFORE compute(t), one barrier/iter.
// EPI 0: bf16 stores   EPI 1: +bias, exact GELU
// EPI 2: rout = rin + acc + bias; per-(b,d) sum/sumsq wave-reduced and atomicAdd'ed
//        into statS/statSS (LN stats fusion; skipped when statS==nullptr)
// EPI 3 (qkv): V third (n0>=4096) stored TRANSPOSED into vT via padded-LDS round-trip.
template <int BM, int BN, int BK, int EPI, int DBUF>
__global__ __launch_bounds__(256) void gemm_bt(
    const __hip_bfloat16* __restrict__ A, const __hip_bfloat16* __restrict__ Bt,
    __hip_bfloat16* __restrict__ Cout, const float* __restrict__ bias,
    const float* __restrict__ rin, float* __restrict__ rout,
    __hip_bfloat16* __restrict__ vT, float* __restrict__ statS,
    float* __restrict__ statSS, int M, int Nc, int K) {
  constexpr int NR = BN / 32;
  constexpr int MR = BM / 32;
  constexpr int GPR = BK / 8;              // 16B granules per row
  constexpr int NKS = BK / 32;             // k-slices per tile
  constexpr int SPAN = (BM + BN) * BK;
  constexpr int CP = BM + 4;               // EPI3 padded nn stride
  static_assert(BN == 64 || BN == 128, "");
  static_assert(BM == 64 || BM == 128, "");
  static_assert(BK == 64 || BK == 128, "");
  constexpr int BUFE = SPAN * (DBUF ? 2 : 1);
  constexpr int LDSE = (EPI == 3) ? (BUFE > 128 * CP ? BUFE : 128 * CP) : BUFE;
  __shared__ __hip_bfloat16 smem[LDSE];
  const int tid = threadIdx.x;
  const int lane = tid & 63, w = tid >> 6;
  const int g = lane >> 4, qr = lane & 15;
  const int wr = w >> 1, wc = w & 1;
  // XCD swizzle: apparent id -> logical id so each XCD gets a contiguous chunk
  const unsigned aid = blockIdx.y * gridDim.x + blockIdx.x;
  const unsigned nwg = gridDim.x * gridDim.y;
  const unsigned lid = (aid & 7u) * (nwg >> 3) + (aid >> 3);
  const int m0 = (int)(lid / gridDim.x) * BM, n0 = (int)(lid % gridDim.x) * BN;
  const int swr = kperm(qr & 7);

  fx4 acc[MR][NR];
#pragma unroll
  for (int m = 0; m < MR; m++)
#pragma unroll
    for (int n = 0; n < NR; n++) acc[m][n] = 0.f;

  constexpr int ACH = (BM * BK) / (8 * 256);
  constexpr int BCH = (BN * BK) / (8 * 256);

  auto stage = [&](int buf, int k0) {
    __hip_bfloat16* As_ = smem + buf * SPAN;
    __hip_bfloat16* Bs_ = As_ + BM * BK;
#pragma unroll
    for (int c = 0; c < ACH; c++) {
      int idx = tid + c * 256;
      int row = idx / GPR, gr2 = idx % GPR;
      g2l16(A + (size_t)(m0 + row) * K + k0 + ((gr2 ^ kperm(row & 7)) << 3), (char*)As_ + idx * 16);
    }
#pragma unroll
    for (int c = 0; c < BCH; c++) {
      int idx = tid + c * 256;
      int col = idx / GPR, gr2 = idx % GPR;
      g2l16(Bt + (size_t)(n0 + col) * K + k0 + ((gr2 ^ kperm(col & 7)) << 3), (char*)Bs_ + idx * 16);
    }
  };
  auto comp = [&](const __hip_bfloat16* As_, const __hip_bfloat16* Bs_) {
#pragma unroll
    for (int ks = 0; ks < NKS; ks++) {
      bh8 af[MR], bf[NR];
#pragma unroll
      for (int m = 0; m < MR; m++)
        af[m] = *(const bh8*)(As_ + (wr * (BM / 2) + m * 16 + qr) * BK + (((ks * 4 + g) ^ swr) << 3));
#pragma unroll
      for (int n = 0; n < NR; n++)
        bf[n] = *(const bh8*)(Bs_ + (wc * (BN / 2) + n * 16 + qr) * BK + (((ks * 4 + g) ^ swr) << 3));
#pragma unroll
      for (int m = 0; m < MR; m++)
#pragma unroll
        for (int n = 0; n < NR; n++) acc[m][n] = mfma16(af[m], bf[n], acc[m][n]);
    }
  };

  if constexpr (DBUF) {
    stage(0, 0);
    __syncthreads();
    const int NT = K / BK;
    for (int t = 0; t < NT; ++t) {
      const int cur = t & 1;
      if (t + 1 < NT) stage(cur ^ 1, (t + 1) * BK);
      comp(smem + cur * SPAN, smem + cur * SPAN + BM * BK);
      __syncthreads();
    }
  } else {
    for (int k0 = 0; k0 < K; k0 += BK) {
      __syncthreads();
      stage(0, k0);
      __syncthreads();
      comp(smem, smem + BM * BK);
    }
  }

  // acc[m][n][r] = C[m0 + wr*(BM/2) + m*16 + g*4 + r][n0 + wc*(BN/2) + n*16 + qr]
  if constexpr (EPI == 2) {
    float psum[NR], psq[NR];
#pragma unroll
    for (int n = 0; n < NR; n++) { psum[n] = 0.f; psq[n] = 0.f; }
#pragma unroll
    for (int n = 0; n < NR; n++) {
      int gc = n0 + wc * (BN / 2) + n * 16 + qr;
      float bv = bias[gc];
#pragma unroll
      for (int m = 0; m < MR; m++) {
        int grb = m0 + wr * (BM / 2) + m * 16 + g * 4;
#pragma unroll
        for (int r = 0; r < 4; r++) {
          float v = rin[(size_t)(grb + r) * Nc + gc] + acc[m][n][r] + bv;
          rout[(size_t)(grb + r) * Nc + gc] = v;
          psum[n] += v; psq[n] += v * v;
        }
      }
    }
    if (statS) {   // LN stats fusion: reduce over the 4 g-groups, one atomic per column
      int b = m0 >> 10;
#pragma unroll
      for (int n = 0; n < NR; n++) {
        int gc = n0 + wc * (BN / 2) + n * 16 + qr;
        float a = psum[n];
        a += __shfl_xor(a, 16); a += __shfl_xor(a, 32);
        float c = psq[n];
        c += __shfl_xor(c, 16); c += __shfl_xor(c, 32);
        if (g == 0) {
          atomicAdd(statS + b * DM + gc, a);
          atomicAdd(statSS + b * DM + gc, c);
        }
      }
    }
  } else if (EPI == 3 && n0 >= 4096) {
    // ---- V third: transposed store into vT via padded-LDS round-trip ----
    __syncthreads();
    __hip_bfloat16* Cs = smem;             // [128 d][CP nn-padded]
#pragma unroll
    for (int n = 0; n < NR; n++) {
      int dl = wc * (BN / 2) + n * 16 + qr;
#pragma unroll
      for (int m = 0; m < MR; m++) {
        int grp = (wr * (BM / 2) + m * 16) & ~31;
        int nlp = grp + g * 8 + (m & 1) * 4;   // PV slot permutation within 32-row group
        bh4 v;
#pragma unroll
        for (int r = 0; r < 4; r++) v[r] = f2bf(acc[m][n][r]);
        *(bh4*)(Cs + dl * CP + nlp) = v;
      }
    }
    __syncthreads();
    const int dl = tid >> 1, half = tid & 1;
    const int bb = m0 >> 10;
    const int hh = (n0 - 4096) >> 8;
    const int d0v = (n0 - 4096) & 255;
    __hip_bfloat16* dst =
        vT + ((size_t)(bb * 8 + hh) * 256 + d0v + dl) * SEQ + (m0 & 1023) + half * (BM / 2);
#pragma unroll
    for (int j = 0; j < BM / 16; j++)
      *(bh8*)(dst + j * 8) = *(const bh8*)(Cs + dl * CP + half * (BM / 2) + j * 8);
  } else {
#pragma unroll
    for (int n = 0; n < NR; n++) {
      int gc = n0 + wc * (BN / 2) + n * 16 + qr;
      float bv = (EPI == 1) ? bias[gc] : 0.f;
#pragma unroll
      for (int m = 0; m < MR; m++) {
        int grb = m0 + wr * (BM / 2) + m * 16 + g * 4;
#pragma unroll
        for (int r = 0; r < 4; r++) {
          float v = acc[m][n][r];
          if (EPI == 1) {
            v += bv;
            v = 0.5f * v * (1.f + erff(v * 0.70710678118654752f));
          }
          Cout[(size_t)(grb + r) * Nc + gc] = __float2bfloat16(v);
        }
      }
    }
  }
}

// ---------------- Flash attention: grid (SEQ/64, NH, NB), 4 waves x 16 q-rows ----------------
// R13/R14 config (best measured): single-buffered Ks/Vs, 256 threads, 4 blocks/CU,
// XCD bijective swizzle, kperm K-granules, defer-max + exp2 softmax, SWAPPED PV
// (lane-local rescale, bh4 z-stores).
//   Ks: [key 0..31][256 d], granule G holds data granule G ^ kperm(key&7)
//   Vs: [d 0..255][32 key-slots] (slots PV-permuted at vT creation), G ^= (d>>1)&3
__global__ __launch_bounds__(256) void attn_k(
    const __hip_bfloat16* __restrict__ qkv, const __hip_bfloat16* __restrict__ vT,
    __hip_bfloat16* __restrict__ z) {
  __shared__ __hip_bfloat16 Ks[32 * 256];
  __shared__ __hip_bfloat16 Vs[256 * 32];
  const int tid = threadIdx.x;
  const int lane = tid & 63, w = tid >> 6;
  const int g = lane >> 4, qr = lane & 15;
  // XCD swizzle: nwg = 16*8*8 = 1024, chunk = 128 logical blocks per XCD
  const unsigned aid = (blockIdx.z * NH + blockIdx.y) * (SEQ / 64) + blockIdx.x;
  const unsigned lid = (aid & 7u) * 128u + (aid >> 3);
  const int qi = lid & 15, hh = (lid >> 4) & 7, b = lid >> 7;
  const int q0 = qi * 64 + w * 16;
  const size_t qkv_b = (size_t)b * SEQ * QKVW;

  // Q fragments: lane holds Q[q0+qr][kd*32 + g*8 .. +8]
  bh8 qf[8];
  {
    const __hip_bfloat16* qrow = qkv + qkv_b + (size_t)(q0 + qr) * QKVW + hh * 256 + g * 8;
#pragma unroll
    for (int kd = 0; kd < 8; kd++) qf[kd] = *(const bh8*)(qrow + kd * 32);
  }

  fx4 o[16];
#pragma unroll
  for (int i = 0; i < 16; i++) o[i] = 0.f;
  float m_run = -INFINITY, l_run = 0.f;        // m_run in RAW score units
  constexpr float cL = 0.0625f * 1.44269504f;  // scale * log2(e)

  const int ksw = kperm(qr & 7);          // Ks read swizzle (rows qr and 16+qr share it)
  const int vsw = ((qr >> 1) & 3);        // Vs read swizzle (d = nd*16+qr -> (d>>1)&3)

  for (int j0 = 0; j0 < SEQ; j0 += 32) {
    __syncthreads();
#pragma unroll
    for (int c = 0; c < 4; c++) {
      int idx = tid + c * 256;
      int key = idx >> 5, c16 = idx & 31;
      int dp = (c16 ^ kperm(key & 7)) << 3; // pre-swizzled source column (elements)
      g2l16(qkv + qkv_b + (size_t)(j0 + key) * QKVW + 2048 + hh * 256 + dp, (char*)Ks + idx * 16);
    }
    const __hip_bfloat16* vb = vT + ((size_t)(b * 8 + hh) * 256) * SEQ + j0;
#pragma unroll
    for (int c = 0; c < 4; c++) {
      int idx = tid + c * 256;
      int d = idx >> 2, gr = idx & 3;
      int np = (gr ^ ((d >> 1) & 3)) << 3; // pre-swizzled source slot (elements)
      g2l16(vb + (size_t)d * SEQ + np, (char*)Vs + idx * 16);
    }
    __syncthreads();

    // S^T = K * Q^T : lane holds S[q=qr][key = {g*4+r, 16+g*4+r}]  (raw scores)
    fx4 s0 = 0.f, s1 = 0.f;
#pragma unroll
    for (int kd = 0; kd < 8; kd++) {
      bh8 k0f = *(const bh8*)(Ks + (size_t)qr * 256 + (((kd * 4 + g) ^ ksw) << 3));
      bh8 k1f = *(const bh8*)(Ks + (size_t)(16 + qr) * 256 + (((kd * 4 + g) ^ ksw) << 3));
      s0 = mfma16(k0f, qf[kd], s0);
      s1 = mfma16(k1f, qf[kd], s1);
    }
    float sv[8];
#pragma unroll
    for (int r = 0; r < 4; r++) { sv[r] = s0[r]; sv[4 + r] = s1[r]; }
    float pmax = sv[0];
#pragma unroll
    for (int i = 1; i < 8; i++) pmax = fmaxf(pmax, sv[i]);
    pmax = fmaxf(pmax, __shfl_xor(pmax, 16));
    pmax = fmaxf(pmax, __shfl_xor(pmax, 32));
    // defer-max: rescale only if some row's max grew by > 128 raw (= 8 scaled)
    if (!__all(pmax <= m_run + 128.f)) {
      float m_new = fmaxf(m_run, pmax);
      float corr = __builtin_amdgcn_exp2f((m_run - m_new) * cL); // first tile: 0
      // swapped-O layout: every o[nd][r] has q = qr -> corr is lane-local
#pragma unroll
      for (int nd = 0; nd < 16; nd++) {
        o[nd][0] *= corr; o[nd][1] *= corr; o[nd][2] *= corr; o[nd][3] *= corr;
      }
      l_run *= corr;
      m_run = m_new;
    }
    float mL = m_run * cL;
    float p[8], ps = 0.f;
#pragma unroll
    for (int i = 0; i < 8; i++) {
      p[i] = __builtin_amdgcn_exp2f(fmaf(sv[i], cL, -mL)); // bounded by 2^8
      ps += p[i];
    }
    ps += __shfl_xor(ps, 16);
    ps += __shfl_xor(ps, 32);
    l_run += ps;
    // P -> bf16 A-frag with key(g,i) = g*4 + (i&3) + 16*(i>>2); Vs slots hold V in the
    // same key order. SWAPPED: mfma16(vf, pa) -> lane holds O[q=qr][d=nd*16+g*4+r].
    bh8 pa;
#pragma unroll
    for (int i = 0; i < 8; i++) pa[i] = f2bf(p[i]);
#pragma unroll
    for (int nd = 0; nd < 16; nd++) {
      int d = nd * 16 + qr;
      bh8 vf = *(const bh8*)(Vs + (size_t)d * 32 + ((g ^ vsw) << 3));
      o[nd] = mfma16(vf, pa, o[nd]);
    }
  }

  float inv = 1.f / l_run;   // q = qr: lane-local, no shuffles
  __hip_bfloat16* zb = z + (size_t)b * SEQ * INNERW + hh * 256 + (size_t)(q0 + qr) * INNERW;
#pragma unroll
  for (int nd = 0; nd < 16; nd++) {
    bh4 ov;
#pragma unroll
    for (int r = 0; r < 4; r++) ov[r] = f2bf(o[nd][r] * inv);
    *(bh4*)(zb + nd * 16 + g * 4) = ov;
  }
}

// ---------------- host ----------------
extern "C" void kernel_launch(void* const* d_in, const int* in_sizes, int n_in,
                              void* d_out, int out_size, void* d_ws, size_t ws_size,
                              hipStream_t stream) {
  const float* x_in  = (const float*)d_in[0];
  const float* ln1g  = (const float*)d_in[1];
  const float* ln1b  = (const float*)d_in[2];
  const float* w_qkv = (const float*)d_in[3];
  const float* w_out = (const float*)d_in[4];
  const float* b_out = (const float*)d_in[5];
  const float* ln2g  = (const float*)d_in[6];
  const float* ln2b  = (const float*)d_in[7];
  const float* w1    = (const float*)d_in[8];
  const float* b1    = (const float*)d_in[9];
  const float* w2    = (const float*)d_in[10];
  const float* b2    = (const float*)d_in[11];

  char* ws = (char*)d_ws;
  size_t off = 0;
  auto alloc = [&](size_t bytes) { char* p = ws + off; off += (bytes + 255) & ~(size_t)255; return p; };
  float*          xf    = (float*)         alloc((size_t)ROWS * DM * 4);
  __hip_bfloat16* h     = (__hip_bfloat16*)alloc((size_t)ROWS * DM * 2);
  __hip_bfloat16* qkv   = (__hip_bfloat16*)alloc((size_t)ROWS * QKVW * 2);
  __hip_bfloat16* vT    = (__hip_bfloat16*)alloc((size_t)NB * NH * 256 * SEQ * 2);
  __hip_bfloat16* zbuf  = (__hip_bfloat16*)alloc((size_t)ROWS * INNERW * 2);
  __hip_bfloat16* mh    = zbuf; // MLP hidden reuses z region (disjoint lifetimes)
  __hip_bfloat16* wqkvT = (__hip_bfloat16*)alloc((size_t)NLAYER * QKVW * DM * 2);
  __hip_bfloat16* woutT = (__hip_bfloat16*)alloc((size_t)NLAYER * DM * INNERW * 2);
  __hip_bfloat16* w1T   = (__hip_bfloat16*)alloc((size_t)NLAYER * MLPD * DM * 2);
  __hip_bfloat16* w2T   = (__hip_bfloat16*)alloc((size_t)NLAYER * DM * MLPD * 2);
  float*          statS = (float*)         alloc((size_t)NB * DM * 4);
  float*          statSS= (float*)         alloc((size_t)NB * DM * 4);
  (void)ws_size; (void)in_sizes; (void)n_in; (void)out_size;

  // weight transposes+casts (weights constant across the launch)
  wtrans_k<<<dim3(QKVW / 32, DM / 32, NLAYER), dim3(32, 8), 0, stream>>>(
      w_qkv, wqkvT, DM, QKVW, (size_t)DM * QKVW, (size_t)DM * QKVW);
  wtrans_k<<<dim3(DM / 32, INNERW / 32, NLAYER), dim3(32, 8), 0, stream>>>(
      w_out, woutT, INNERW, DM, (size_t)INNERW * DM, (size_t)INNERW * DM);
  wtrans_k<<<dim3(MLPD / 32, DM / 32, NLAYER), dim3(32, 8), 0, stream>>>(
      w1, w1T, DM, MLPD, (size_t)DM * MLPD, (size_t)DM * MLPD);
  wtrans_k<<<dim3(DM / 32, MLPD / 32, NLAYER), dim3(32, 8), 0, stream>>>(
      w2, w2T, MLPD, DM, (size_t)MLPD * DM, (size_t)MLPD * DM);

  // layer-0 ln1 stats from x_in (also leaves buffers ready: ln_k zeros after reading)
  stats0_k<<<dim3(DM / 8, NB), 256, 0, stream>>>(x_in, statS, statSS);

  for (int i = 0; i < NLAYER; i++) {
    const float* xcur = (i == 0) ? x_in : xf;
    float* xnext_out = (i == NLAYER - 1) ? (float*)d_out : xf;
    float* sS = (i == NLAYER - 1) ? nullptr : statS;    // last mlp2's stats unused
    float* sSS = (i == NLAYER - 1) ? nullptr : statSS;

    // ln1: stats from previous mlp2 (or stats0_k); zeros buffers after reading
    ln_k<<<dim3(DM / 8, NB), 256, 0, stream>>>(xcur, ln1g + i * SEQ, ln1b + i * SEQ, h,
                                               statS, statSS);
    // qkv GEMM with fused V-transpose epilogue; dbuf pipeline (BM=64, BK=64)
    gemm_bt<64, 128, 64, 3, 1><<<dim3(QKVW / 128, ROWS / 64), 256, 0, stream>>>(
        h, wqkvT + (size_t)i * QKVW * DM, qkv, nullptr, nullptr, nullptr, vT,
        nullptr, nullptr, ROWS, QKVW, DM);
    attn_k<<<dim3(SEQ / 64, NH, NB), 256, 0, stream>>>(qkv, vT, zbuf);
    // attn-out: BK=128 (16 iters instead of 32, same 2 blocks/CU); stats for ln2
    gemm_bt<64, 64, 128, 2, 1><<<dim3(DM / 64, ROWS / 64), 256, 0, stream>>>(
        zbuf, woutT + (size_t)i * DM * INNERW, nullptr, b_out + i * DM, xcur, xf, nullptr,
        statS, statSS, ROWS, DM, INNERW);
    // ln2: reads attn-out stats; zeros buffers
    ln_k<<<dim3(DM / 8, NB), 256, 0, stream>>>(xf, ln2g + i * SEQ, ln2b + i * SEQ, h,
                                               statS, statSS);
    gemm_bt<64, 128, 64, 1, 1><<<dim3(MLPD / 128, ROWS / 64), 256, 0, stream>>>(
        h, w1T + (size_t)i * MLPD * DM, mh, b1 + i * MLPD, nullptr, nullptr, nullptr,
        nullptr, nullptr, ROWS, MLPD, DM);
    // mlp2: BK=128 (8 iters instead of 16); resid xf->(xf|d_out); stats for next ln1
    gemm_bt<64, 64, 128, 2, 1><<<dim3(DM / 64, ROWS / 64), 256, 0, stream>>>(
        mh, w2T + (size_t)i * DM * MLPD, nullptr, b2 + i * DM, xf, xnext_out, nullptr,
        sS, sSS, ROWS, DM, MLPD);
  }
}

// Round 18
// 905.333 us; speedup vs baseline: 1.2929x; 1.0164x over previous
//
#include <hip/hip_runtime.h>
#include <hip/hip_bf16.h>

#define SEQ    1024
#define DM     256
#define NH     8
#define NB     8
#define NLAYER 4
#define MLPD   1024
#define ROWS   (NB*SEQ)      // 8192
#define QKVW   6144          // 3*NH*DM
#define INNERW 2048          // NH*DM

typedef __attribute__((ext_vector_type(8))) short bh8;
typedef __attribute__((ext_vector_type(4))) short bh4;
typedef __attribute__((ext_vector_type(4))) float fx4;

__device__ __forceinline__ short f2bf(float f) {
  return __builtin_bit_cast(short, __float2bfloat16(f));
}
__device__ __forceinline__ fx4 mfma16(bh8 a, bh8 b, fx4 c) {
  return __builtin_amdgcn_mfma_f32_16x16x32_bf16(a, b, c, 0, 0, 0);
}
__device__ __forceinline__ void g2l16(const void* g, void* l) {
  __builtin_amdgcn_global_load_lds(
      (const __attribute__((address_space(1))) void*)g,
      (__attribute__((address_space(3))) void*)l, 16, 0, 0);
}
__device__ __forceinline__ int kperm(int r) {
  return ((r & 1) << 2) | ((r >> 1) & 3);
}

// ---------------- f32 -> bf16 transpose (per-layer via blockIdx.z) ----------------
// 64x64 tiles: 256-B read segments, 128-B write segments (vtrans-proven pattern).
// src: [R][C] f32 (row stride C), dst: [C][R] bf16
__global__ void wtrans_k(const float* __restrict__ src, __hip_bfloat16* __restrict__ dst,
                         int R, int C, size_t sls, size_t dls) {
  src += (size_t)blockIdx.z * sls;
  dst += (size_t)blockIdx.z * dls;
  __shared__ float t[64][65];
  int tx = threadIdx.x, ty = threadIdx.y;   // (64, 8)
  int r0 = blockIdx.y * 64, c0 = blockIdx.x * 64;
#pragma unroll
  for (int i = 0; i < 64; i += 8) t[ty + i][tx] = src[(size_t)(r0 + ty + i) * C + c0 + tx];
  __syncthreads();
#pragma unroll
  for (int i = 0; i < 64; i += 8)
    dst[(size_t)(c0 + ty + i) * R + r0 + tx] = __float2bfloat16(t[tx][ty + i]);
}

// ---------------- layer-0 LN stats: column sums of x_in ----------------
// grid (DM/8, NB), block 256. Writes per-(b,d) sum and sumsq (plain stores).
__global__ void stats0_k(const float* __restrict__ x, float* __restrict__ statS,
                         float* __restrict__ statSS) {
  int b = blockIdx.y, d0 = blockIdx.x * 8;
  int dl = threadIdx.x & 1, nt = threadIdx.x >> 1;
  const float* xb = x + (size_t)b * SEQ * DM + d0 + dl * 4;
  fx4 s = 0.f, ss = 0.f;
  for (int n = nt; n < SEQ; n += 128) {
    fx4 v = *(const fx4*)(xb + (size_t)n * DM);
    s += v; ss += v * v;
  }
  __shared__ fx4 S1[128][2], S2[128][2];
  S1[nt][dl] = s; S2[nt][dl] = ss;
  __syncthreads();
  if (nt < 16) {
    fx4 a = S1[nt][dl], c = S2[nt][dl];
#pragma unroll
    for (int i = 0; i < 7; i++) { a += S1[nt + 16 + i * 16][dl]; c += S2[nt + 16 + i * 16][dl]; }
    S1[nt][dl] = a; S2[nt][dl] = c;
  }
  __syncthreads();
  if (nt == 0) {
    fx4 a = 0.f, c = 0.f;
#pragma unroll
    for (int i = 0; i < 16; i++) { a += S1[i][dl]; c += S2[i][dl]; }
    *(fx4*)(statS + b * DM + d0 + dl * 4) = a;
    *(fx4*)(statSS + b * DM + d0 + dl * 4) = c;
  }
}

// ---------------- LayerNorm normalize-only (stats precomputed) ----------------
// grid (DM/8, NB) = 256 blocks. Reads statS/SS, single pass over xf, then ZEROS the
// stats so the next accumulating GEMM (EPI2) finds clean buffers.
__global__ void ln_k(const float* __restrict__ xf, const float* __restrict__ gam,
                     const float* __restrict__ bet, __hip_bfloat16* __restrict__ h,
                     float* __restrict__ statS, float* __restrict__ statSS) {
  int b = blockIdx.y, d0 = blockIdx.x * 8;
  int dl = threadIdx.x & 1;
  int nt = threadIdx.x >> 1;
  fx4 s = *(const fx4*)(statS + b * DM + d0 + dl * 4);
  fx4 ss = *(const fx4*)(statSS + b * DM + d0 + dl * 4);
  fx4 mu, rs;
#pragma unroll
  for (int r = 0; r < 4; r++) {
    mu[r] = s[r] * (1.f / SEQ);
    float var = ss[r] * (1.f / SEQ) - mu[r] * mu[r];
    rs[r] = rsqrtf(var + 1e-3f);
  }
  __syncthreads();   // all threads have read stats
  if (threadIdx.x < 2) {
    *(fx4*)(statS + b * DM + d0 + threadIdx.x * 4) = fx4{0.f, 0.f, 0.f, 0.f};
    *(fx4*)(statSS + b * DM + d0 + threadIdx.x * 4) = fx4{0.f, 0.f, 0.f, 0.f};
  }
  const float* xb = xf + (size_t)b * SEQ * DM + d0 + dl * 4;
  __hip_bfloat16* hb = h + (size_t)b * SEQ * DM + d0 + dl * 4;
  for (int n = nt; n < SEQ; n += 128) {
    fx4 v = *(const fx4*)(xb + (size_t)n * DM);
    float gn = gam[n], bn = bet[n];
    bh4 o;
#pragma unroll
    for (int r = 0; r < 4; r++) o[r] = f2bf((v[r] - mu[r]) * rs[r] * gn + bn);
    *(bh4*)(hb + (size_t)n * DM) = o;
  }
}

// ---------------- GEMM: C[M,Nc] = A[M,K] * Bt[Nc,K]^T  (+ epilogues) ----------------
// BK templated (64 for K=256 GEMMs; 128 for long-K EPI2 GEMMs). kperm-swizzled LDS
// staging, XCD-aware bijective block swizzle.
// DBUF=1: double-buffered LDS, stage(t+1) issued BEFORE compute(t), one barrier/iter.
// EPI 0: bf16 stores   EPI 1: +bias, exact GELU
// EPI 2: rout = rin + acc + bias; per-(b,d) sum/sumsq wave-reduced and atomicAdd'ed
//        into statS/statSS (LN stats fusion; skipped when statS==nullptr)
// EPI 3 (qkv): V third (n0>=4096) stored TRANSPOSED into vT via padded-LDS round-trip.
template <int BM, int BN, int BK, int EPI, int DBUF>
__global__ __launch_bounds__(256) void gemm_bt(
    const __hip_bfloat16* __restrict__ A, const __hip_bfloat16* __restrict__ Bt,
    __hip_bfloat16* __restrict__ Cout, const float* __restrict__ bias,
    const float* __restrict__ rin, float* __restrict__ rout,
    __hip_bfloat16* __restrict__ vT, float* __restrict__ statS,
    float* __restrict__ statSS, int M, int Nc, int K) {
  constexpr int NR = BN / 32;
  constexpr int MR = BM / 32;
  constexpr int GPR = BK / 8;              // 16B granules per row
  constexpr int NKS = BK / 32;             // k-slices per tile
  constexpr int SPAN = (BM + BN) * BK;
  constexpr int CP = BM + 4;               // EPI3 padded nn stride
  static_assert(BN == 64 || BN == 128, "");
  static_assert(BM == 64 || BM == 128, "");
  static_assert(BK == 64 || BK == 128, "");
  constexpr int BUFE = SPAN * (DBUF ? 2 : 1);
  constexpr int LDSE = (EPI == 3) ? (BUFE > 128 * CP ? BUFE : 128 * CP) : BUFE;
  __shared__ __hip_bfloat16 smem[LDSE];
  const int tid = threadIdx.x;
  const int lane = tid & 63, w = tid >> 6;
  const int g = lane >> 4, qr = lane & 15;
  const int wr = w >> 1, wc = w & 1;
  // XCD swizzle: apparent id -> logical id so each XCD gets a contiguous chunk
  const unsigned aid = blockIdx.y * gridDim.x + blockIdx.x;
  const unsigned nwg = gridDim.x * gridDim.y;
  const unsigned lid = (aid & 7u) * (nwg >> 3) + (aid >> 3);
  const int m0 = (int)(lid / gridDim.x) * BM, n0 = (int)(lid % gridDim.x) * BN;
  const int swr = kperm(qr & 7);

  fx4 acc[MR][NR];
#pragma unroll
  for (int m = 0; m < MR; m++)
#pragma unroll
    for (int n = 0; n < NR; n++) acc[m][n] = 0.f;

  constexpr int ACH = (BM * BK) / (8 * 256);
  constexpr int BCH = (BN * BK) / (8 * 256);

  auto stage = [&](int buf, int k0) {
    __hip_bfloat16* As_ = smem + buf * SPAN;
    __hip_bfloat16* Bs_ = As_ + BM * BK;
#pragma unroll
    for (int c = 0; c < ACH; c++) {
      int idx = tid + c * 256;
      int row = idx / GPR, gr2 = idx % GPR;
      g2l16(A + (size_t)(m0 + row) * K + k0 + ((gr2 ^ kperm(row & 7)) << 3), (char*)As_ + idx * 16);
    }
#pragma unroll
    for (int c = 0; c < BCH; c++) {
      int idx = tid + c * 256;
      int col = idx / GPR, gr2 = idx % GPR;
      g2l16(Bt + (size_t)(n0 + col) * K + k0 + ((gr2 ^ kperm(col & 7)) << 3), (char*)Bs_ + idx * 16);
    }
  };
  auto comp = [&](const __hip_bfloat16* As_, const __hip_bfloat16* Bs_) {
#pragma unroll
    for (int ks = 0; ks < NKS; ks++) {
      bh8 af[MR], bf[NR];
#pragma unroll
      for (int m = 0; m < MR; m++)
        af[m] = *(const bh8*)(As_ + (wr * (BM / 2) + m * 16 + qr) * BK + (((ks * 4 + g) ^ swr) << 3));
#pragma unroll
      for (int n = 0; n < NR; n++)
        bf[n] = *(const bh8*)(Bs_ + (wc * (BN / 2) + n * 16 + qr) * BK + (((ks * 4 + g) ^ swr) << 3));
#pragma unroll
      for (int m = 0; m < MR; m++)
#pragma unroll
        for (int n = 0; n < NR; n++) acc[m][n] = mfma16(af[m], bf[n], acc[m][n]);
    }
  };

  if constexpr (DBUF) {
    stage(0, 0);
    __syncthreads();
    const int NT = K / BK;
    for (int t = 0; t < NT; ++t) {
      const int cur = t & 1;
      if (t + 1 < NT) stage(cur ^ 1, (t + 1) * BK);
      comp(smem + cur * SPAN, smem + cur * SPAN + BM * BK);
      __syncthreads();
    }
  } else {
    for (int k0 = 0; k0 < K; k0 += BK) {
      __syncthreads();
      stage(0, k0);
      __syncthreads();
      comp(smem, smem + BM * BK);
    }
  }

  // acc[m][n][r] = C[m0 + wr*(BM/2) + m*16 + g*4 + r][n0 + wc*(BN/2) + n*16 + qr]
  if constexpr (EPI == 2) {
    float psum[NR], psq[NR];
#pragma unroll
    for (int n = 0; n < NR; n++) { psum[n] = 0.f; psq[n] = 0.f; }
#pragma unroll
    for (int n = 0; n < NR; n++) {
      int gc = n0 + wc * (BN / 2) + n * 16 + qr;
      float bv = bias[gc];
#pragma unroll
      for (int m = 0; m < MR; m++) {
        int grb = m0 + wr * (BM / 2) + m * 16 + g * 4;
#pragma unroll
        for (int r = 0; r < 4; r++) {
          float v = rin[(size_t)(grb + r) * Nc + gc] + acc[m][n][r] + bv;
          rout[(size_t)(grb + r) * Nc + gc] = v;
          psum[n] += v; psq[n] += v * v;
        }
      }
    }
    if (statS) {   // LN stats fusion: reduce over the 4 g-groups, one atomic per column
      int b = m0 >> 10;
#pragma unroll
      for (int n = 0; n < NR; n++) {
        int gc = n0 + wc * (BN / 2) + n * 16 + qr;
        float a = psum[n];
        a += __shfl_xor(a, 16); a += __shfl_xor(a, 32);
        float c = psq[n];
        c += __shfl_xor(c, 16); c += __shfl_xor(c, 32);
        if (g == 0) {
          atomicAdd(statS + b * DM + gc, a);
          atomicAdd(statSS + b * DM + gc, c);
        }
      }
    }
  } else if (EPI == 3 && n0 >= 4096) {
    // ---- V third: transposed store into vT via padded-LDS round-trip ----
    __syncthreads();
    __hip_bfloat16* Cs = smem;             // [128 d][CP nn-padded]
#pragma unroll
    for (int n = 0; n < NR; n++) {
      int dl = wc * (BN / 2) + n * 16 + qr;
#pragma unroll
      for (int m = 0; m < MR; m++) {
        int grp = (wr * (BM / 2) + m * 16) & ~31;
        int nlp = grp + g * 8 + (m & 1) * 4;   // PV slot permutation within 32-row group
        bh4 v;
#pragma unroll
        for (int r = 0; r < 4; r++) v[r] = f2bf(acc[m][n][r]);
        *(bh4*)(Cs + dl * CP + nlp) = v;
      }
    }
    __syncthreads();
    const int dl = tid >> 1, half = tid & 1;
    const int bb = m0 >> 10;
    const int hh = (n0 - 4096) >> 8;
    const int d0v = (n0 - 4096) & 255;
    __hip_bfloat16* dst =
        vT + ((size_t)(bb * 8 + hh) * 256 + d0v + dl) * SEQ + (m0 & 1023) + half * (BM / 2);
#pragma unroll
    for (int j = 0; j < BM / 16; j++)
      *(bh8*)(dst + j * 8) = *(const bh8*)(Cs + dl * CP + half * (BM / 2) + j * 8);
  } else {
#pragma unroll
    for (int n = 0; n < NR; n++) {
      int gc = n0 + wc * (BN / 2) + n * 16 + qr;
      float bv = (EPI == 1) ? bias[gc] : 0.f;
#pragma unroll
      for (int m = 0; m < MR; m++) {
        int grb = m0 + wr * (BM / 2) + m * 16 + g * 4;
#pragma unroll
        for (int r = 0; r < 4; r++) {
          float v = acc[m][n][r];
          if (EPI == 1) {
            v += bv;
            v = 0.5f * v * (1.f + erff(v * 0.70710678118654752f));
          }
          Cout[(size_t)(grb + r) * Nc + gc] = __float2bfloat16(v);
        }
      }
    }
  }
}

// ---------------- Flash attention: grid (SEQ/64, NH, NB), 4 waves x 16 q-rows ----------------
// R13/R14 structure + deferred l-reduction: l is kept as a PER-LANE partial (each
// lane sums its own 8 p's; the row-uniform corr factor keeps partials consistent),
// reduced across the 4 g-groups ONCE at the end — removes 2 shfl (LDS-pipe ops)
// per j-tile (64 per wave). pmax's 2 shfl/tile stay (mL must be row-uniform for
// the MFMA-summed pa fragments).
//   Ks: [key 0..31][256 d], granule G holds data granule G ^ kperm(key&7)
//   Vs: [d 0..255][32 key-slots] (slots PV-permuted at vT creation), G ^= (d>>1)&3
__global__ __launch_bounds__(256) void attn_k(
    const __hip_bfloat16* __restrict__ qkv, const __hip_bfloat16* __restrict__ vT,
    __hip_bfloat16* __restrict__ z) {
  __shared__ __hip_bfloat16 Ks[32 * 256];
  __shared__ __hip_bfloat16 Vs[256 * 32];
  const int tid = threadIdx.x;
  const int lane = tid & 63, w = tid >> 6;
  const int g = lane >> 4, qr = lane & 15;
  // XCD swizzle: nwg = 16*8*8 = 1024, chunk = 128 logical blocks per XCD
  const unsigned aid = (blockIdx.z * NH + blockIdx.y) * (SEQ / 64) + blockIdx.x;
  const unsigned lid = (aid & 7u) * 128u + (aid >> 3);
  const int qi = lid & 15, hh = (lid >> 4) & 7, b = lid >> 7;
  const int q0 = qi * 64 + w * 16;
  const size_t qkv_b = (size_t)b * SEQ * QKVW;

  // Q fragments: lane holds Q[q0+qr][kd*32 + g*8 .. +8]
  bh8 qf[8];
  {
    const __hip_bfloat16* qrow = qkv + qkv_b + (size_t)(q0 + qr) * QKVW + hh * 256 + g * 8;
#pragma unroll
    for (int kd = 0; kd < 8; kd++) qf[kd] = *(const bh8*)(qrow + kd * 32);
  }

  fx4 o[16];
#pragma unroll
  for (int i = 0; i < 16; i++) o[i] = 0.f;
  float m_run = -INFINITY, l_par = 0.f;        // l_par: PER-LANE partial denominator
  constexpr float cL = 0.0625f * 1.44269504f;  // scale * log2(e)

  const int ksw = kperm(qr & 7);          // Ks read swizzle (rows qr and 16+qr share it)
  const int vsw = ((qr >> 1) & 3);        // Vs read swizzle (d = nd*16+qr -> (d>>1)&3)

  for (int j0 = 0; j0 < SEQ; j0 += 32) {
    __syncthreads();
#pragma unroll
    for (int c = 0; c < 4; c++) {
      int idx = tid + c * 256;
      int key = idx >> 5, c16 = idx & 31;
      int dp = (c16 ^ kperm(key & 7)) << 3; // pre-swizzled source column (elements)
      g2l16(qkv + qkv_b + (size_t)(j0 + key) * QKVW + 2048 + hh * 256 + dp, (char*)Ks + idx * 16);
    }
    const __hip_bfloat16* vb = vT + ((size_t)(b * 8 + hh) * 256) * SEQ + j0;
#pragma unroll
    for (int c = 0; c < 4; c++) {
      int idx = tid + c * 256;
      int d = idx >> 2, gr = idx & 3;
      int np = (gr ^ ((d >> 1) & 3)) << 3; // pre-swizzled source slot (elements)
      g2l16(vb + (size_t)d * SEQ + np, (char*)Vs + idx * 16);
    }
    __syncthreads();

    // S^T = K * Q^T : lane holds S[q=qr][key = {g*4+r, 16+g*4+r}]  (raw scores)
    fx4 s0 = 0.f, s1 = 0.f;
#pragma unroll
    for (int kd = 0; kd < 8; kd++) {
      bh8 k0f = *(const bh8*)(Ks + (size_t)qr * 256 + (((kd * 4 + g) ^ ksw) << 3));
      bh8 k1f = *(const bh8*)(Ks + (size_t)(16 + qr) * 256 + (((kd * 4 + g) ^ ksw) << 3));
      s0 = mfma16(k0f, qf[kd], s0);
      s1 = mfma16(k1f, qf[kd], s1);
    }
    float sv[8];
#pragma unroll
    for (int r = 0; r < 4; r++) { sv[r] = s0[r]; sv[4 + r] = s1[r]; }
    float pmax = sv[0];
#pragma unroll
    for (int i = 1; i < 8; i++) pmax = fmaxf(pmax, sv[i]);
    pmax = fmaxf(pmax, __shfl_xor(pmax, 16));
    pmax = fmaxf(pmax, __shfl_xor(pmax, 32));
    // defer-max: rescale only if some row's max grew by > 128 raw (= 8 scaled)
    if (!__all(pmax <= m_run + 128.f)) {
      float m_new = fmaxf(m_run, pmax);
      float corr = __builtin_amdgcn_exp2f((m_run - m_new) * cL); // first tile: 0
      // swapped-O layout: every o[nd][r] has q = qr -> corr is lane-local;
      // corr is row-uniform so per-lane l partials stay consistent
#pragma unroll
      for (int nd = 0; nd < 16; nd++) {
        o[nd][0] *= corr; o[nd][1] *= corr; o[nd][2] *= corr; o[nd][3] *= corr;
      }
      l_par *= corr;
      m_run = m_new;
    }
    float mL = m_run * cL;
    float p[8];
#pragma unroll
    for (int i = 0; i < 8; i++) {
      p[i] = __builtin_amdgcn_exp2f(fmaf(sv[i], cL, -mL)); // bounded by 2^8
      l_par += p[i];
    }
    // P -> bf16 A-frag with key(g,i) = g*4 + (i&3) + 16*(i>>2); Vs slots hold V in the
    // same key order. SWAPPED: mfma16(vf, pa) -> lane holds O[q=qr][d=nd*16+g*4+r].
    bh8 pa;
#pragma unroll
    for (int i = 0; i < 8; i++) pa[i] = f2bf(p[i]);
#pragma unroll
    for (int nd = 0; nd < 16; nd++) {
      int d = nd * 16 + qr;
      bh8 vf = *(const bh8*)(Vs + (size_t)d * 32 + ((g ^ vsw) << 3));
      o[nd] = mfma16(vf, pa, o[nd]);
    }
  }

  // final l reduction across the 4 g-groups of this row (once, not per tile)
  float l_tot = l_par;
  l_tot += __shfl_xor(l_tot, 16);
  l_tot += __shfl_xor(l_tot, 32);
  float inv = 1.f / l_tot;   // q = qr: lane-local epilogue, no further shuffles
  __hip_bfloat16* zb = z + (size_t)b * SEQ * INNERW + hh * 256 + (size_t)(q0 + qr) * INNERW;
#pragma unroll
  for (int nd = 0; nd < 16; nd++) {
    bh4 ov;
#pragma unroll
    for (int r = 0; r < 4; r++) ov[r] = f2bf(o[nd][r] * inv);
    *(bh4*)(zb + nd * 16 + g * 4) = ov;
  }
}

// ---------------- host ----------------
extern "C" void kernel_launch(void* const* d_in, const int* in_sizes, int n_in,
                              void* d_out, int out_size, void* d_ws, size_t ws_size,
                              hipStream_t stream) {
  const float* x_in  = (const float*)d_in[0];
  const float* ln1g  = (const float*)d_in[1];
  const float* ln1b  = (const float*)d_in[2];
  const float* w_qkv = (const float*)d_in[3];
  const float* w_out = (const float*)d_in[4];
  const float* b_out = (const float*)d_in[5];
  const float* ln2g  = (const float*)d_in[6];
  const float* ln2b  = (const float*)d_in[7];
  const float* w1    = (const float*)d_in[8];
  const float* b1    = (const float*)d_in[9];
  const float* w2    = (const float*)d_in[10];
  const float* b2    = (const float*)d_in[11];

  char* ws = (char*)d_ws;
  size_t off = 0;
  auto alloc = [&](size_t bytes) { char* p = ws + off; off += (bytes + 255) & ~(size_t)255; return p; };
  float*          xf    = (float*)         alloc((size_t)ROWS * DM * 4);
  __hip_bfloat16* h     = (__hip_bfloat16*)alloc((size_t)ROWS * DM * 2);
  __hip_bfloat16* qkv   = (__hip_bfloat16*)alloc((size_t)ROWS * QKVW * 2);
  __hip_bfloat16* vT    = (__hip_bfloat16*)alloc((size_t)NB * NH * 256 * SEQ * 2);
  __hip_bfloat16* zbuf  = (__hip_bfloat16*)alloc((size_t)ROWS * INNERW * 2);
  __hip_bfloat16* mh    = zbuf; // MLP hidden reuses z region (disjoint lifetimes)
  __hip_bfloat16* wqkvT = (__hip_bfloat16*)alloc((size_t)NLAYER * QKVW * DM * 2);
  __hip_bfloat16* woutT = (__hip_bfloat16*)alloc((size_t)NLAYER * DM * INNERW * 2);
  __hip_bfloat16* w1T   = (__hip_bfloat16*)alloc((size_t)NLAYER * MLPD * DM * 2);
  __hip_bfloat16* w2T   = (__hip_bfloat16*)alloc((size_t)NLAYER * DM * MLPD * 2);
  float*          statS = (float*)         alloc((size_t)NB * DM * 4);
  float*          statSS= (float*)         alloc((size_t)NB * DM * 4);
  (void)ws_size; (void)in_sizes; (void)n_in; (void)out_size;

  // weight transposes+casts (weights constant across the launch); 64x64 tiles
  wtrans_k<<<dim3(QKVW / 64, DM / 64, NLAYER), dim3(64, 8), 0, stream>>>(
      w_qkv, wqkvT, DM, QKVW, (size_t)DM * QKVW, (size_t)DM * QKVW);
  wtrans_k<<<dim3(DM / 64, INNERW / 64, NLAYER), dim3(64, 8), 0, stream>>>(
      w_out, woutT, INNERW, DM, (size_t)INNERW * DM, (size_t)INNERW * DM);
  wtrans_k<<<dim3(MLPD / 64, DM / 64, NLAYER), dim3(64, 8), 0, stream>>>(
      w1, w1T, DM, MLPD, (size_t)DM * MLPD, (size_t)DM * MLPD);
  wtrans_k<<<dim3(DM / 64, MLPD / 64, NLAYER), dim3(64, 8), 0, stream>>>(
      w2, w2T, MLPD, DM, (size_t)MLPD * DM, (size_t)MLPD * DM);

  // layer-0 ln1 stats from x_in (also leaves buffers ready: ln_k zeros after reading)
  stats0_k<<<dim3(DM / 8, NB), 256, 0, stream>>>(x_in, statS, statSS);

  for (int i = 0; i < NLAYER; i++) {
    const float* xcur = (i == 0) ? x_in : xf;
    float* xnext_out = (i == NLAYER - 1) ? (float*)d_out : xf;
    float* sS = (i == NLAYER - 1) ? nullptr : statS;    // last mlp2's stats unused
    float* sSS = (i == NLAYER - 1) ? nullptr : statSS;

    // ln1: stats from previous mlp2 (or stats0_k); zeros buffers after reading
    ln_k<<<dim3(DM / 8, NB), 256, 0, stream>>>(xcur, ln1g + i * SEQ, ln1b + i * SEQ, h,
                                               statS, statSS);
    // qkv GEMM with fused V-transpose epilogue; dbuf pipeline (BM=64, BK=64)
    gemm_bt<64, 128, 64, 3, 1><<<dim3(QKVW / 128, ROWS / 64), 256, 0, stream>>>(
        h, wqkvT + (size_t)i * QKVW * DM, qkv, nullptr, nullptr, nullptr, vT,
        nullptr, nullptr, ROWS, QKVW, DM);
    attn_k<<<dim3(SEQ / 64, NH, NB), 256, 0, stream>>>(qkv, vT, zbuf);
    // attn-out: BK=128 (16 iters, 2 blocks/CU); stats for ln2
    gemm_bt<64, 64, 128, 2, 1><<<dim3(DM / 64, ROWS / 64), 256, 0, stream>>>(
        zbuf, woutT + (size_t)i * DM * INNERW, nullptr, b_out + i * DM, xcur, xf, nullptr,
        statS, statSS, ROWS, DM, INNERW);
    // ln2: reads attn-out stats; zeros buffers
    ln_k<<<dim3(DM / 8, NB), 256, 0, stream>>>(xf, ln2g + i * SEQ, ln2b + i * SEQ, h,
                                               statS, statSS);
    gemm_bt<64, 128, 64, 1, 1><<<dim3(MLPD / 128, ROWS / 64), 256, 0, stream>>>(
        h, w1T + (size_t)i * MLPD * DM, mh, b1 + i * MLPD, nullptr, nullptr, nullptr,
        nullptr, nullptr, ROWS, MLPD, DM);
    // mlp2: BK=128 (8 iters); resid xf->(xf|d_out); stats for next ln1
    gemm_bt<64, 64, 128, 2, 1><<<dim3(DM / 64, ROWS / 64), 256, 0, stream>>>(
        mh, w2T + (size_t)i * DM * MLPD, nullptr, b2 + i * DM, xf, xnext_out, nullptr,
        sS, sSS, ROWS, DM, MLPD);
  }
}

// Round 19
// 901.682 us; speedup vs baseline: 1.2981x; 1.0040x over previous
//
#include <hip/hip_runtime.h>
#include <hip/hip_bf16.h>

#define SEQ    1024
#define DM     256
#define NH     8
#define NB     8
#define NLAYER 4
#define MLPD   1024
#define ROWS   (NB*SEQ)      // 8192
#define QKVW   6144          // 3*NH*DM
#define INNERW 2048          // NH*DM

typedef __attribute__((ext_vector_type(8))) short bh8;
typedef __attribute__((ext_vector_type(4))) short bh4;
typedef __attribute__((ext_vector_type(4))) float fx4;

__device__ __forceinline__ short f2bf(float f) {
  return __builtin_bit_cast(short, __float2bfloat16(f));
}
__device__ __forceinline__ fx4 mfma16(bh8 a, bh8 b, fx4 c) {
  return __builtin_amdgcn_mfma_f32_16x16x32_bf16(a, b, c, 0, 0, 0);
}
__device__ __forceinline__ void g2l16(const void* g, void* l) {
  __builtin_amdgcn_global_load_lds(
      (const __attribute__((address_space(1))) void*)g,
      (__attribute__((address_space(3))) void*)l, 16, 0, 0);
}
__device__ __forceinline__ int kperm(int r) {
  return ((r & 1) << 2) | ((r >> 1) & 3);
}

// ---------------- f32 -> bf16 transpose (per-layer via blockIdx.z) ----------------
// 64x64 tiles: 256-B read segments, 128-B write segments.
// src: [R][C] f32 (row stride C), dst: [C][R] bf16
__global__ void wtrans_k(const float* __restrict__ src, __hip_bfloat16* __restrict__ dst,
                         int R, int C, size_t sls, size_t dls) {
  src += (size_t)blockIdx.z * sls;
  dst += (size_t)blockIdx.z * dls;
  __shared__ float t[64][65];
  int tx = threadIdx.x, ty = threadIdx.y;   // (64, 8)
  int r0 = blockIdx.y * 64, c0 = blockIdx.x * 64;
#pragma unroll
  for (int i = 0; i < 64; i += 8) t[ty + i][tx] = src[(size_t)(r0 + ty + i) * C + c0 + tx];
  __syncthreads();
#pragma unroll
  for (int i = 0; i < 64; i += 8)
    dst[(size_t)(c0 + ty + i) * R + r0 + tx] = __float2bfloat16(t[tx][ty + i]);
}

// ---------------- layer-0 LN stats: column sums of x_in ----------------
__global__ void stats0_k(const float* __restrict__ x, float* __restrict__ statS,
                         float* __restrict__ statSS) {
  int b = blockIdx.y, d0 = blockIdx.x * 8;
  int dl = threadIdx.x & 1, nt = threadIdx.x >> 1;
  const float* xb = x + (size_t)b * SEQ * DM + d0 + dl * 4;
  fx4 s = 0.f, ss = 0.f;
  for (int n = nt; n < SEQ; n += 128) {
    fx4 v = *(const fx4*)(xb + (size_t)n * DM);
    s += v; ss += v * v;
  }
  __shared__ fx4 S1[128][2], S2[128][2];
  S1[nt][dl] = s; S2[nt][dl] = ss;
  __syncthreads();
  if (nt < 16) {
    fx4 a = S1[nt][dl], c = S2[nt][dl];
#pragma unroll
    for (int i = 0; i < 7; i++) { a += S1[nt + 16 + i * 16][dl]; c += S2[nt + 16 + i * 16][dl]; }
    S1[nt][dl] = a; S2[nt][dl] = c;
  }
  __syncthreads();
  if (nt == 0) {
    fx4 a = 0.f, c = 0.f;
#pragma unroll
    for (int i = 0; i < 16; i++) { a += S1[i][dl]; c += S2[i][dl]; }
    *(fx4*)(statS + b * DM + d0 + dl * 4) = a;
    *(fx4*)(statSS + b * DM + d0 + dl * 4) = c;
  }
}

// ---------------- LayerNorm normalize-only (stats precomputed) ----------------
__global__ void ln_k(const float* __restrict__ xf, const float* __restrict__ gam,
                     const float* __restrict__ bet, __hip_bfloat16* __restrict__ h,
                     float* __restrict__ statS, float* __restrict__ statSS) {
  int b = blockIdx.y, d0 = blockIdx.x * 8;
  int dl = threadIdx.x & 1;
  int nt = threadIdx.x >> 1;
  fx4 s = *(const fx4*)(statS + b * DM + d0 + dl * 4);
  fx4 ss = *(const fx4*)(statSS + b * DM + d0 + dl * 4);
  fx4 mu, rs;
#pragma unroll
  for (int r = 0; r < 4; r++) {
    mu[r] = s[r] * (1.f / SEQ);
    float var = ss[r] * (1.f / SEQ) - mu[r] * mu[r];
    rs[r] = rsqrtf(var + 1e-3f);
  }
  __syncthreads();   // all threads have read stats
  if (threadIdx.x < 2) {
    *(fx4*)(statS + b * DM + d0 + threadIdx.x * 4) = fx4{0.f, 0.f, 0.f, 0.f};
    *(fx4*)(statSS + b * DM + d0 + threadIdx.x * 4) = fx4{0.f, 0.f, 0.f, 0.f};
  }
  const float* xb = xf + (size_t)b * SEQ * DM + d0 + dl * 4;
  __hip_bfloat16* hb = h + (size_t)b * SEQ * DM + d0 + dl * 4;
  for (int n = nt; n < SEQ; n += 128) {
    fx4 v = *(const fx4*)(xb + (size_t)n * DM);
    float gn = gam[n], bn = bet[n];
    bh4 o;
#pragma unroll
    for (int r = 0; r < 4; r++) o[r] = f2bf((v[r] - mu[r]) * rs[r] * gn + bn);
    *(bh4*)(hb + (size_t)n * DM) = o;
  }
}

// ---------------- GEMM: C[M,Nc] = A[M,K] * Bt[Nc,K]^T  (+ epilogues) ----------------
// BM/BK templated. K=256 GEMMs (qkv, mlp1): BM=128 — 32 MFMA per dbuf iteration
// against 8 staging loads (2x the compute density of BM=64; 2 blocks/CU at 64 KB
// dbuf LDS). Long-K EPI2 GEMMs: BM=64, BK=128 (occupancy-favoring, R14).
// kperm-swizzled LDS staging, XCD-aware bijective block swizzle.
// DBUF=1: double-buffered LDS, stage(t+1) issued BEFORE compute(t), one barrier/iter.
// EPI 0: bf16 stores   EPI 1: +bias, exact GELU
// EPI 2: rout = rin + acc + bias; LN stats fused via wave-reduce + atomicAdd
// EPI 3 (qkv): V third (n0>=4096) stored TRANSPOSED into vT via padded-LDS round-trip.
template <int BM, int BN, int BK, int EPI, int DBUF>
__global__ __launch_bounds__(256) void gemm_bt(
    const __hip_bfloat16* __restrict__ A, const __hip_bfloat16* __restrict__ Bt,
    __hip_bfloat16* __restrict__ Cout, const float* __restrict__ bias,
    const float* __restrict__ rin, float* __restrict__ rout,
    __hip_bfloat16* __restrict__ vT, float* __restrict__ statS,
    float* __restrict__ statSS, int M, int Nc, int K) {
  constexpr int NR = BN / 32;
  constexpr int MR = BM / 32;
  constexpr int GPR = BK / 8;              // 16B granules per row
  constexpr int NKS = BK / 32;             // k-slices per tile
  constexpr int SPAN = (BM + BN) * BK;
  constexpr int CP = BM + 4;               // EPI3 padded nn stride
  static_assert(BN == 64 || BN == 128, "");
  static_assert(BM == 64 || BM == 128, "");
  static_assert(BK == 64 || BK == 128, "");
  constexpr int BUFE = SPAN * (DBUF ? 2 : 1);
  constexpr int LDSE = (EPI == 3) ? (BUFE > 128 * CP ? BUFE : 128 * CP) : BUFE;
  __shared__ __hip_bfloat16 smem[LDSE];
  const int tid = threadIdx.x;
  const int lane = tid & 63, w = tid >> 6;
  const int g = lane >> 4, qr = lane & 15;
  const int wr = w >> 1, wc = w & 1;
  // XCD swizzle: apparent id -> logical id so each XCD gets a contiguous chunk
  const unsigned aid = blockIdx.y * gridDim.x + blockIdx.x;
  const unsigned nwg = gridDim.x * gridDim.y;
  const unsigned lid = (aid & 7u) * (nwg >> 3) + (aid >> 3);
  const int m0 = (int)(lid / gridDim.x) * BM, n0 = (int)(lid % gridDim.x) * BN;
  const int swr = kperm(qr & 7);

  fx4 acc[MR][NR];
#pragma unroll
  for (int m = 0; m < MR; m++)
#pragma unroll
    for (int n = 0; n < NR; n++) acc[m][n] = 0.f;

  constexpr int ACH = (BM * BK) / (8 * 256);
  constexpr int BCH = (BN * BK) / (8 * 256);

  auto stage = [&](int buf, int k0) {
    __hip_bfloat16* As_ = smem + buf * SPAN;
    __hip_bfloat16* Bs_ = As_ + BM * BK;
#pragma unroll
    for (int c = 0; c < ACH; c++) {
      int idx = tid + c * 256;
      int row = idx / GPR, gr2 = idx % GPR;
      g2l16(A + (size_t)(m0 + row) * K + k0 + ((gr2 ^ kperm(row & 7)) << 3), (char*)As_ + idx * 16);
    }
#pragma unroll
    for (int c = 0; c < BCH; c++) {
      int idx = tid + c * 256;
      int col = idx / GPR, gr2 = idx % GPR;
      g2l16(Bt + (size_t)(n0 + col) * K + k0 + ((gr2 ^ kperm(col & 7)) << 3), (char*)Bs_ + idx * 16);
    }
  };
  auto comp = [&](const __hip_bfloat16* As_, const __hip_bfloat16* Bs_) {
#pragma unroll
    for (int ks = 0; ks < NKS; ks++) {
      bh8 af[MR], bf[NR];
#pragma unroll
      for (int m = 0; m < MR; m++)
        af[m] = *(const bh8*)(As_ + (wr * (BM / 2) + m * 16 + qr) * BK + (((ks * 4 + g) ^ swr) << 3));
#pragma unroll
      for (int n = 0; n < NR; n++)
        bf[n] = *(const bh8*)(Bs_ + (wc * (BN / 2) + n * 16 + qr) * BK + (((ks * 4 + g) ^ swr) << 3));
#pragma unroll
      for (int m = 0; m < MR; m++)
#pragma unroll
        for (int n = 0; n < NR; n++) acc[m][n] = mfma16(af[m], bf[n], acc[m][n]);
    }
  };

  if constexpr (DBUF) {
    stage(0, 0);
    __syncthreads();
    const int NT = K / BK;
    for (int t = 0; t < NT; ++t) {
      const int cur = t & 1;
      if (t + 1 < NT) stage(cur ^ 1, (t + 1) * BK);
      comp(smem + cur * SPAN, smem + cur * SPAN + BM * BK);
      __syncthreads();
    }
  } else {
    for (int k0 = 0; k0 < K; k0 += BK) {
      __syncthreads();
      stage(0, k0);
      __syncthreads();
      comp(smem, smem + BM * BK);
    }
  }

  // acc[m][n][r] = C[m0 + wr*(BM/2) + m*16 + g*4 + r][n0 + wc*(BN/2) + n*16 + qr]
  if constexpr (EPI == 2) {
    float psum[NR], psq[NR];
#pragma unroll
    for (int n = 0; n < NR; n++) { psum[n] = 0.f; psq[n] = 0.f; }
#pragma unroll
    for (int n = 0; n < NR; n++) {
      int gc = n0 + wc * (BN / 2) + n * 16 + qr;
      float bv = bias[gc];
#pragma unroll
      for (int m = 0; m < MR; m++) {
        int grb = m0 + wr * (BM / 2) + m * 16 + g * 4;
#pragma unroll
        for (int r = 0; r < 4; r++) {
          float v = rin[(size_t)(grb + r) * Nc + gc] + acc[m][n][r] + bv;
          rout[(size_t)(grb + r) * Nc + gc] = v;
          psum[n] += v; psq[n] += v * v;
        }
      }
    }
    if (statS) {   // LN stats fusion: reduce over the 4 g-groups, one atomic per column
      int b = m0 >> 10;
#pragma unroll
      for (int n = 0; n < NR; n++) {
        int gc = n0 + wc * (BN / 2) + n * 16 + qr;
        float a = psum[n];
        a += __shfl_xor(a, 16); a += __shfl_xor(a, 32);
        float c = psq[n];
        c += __shfl_xor(c, 16); c += __shfl_xor(c, 32);
        if (g == 0) {
          atomicAdd(statS + b * DM + gc, a);
          atomicAdd(statSS + b * DM + gc, c);
        }
      }
    }
  } else if (EPI == 3 && n0 >= 4096) {
    // ---- V third: transposed store into vT via padded-LDS round-trip ----
    __syncthreads();
    __hip_bfloat16* Cs = smem;             // [128 d][CP nn-padded]
#pragma unroll
    for (int n = 0; n < NR; n++) {
      int dl = wc * (BN / 2) + n * 16 + qr;
#pragma unroll
      for (int m = 0; m < MR; m++) {
        int grp = (wr * (BM / 2) + m * 16) & ~31;
        int nlp = grp + g * 8 + (m & 1) * 4;   // PV slot permutation within 32-row group
        bh4 v;
#pragma unroll
        for (int r = 0; r < 4; r++) v[r] = f2bf(acc[m][n][r]);
        *(bh4*)(Cs + dl * CP + nlp) = v;
      }
    }
    __syncthreads();
    const int dl = tid >> 1, half = tid & 1;
    const int bb = m0 >> 10;
    const int hh = (n0 - 4096) >> 8;
    const int d0v = (n0 - 4096) & 255;
    __hip_bfloat16* dst =
        vT + ((size_t)(bb * 8 + hh) * 256 + d0v + dl) * SEQ + (m0 & 1023) + half * (BM / 2);
#pragma unroll
    for (int j = 0; j < BM / 16; j++)
      *(bh8*)(dst + j * 8) = *(const bh8*)(Cs + dl * CP + half * (BM / 2) + j * 8);
  } else {
#pragma unroll
    for (int n = 0; n < NR; n++) {
      int gc = n0 + wc * (BN / 2) + n * 16 + qr;
      float bv = (EPI == 1) ? bias[gc] : 0.f;
#pragma unroll
      for (int m = 0; m < MR; m++) {
        int grb = m0 + wr * (BM / 2) + m * 16 + g * 4;
#pragma unroll
        for (int r = 0; r < 4; r++) {
          float v = acc[m][n][r];
          if (EPI == 1) {
            v += bv;
            v = 0.5f * v * (1.f + erff(v * 0.70710678118654752f));
          }
          Cout[(size_t)(grb + r) * Nc + gc] = __float2bfloat16(v);
        }
      }
    }
  }
}

// ---------------- Flash attention: grid (SEQ/64, NH, NB), 4 waves x 16 q-rows ----------------
// R18 config: single-buffered Ks/Vs, 256 threads, 4 blocks/CU, XCD bijective swizzle,
// kperm K-granules, defer-max + exp2 softmax, SWAPPED PV (lane-local rescale,
// bh4 z-stores), deferred per-lane l-reduction (2 shfl total at the end).
//   Ks: [key 0..31][256 d], granule G holds data granule G ^ kperm(key&7)
//   Vs: [d 0..255][32 key-slots] (slots PV-permuted at vT creation), G ^= (d>>1)&3
__global__ __launch_bounds__(256) void attn_k(
    const __hip_bfloat16* __restrict__ qkv, const __hip_bfloat16* __restrict__ vT,
    __hip_bfloat16* __restrict__ z) {
  __shared__ __hip_bfloat16 Ks[32 * 256];
  __shared__ __hip_bfloat16 Vs[256 * 32];
  const int tid = threadIdx.x;
  const int lane = tid & 63, w = tid >> 6;
  const int g = lane >> 4, qr = lane & 15;
  // XCD swizzle: nwg = 16*8*8 = 1024, chunk = 128 logical blocks per XCD
  const unsigned aid = (blockIdx.z * NH + blockIdx.y) * (SEQ / 64) + blockIdx.x;
  const unsigned lid = (aid & 7u) * 128u + (aid >> 3);
  const int qi = lid & 15, hh = (lid >> 4) & 7, b = lid >> 7;
  const int q0 = qi * 64 + w * 16;
  const size_t qkv_b = (size_t)b * SEQ * QKVW;

  // Q fragments: lane holds Q[q0+qr][kd*32 + g*8 .. +8]
  bh8 qf[8];
  {
    const __hip_bfloat16* qrow = qkv + qkv_b + (size_t)(q0 + qr) * QKVW + hh * 256 + g * 8;
#pragma unroll
    for (int kd = 0; kd < 8; kd++) qf[kd] = *(const bh8*)(qrow + kd * 32);
  }

  fx4 o[16];
#pragma unroll
  for (int i = 0; i < 16; i++) o[i] = 0.f;
  float m_run = -INFINITY, l_par = 0.f;        // l_par: PER-LANE partial denominator
  constexpr float cL = 0.0625f * 1.44269504f;  // scale * log2(e)

  const int ksw = kperm(qr & 7);          // Ks read swizzle (rows qr and 16+qr share it)
  const int vsw = ((qr >> 1) & 3);        // Vs read swizzle (d = nd*16+qr -> (d>>1)&3)

  for (int j0 = 0; j0 < SEQ; j0 += 32) {
    __syncthreads();
#pragma unroll
    for (int c = 0; c < 4; c++) {
      int idx = tid + c * 256;
      int key = idx >> 5, c16 = idx & 31;
      int dp = (c16 ^ kperm(key & 7)) << 3; // pre-swizzled source column (elements)
      g2l16(qkv + qkv_b + (size_t)(j0 + key) * QKVW + 2048 + hh * 256 + dp, (char*)Ks + idx * 16);
    }
    const __hip_bfloat16* vb = vT + ((size_t)(b * 8 + hh) * 256) * SEQ + j0;
#pragma unroll
    for (int c = 0; c < 4; c++) {
      int idx = tid + c * 256;
      int d = idx >> 2, gr = idx & 3;
      int np = (gr ^ ((d >> 1) & 3)) << 3; // pre-swizzled source slot (elements)
      g2l16(vb + (size_t)d * SEQ + np, (char*)Vs + idx * 16);
    }
    __syncthreads();

    // S^T = K * Q^T : lane holds S[q=qr][key = {g*4+r, 16+g*4+r}]  (raw scores)
    fx4 s0 = 0.f, s1 = 0.f;
#pragma unroll
    for (int kd = 0; kd < 8; kd++) {
      bh8 k0f = *(const bh8*)(Ks + (size_t)qr * 256 + (((kd * 4 + g) ^ ksw) << 3));
      bh8 k1f = *(const bh8*)(Ks + (size_t)(16 + qr) * 256 + (((kd * 4 + g) ^ ksw) << 3));
      s0 = mfma16(k0f, qf[kd], s0);
      s1 = mfma16(k1f, qf[kd], s1);
    }
    float sv[8];
#pragma unroll
    for (int r = 0; r < 4; r++) { sv[r] = s0[r]; sv[4 + r] = s1[r]; }
    float pmax = sv[0];
#pragma unroll
    for (int i = 1; i < 8; i++) pmax = fmaxf(pmax, sv[i]);
    pmax = fmaxf(pmax, __shfl_xor(pmax, 16));
    pmax = fmaxf(pmax, __shfl_xor(pmax, 32));
    // defer-max: rescale only if some row's max grew by > 128 raw (= 8 scaled)
    if (!__all(pmax <= m_run + 128.f)) {
      float m_new = fmaxf(m_run, pmax);
      float corr = __builtin_amdgcn_exp2f((m_run - m_new) * cL); // first tile: 0
      // swapped-O layout: every o[nd][r] has q = qr -> corr is lane-local;
      // corr is row-uniform so per-lane l partials stay consistent
#pragma unroll
      for (int nd = 0; nd < 16; nd++) {
        o[nd][0] *= corr; o[nd][1] *= corr; o[nd][2] *= corr; o[nd][3] *= corr;
      }
      l_par *= corr;
      m_run = m_new;
    }
    float mL = m_run * cL;
    float p[8];
#pragma unroll
    for (int i = 0; i < 8; i++) {
      p[i] = __builtin_amdgcn_exp2f(fmaf(sv[i], cL, -mL)); // bounded by 2^8
      l_par += p[i];
    }
    // P -> bf16 A-frag with key(g,i) = g*4 + (i&3) + 16*(i>>2); Vs slots hold V in the
    // same key order. SWAPPED: mfma16(vf, pa) -> lane holds O[q=qr][d=nd*16+g*4+r].
    bh8 pa;
#pragma unroll
    for (int i = 0; i < 8; i++) pa[i] = f2bf(p[i]);
#pragma unroll
    for (int nd = 0; nd < 16; nd++) {
      int d = nd * 16 + qr;
      bh8 vf = *(const bh8*)(Vs + (size_t)d * 32 + ((g ^ vsw) << 3));
      o[nd] = mfma16(vf, pa, o[nd]);
    }
  }

  // final l reduction across the 4 g-groups of this row (once, not per tile)
  float l_tot = l_par;
  l_tot += __shfl_xor(l_tot, 16);
  l_tot += __shfl_xor(l_tot, 32);
  float inv = 1.f / l_tot;   // q = qr: lane-local epilogue, no further shuffles
  __hip_bfloat16* zb = z + (size_t)b * SEQ * INNERW + hh * 256 + (size_t)(q0 + qr) * INNERW;
#pragma unroll
  for (int nd = 0; nd < 16; nd++) {
    bh4 ov;
#pragma unroll
    for (int r = 0; r < 4; r++) ov[r] = f2bf(o[nd][r] * inv);
    *(bh4*)(zb + nd * 16 + g * 4) = ov;
  }
}

// ---------------- host ----------------
extern "C" void kernel_launch(void* const* d_in, const int* in_sizes, int n_in,
                              void* d_out, int out_size, void* d_ws, size_t ws_size,
                              hipStream_t stream) {
  const float* x_in  = (const float*)d_in[0];
  const float* ln1g  = (const float*)d_in[1];
  const float* ln1b  = (const float*)d_in[2];
  const float* w_qkv = (const float*)d_in[3];
  const float* w_out = (const float*)d_in[4];
  const float* b_out = (const float*)d_in[5];
  const float* ln2g  = (const float*)d_in[6];
  const float* ln2b  = (const float*)d_in[7];
  const float* w1    = (const float*)d_in[8];
  const float* b1    = (const float*)d_in[9];
  const float* w2    = (const float*)d_in[10];
  const float* b2    = (const float*)d_in[11];

  char* ws = (char*)d_ws;
  size_t off = 0;
  auto alloc = [&](size_t bytes) { char* p = ws + off; off += (bytes + 255) & ~(size_t)255; return p; };
  float*          xf    = (float*)         alloc((size_t)ROWS * DM * 4);
  __hip_bfloat16* h     = (__hip_bfloat16*)alloc((size_t)ROWS * DM * 2);
  __hip_bfloat16* qkv   = (__hip_bfloat16*)alloc((size_t)ROWS * QKVW * 2);
  __hip_bfloat16* vT    = (__hip_bfloat16*)alloc((size_t)NB * NH * 256 * SEQ * 2);
  __hip_bfloat16* zbuf  = (__hip_bfloat16*)alloc((size_t)ROWS * INNERW * 2);
  __hip_bfloat16* mh    = zbuf; // MLP hidden reuses z region (disjoint lifetimes)
  __hip_bfloat16* wqkvT = (__hip_bfloat16*)alloc((size_t)NLAYER * QKVW * DM * 2);
  __hip_bfloat16* woutT = (__hip_bfloat16*)alloc((size_t)NLAYER * DM * INNERW * 2);
  __hip_bfloat16* w1T   = (__hip_bfloat16*)alloc((size_t)NLAYER * MLPD * DM * 2);
  __hip_bfloat16* w2T   = (__hip_bfloat16*)alloc((size_t)NLAYER * DM * MLPD * 2);
  float*          statS = (float*)         alloc((size_t)NB * DM * 4);
  float*          statSS= (float*)         alloc((size_t)NB * DM * 4);
  (void)ws_size; (void)in_sizes; (void)n_in; (void)out_size;

  // weight transposes+casts (weights constant across the launch); 64x64 tiles
  wtrans_k<<<dim3(QKVW / 64, DM / 64, NLAYER), dim3(64, 8), 0, stream>>>(
      w_qkv, wqkvT, DM, QKVW, (size_t)DM * QKVW, (size_t)DM * QKVW);
  wtrans_k<<<dim3(DM / 64, INNERW / 64, NLAYER), dim3(64, 8), 0, stream>>>(
      w_out, woutT, INNERW, DM, (size_t)INNERW * DM, (size_t)INNERW * DM);
  wtrans_k<<<dim3(MLPD / 64, DM / 64, NLAYER), dim3(64, 8), 0, stream>>>(
      w1, w1T, DM, MLPD, (size_t)DM * MLPD, (size_t)DM * MLPD);
  wtrans_k<<<dim3(DM / 64, MLPD / 64, NLAYER), dim3(64, 8), 0, stream>>>(
      w2, w2T, MLPD, DM, (size_t)MLPD * DM, (size_t)MLPD * DM);

  // layer-0 ln1 stats from x_in (also leaves buffers ready: ln_k zeros after reading)
  stats0_k<<<dim3(DM / 8, NB), 256, 0, stream>>>(x_in, statS, statSS);

  for (int i = 0; i < NLAYER; i++) {
    const float* xcur = (i == 0) ? x_in : xf;
    float* xnext_out = (i == NLAYER - 1) ? (float*)d_out : xf;
    float* sS = (i == NLAYER - 1) ? nullptr : statS;    // last mlp2's stats unused
    float* sSS = (i == NLAYER - 1) ? nullptr : statSS;

    // ln1: stats from previous mlp2 (or stats0_k); zeros buffers after reading
    ln_k<<<dim3(DM / 8, NB), 256, 0, stream>>>(xcur, ln1g + i * SEQ, ln1b + i * SEQ, h,
                                               statS, statSS);
    // qkv GEMM, BM=128: 32 MFMA/iter vs 8 staging loads; fused V-transpose epilogue
    gemm_bt<128, 128, 64, 3, 1><<<dim3(QKVW / 128, ROWS / 128), 256, 0, stream>>>(
        h, wqkvT + (size_t)i * QKVW * DM, qkv, nullptr, nullptr, nullptr, vT,
        nullptr, nullptr, ROWS, QKVW, DM);
    attn_k<<<dim3(SEQ / 64, NH, NB), 256, 0, stream>>>(qkv, vT, zbuf);
    // attn-out: BM=64, BK=128 (16 iters, 2 blocks/CU); stats for ln2
    gemm_bt<64, 64, 128, 2, 1><<<dim3(DM / 64, ROWS / 64), 256, 0, stream>>>(
        zbuf, woutT + (size_t)i * DM * INNERW, nullptr, b_out + i * DM, xcur, xf, nullptr,
        statS, statSS, ROWS, DM, INNERW);
    // ln2: reads attn-out stats; zeros buffers
    ln_k<<<dim3(DM / 8, NB), 256, 0, stream>>>(xf, ln2g + i * SEQ, ln2b + i * SEQ, h,
                                               statS, statSS);
    // mlp1: BM=128 density variant
    gemm_bt<128, 128, 64, 1, 1><<<dim3(MLPD / 128, ROWS / 128), 256, 0, stream>>>(
        h, w1T + (size_t)i * MLPD * DM, mh, b1 + i * MLPD, nullptr, nullptr, nullptr,
        nullptr, nullptr, ROWS, MLPD, DM);
    // mlp2: BK=128 (8 iters); resid xf->(xf|d_out); stats for next ln1
    gemm_bt<64, 64, 128, 2, 1><<<dim3(DM / 64, ROWS / 64), 256, 0, stream>>>(
        mh, w2T + (size_t)i * DM * MLPD, nullptr, b2 + i * DM, xf, xnext_out, nullptr,
        sS, sSS, ROWS, DM, MLPD);
  }
}